// Round 4
// baseline (415.743 us; speedup 1.0000x reference)
//
#include <hip/hip_runtime.h>

#define B_ 2
#define S_LEN 2048
#define DMODEL 2048
#define NH 16
#define NKVH 4
#define HD 128
#define RLORA 128
#define WINDOW_ 512
#define NGLOBAL 64

#define FENCE asm volatile("" ::: "memory")

typedef __bf16 bf16x8 __attribute__((ext_vector_type(8)));
typedef float f32x4 __attribute__((ext_vector_type(4)));

__device__ __forceinline__ float bf2f(unsigned short h) {
    return __uint_as_float(((unsigned int)h) << 16);
}
__device__ __forceinline__ unsigned short f2bf(float f) {
    unsigned int u = __float_as_uint(f);
    unsigned int r = u + 0x7fffu + ((u >> 16) & 1u);
    return (unsigned short)(r >> 16);
}
__device__ __forceinline__ unsigned int pack2bf(float a, float b) {
    return (unsigned int)f2bf(a) | ((unsigned int)f2bf(b) << 16);
}
__device__ __forceinline__ uint4 load8f(const float* p) {
    float4 f0 = *(const float4*)p;
    float4 f1 = *(const float4*)(p + 4);
    uint4 u;
    u.x = pack2bf(f0.x, f0.y);
    u.y = pack2bf(f0.z, f0.w);
    u.z = pack2bf(f1.x, f1.y);
    u.w = pack2bf(f1.z, f1.w);
    return u;
}

// Async global->LDS, 16 B per lane. LDS dest = wave-uniform base + lane*16.
__device__ __forceinline__ void gld16(const unsigned short* g, unsigned short* l) {
    __builtin_amdgcn_global_load_lds(
        (const __attribute__((address_space(1))) unsigned int*)g,
        (__attribute__((address_space(3))) unsigned int*)l,
        16, 0, 0);
}

// ---------------------------------------------------------------------------
// Batched fp32 -> bf16 conversion over up to 12 tensors. 2048 elems/block.
// ---------------------------------------------------------------------------
struct Conv12 {
    const float* s[12];
    unsigned short* d[12];
    int c[13];
};
__global__ __launch_bounds__(256) void convk(Conv12 a)
{
    int b = blockIdx.x;
    int seg = 0;
    while (b >= a.c[seg + 1]) seg++;
    int off = (b - a.c[seg]) * 2048 + threadIdx.x * 8;
    *(uint4*)(a.d[seg] + off) = load8f(a.s[seg] + off);
}

// ---------------------------------------------------------------------------
// 256x256 8-phase GEMM core (R4). BK=64, 8 waves (2Mx4N), 512 threads,
// 128 KiB LDS (2 dbuf x [A 256x64 + B 256x64] bf16). Derived from the
// verified 8-phase template: per K-tile 4 phases x {ds_read subtile ||
// stage 1 half-tile || 16 MFMA}, counted vmcnt(6) ONCE per tile (never 0
// in-loop), T2 both-sides swizzle (linear LDS dest + pre-swizzled global
// src byte^((row&7)<<4), same XOR on ds_read), setprio around MFMA.
// Stage schedule (region freed -> restaged >=1 barrier later):
//   P1: A-h1(t+1)   [freed at (t-1)P3]
//   P2: B-h0(t+2)   [all B frags read+lgkm0'd in P1]
//   P3: B-h1(t+2)
//   P4: A-h0(t+2)   [A-m1 read in P3]
// Tile-ready proof: tile t+1's 4 halves are staged at (t-1)P2..P4 + tP1 ->
// all outside the newest-3 window of tP4's vmcnt(6).
// LoRA tail merged: nt = Kmain/64 + 2 tiles from (TA,BL).
// ---------------------------------------------------------------------------
__device__ __forceinline__ void gemm256_acc(
    const unsigned short* __restrict__ A, int lda, int m0,
    const unsigned short* __restrict__ W, int ldw, int n0,
    const unsigned short* __restrict__ TA, int ldt,
    const unsigned short* __restrict__ BL,
    int Kmain, f32x4 (&acc)[8][4])
{
    __shared__ __align__(16) unsigned short As[2][16384];
    __shared__ __align__(16) unsigned short Bs[2][16384];
    const int tid = threadIdx.x;
    const int lane = tid & 63, wid = tid >> 6;
    const int quad = lane >> 4, l16 = lane & 15;
    const int wm0 = (wid >> 2) * 128, wn0 = (wid & 3) * 64;

    // staging source map (per thread, 2 chunks): LDS dest linear
    // o = tid*16 + c*8192 bytes within a 16 KB half-tile.
    int rS[2], cS[2];
    #pragma unroll
    for (int c = 0; c < 2; c++) {
        const int o = tid * 16 + c * 8192;
        rS[c] = o >> 7;                                   // row in half (0..127)
        cS[c] = ((o & 127) ^ ((rS[c] & 7) << 4)) >> 1;    // true col (shorts)
    }
    const int ntm = Kmain >> 6;
    const int nt = ntm + 2;
    const int ldsbase = wid * 512;    // shorts; + c*4096 + h*8192

    auto stageA = [&](int bb, int h, int j) {
        const unsigned short* s; int ld, k0;
        if (j < ntm) { s = A + (size_t)m0 * lda;  ld = lda; k0 = j << 6; }
        else         { s = TA + (size_t)m0 * ldt; ld = ldt; k0 = (j - ntm) << 6; }
        #pragma unroll
        for (int c = 0; c < 2; c++)
            gld16(s + (size_t)(h * 128 + rS[c]) * ld + k0 + cS[c],
                  &As[bb][h * 8192 + c * 4096 + ldsbase]);
    };
    auto stageB = [&](int bb, int h, int j) {
        const unsigned short* s; int ld, k0;
        if (j < ntm) { s = W + (size_t)n0 * ldw;     ld = ldw;   k0 = j << 6; }
        else         { s = BL + (size_t)n0 * RLORA;  ld = RLORA; k0 = (j - ntm) << 6; }
        #pragma unroll
        for (int c = 0; c < 2; c++)
            gld16(s + (size_t)(h * 128 + rS[c]) * ld + k0 + cS[c],
                  &Bs[bb][h * 8192 + c * 4096 + ldsbase]);
    };

    // fragment read offsets (shorts). row&7 == l16&7 for all frags.
    int xk[2];
    #pragma unroll
    for (int kk = 0; kk < 2; kk++)
        xk[kk] = ((kk * 64 + quad * 16) ^ ((l16 & 7) << 4)) >> 1;
    const int abase = (wm0 + l16) * 64;
    const int bbase = (wn0 + l16) * 64;

    // prologue: tile0 full + tile1 {B-h0, B-h1, A-h0} (A-h1(1) comes at t0P1)
    stageA(0, 0, 0); stageA(0, 1, 0); stageB(0, 0, 0); stageB(0, 1, 0);
    stageB(1, 0, 1); stageB(1, 1, 1); stageA(1, 0, 1);
    asm volatile("s_waitcnt vmcnt(6)" ::: "memory");
    __builtin_amdgcn_sched_barrier(0);
    FENCE; __builtin_amdgcn_s_barrier(); FENCE;

    for (int t = 0; t < nt; t++) {
        const int bb = t & 1, ob = bb ^ 1;
        const int jn = (t + 1 < nt) ? t + 1 : nt - 1;
        const int j2 = (t + 2 < nt) ? t + 2 : nt - 1;
        const unsigned short* Ab = As[bb];
        const unsigned short* Bb = Bs[bb];
        bf16x8 af[4][2], bf[4][2];

        // ---- P1: read A-m0 (8) + B all (8); stage A-h1(t+1) ----
        #pragma unroll
        for (int mi = 0; mi < 4; mi++)
            #pragma unroll
            for (int kk = 0; kk < 2; kk++)
                af[mi][kk] = *(const bf16x8*)&Ab[abase + mi * 1024 + xk[kk]];
        #pragma unroll
        for (int ni = 0; ni < 4; ni++)
            #pragma unroll
            for (int kk = 0; kk < 2; kk++)
                bf[ni][kk] = *(const bf16x8*)&Bb[bbase + ni * 1024 + xk[kk]];
        stageA(ob, 1, jn);
        FENCE; __builtin_amdgcn_s_barrier(); FENCE;
        asm volatile("s_waitcnt lgkmcnt(0)" ::: "memory");   // all P1 reads serviced
        __builtin_amdgcn_sched_barrier(0);
        __builtin_amdgcn_s_setprio(1);
        #pragma unroll
        for (int mi = 0; mi < 4; mi++)
            #pragma unroll
            for (int ni = 0; ni < 2; ni++)
                #pragma unroll
                for (int kk = 0; kk < 2; kk++)
                    acc[mi][ni] = __builtin_amdgcn_mfma_f32_16x16x32_bf16(
                        af[mi][kk], bf[ni][kk], acc[mi][ni], 0, 0, 0);
        __builtin_amdgcn_s_setprio(0);
        FENCE; __builtin_amdgcn_s_barrier(); FENCE;

        // ---- P2: stage B-h0(t+2) ----
        stageB(bb, 0, j2);
        FENCE; __builtin_amdgcn_s_barrier(); FENCE;
        __builtin_amdgcn_s_setprio(1);
        #pragma unroll
        for (int mi = 0; mi < 4; mi++)
            #pragma unroll
            for (int ni = 0; ni < 2; ni++)
                #pragma unroll
                for (int kk = 0; kk < 2; kk++)
                    acc[mi][ni + 2] = __builtin_amdgcn_mfma_f32_16x16x32_bf16(
                        af[mi][kk], bf[ni + 2][kk], acc[mi][ni + 2], 0, 0, 0);
        __builtin_amdgcn_s_setprio(0);
        FENCE; __builtin_amdgcn_s_barrier(); FENCE;

        // ---- P3: read A-m1 (8); stage B-h1(t+2) ----
        #pragma unroll
        for (int mi = 0; mi < 4; mi++)
            #pragma unroll
            for (int kk = 0; kk < 2; kk++)
                af[mi][kk] = *(const bf16x8*)&Ab[abase + (4 + mi) * 1024 + xk[kk]];
        stageB(bb, 1, j2);
        FENCE; __builtin_amdgcn_s_barrier(); FENCE;
        __builtin_amdgcn_s_setprio(1);
        #pragma unroll
        for (int mi = 0; mi < 4; mi++)
            #pragma unroll
            for (int ni = 0; ni < 2; ni++)
                #pragma unroll
                for (int kk = 0; kk < 2; kk++)
                    acc[mi + 4][ni + 2] = __builtin_amdgcn_mfma_f32_16x16x32_bf16(
                        af[mi][kk], bf[ni + 2][kk], acc[mi + 4][ni + 2], 0, 0, 0);
        __builtin_amdgcn_s_setprio(0);
        FENCE; __builtin_amdgcn_s_barrier(); FENCE;

        // ---- P4: stage A-h0(t+2); vmcnt(6) gate for tile t+1 ----
        stageA(bb, 0, j2);
        FENCE; __builtin_amdgcn_s_barrier(); FENCE;
        __builtin_amdgcn_s_setprio(1);
        #pragma unroll
        for (int mi = 0; mi < 4; mi++)
            #pragma unroll
            for (int ni = 0; ni < 2; ni++)
                #pragma unroll
                for (int kk = 0; kk < 2; kk++)
                    acc[mi + 4][ni] = __builtin_amdgcn_mfma_f32_16x16x32_bf16(
                        af[mi][kk], bf[ni][kk], acc[mi + 4][ni], 0, 0, 0);
        __builtin_amdgcn_s_setprio(0);
        asm volatile("s_waitcnt vmcnt(6)" ::: "memory");
        __builtin_amdgcn_sched_barrier(0);
        FENCE; __builtin_amdgcn_s_barrier(); FENCE;
    }
}

// Fused QKV on the 8-phase core. Grid (16, 12): ny<8 Q, 8-9 K, 10-11 V.
__global__ __launch_bounds__(512, 2) void gemm256_qkv(
    const unsigned short* __restrict__ Xb,
    const unsigned short* __restrict__ Wqkv,
    const unsigned short* __restrict__ T,
    const unsigned short* __restrict__ Bqkv,
    unsigned short* __restrict__ Qo, unsigned short* __restrict__ Ko,
    unsigned short* __restrict__ Vt)
{
    const int m0 = blockIdx.x * 256;
    const int n0 = blockIdx.y * 256;
    const unsigned short* Ts =
        T + ((n0 < 2048) ? 0 : (n0 < 2560) ? RLORA : 2 * RLORA);
    f32x4 acc[8][4] = {};
    gemm256_acc(Xb, DMODEL, m0, Wqkv, DMODEL, n0, Ts, 3 * RLORA, Bqkv,
                DMODEL, acc);

    const int tid = threadIdx.x, lane = tid & 63, wid = tid >> 6;
    const int l16 = lane & 15, quad = lane >> 4;
    const int wm0 = (wid >> 2) * 128, wn0 = (wid & 3) * 64;

    if (n0 < 2048) {
        #pragma unroll
        for (int mi = 0; mi < 8; mi++)
            #pragma unroll
            for (int ni = 0; ni < 4; ni++) {
                const int col = n0 + wn0 + ni * 16 + l16;
                const size_t rb = (size_t)(m0 + wm0 + mi * 16 + quad * 4);
                #pragma unroll
                for (int r = 0; r < 4; r++)
                    Qo[(rb + r) * DMODEL + col] = f2bf(acc[mi][ni][r]);
            }
    } else if (n0 < 2560) {
        #pragma unroll
        for (int mi = 0; mi < 8; mi++)
            #pragma unroll
            for (int ni = 0; ni < 4; ni++) {
                const int col = n0 - 2048 + wn0 + ni * 16 + l16;
                const size_t rb = (size_t)(m0 + wm0 + mi * 16 + quad * 4);
                #pragma unroll
                for (int r = 0; r < 4; r++)
                    Ko[(rb + r) * 512 + col] = f2bf(acc[mi][ni][r]);
            }
    } else {
        const int b = m0 >> 11;
        #pragma unroll
        for (int mi = 0; mi < 8; mi++)
            #pragma unroll
            for (int ni = 0; ni < 4; ni++) {
                const int ncol = n0 - 2560 + wn0 + ni * 16 + l16;
                const int head = ncol >> 7, dd = ncol & 127;
                const int srow = (m0 & (S_LEN - 1)) + wm0 + mi * 16 + quad * 4;
                uint2 pk;
                pk.x = pack2bf(acc[mi][ni][0], acc[mi][ni][1]);
                pk.y = pack2bf(acc[mi][ni][2], acc[mi][ni][3]);
                *(uint2*)(Vt + ((size_t)(b * NKVH + head) * HD + dd) * S_LEN + srow) = pk;
            }
    }
}

// Output projection on the 8-phase core. Grid (16, 8), fp32 out.
__global__ __launch_bounds__(512, 2) void gemm256_out(
    const unsigned short* __restrict__ Xb,
    const unsigned short* __restrict__ Ww,
    const unsigned short* __restrict__ T2,
    const unsigned short* __restrict__ Bl,
    float* __restrict__ Out)
{
    const int m0 = blockIdx.x * 256;
    const int n0 = blockIdx.y * 256;
    f32x4 acc[8][4] = {};
    gemm256_acc(Xb, DMODEL, m0, Ww, DMODEL, n0, T2, RLORA, Bl, DMODEL, acc);

    const int tid = threadIdx.x, lane = tid & 63, wid = tid >> 6;
    const int l16 = lane & 15, quad = lane >> 4;
    const int wm0 = (wid >> 2) * 128, wn0 = (wid & 3) * 64;
    #pragma unroll
    for (int mi = 0; mi < 8; mi++)
        #pragma unroll
        for (int ni = 0; ni < 4; ni++) {
            const int col = n0 + wn0 + ni * 16 + l16;
            const size_t rb = (size_t)(m0 + wm0 + mi * 16 + quad * 4);
            #pragma unroll
            for (int r = 0; r < 4; r++)
                Out[(rb + r) * DMODEL + col] = acc[mi][ni][r];
        }
}

// ---------------------------------------------------------------------------
// 128x128 2-barrier GEMM (kept for the small T = xb @ A^T LoRA projection).
// ---------------------------------------------------------------------------
template<int BM, int BN, bool OUTF>
__device__ __forceinline__ void gemm_core(
    const unsigned short* __restrict__ X, int ldx, int m0,
    const unsigned short* __restrict__ W, int ldw, int nrow0,
    void* __restrict__ Out, int ldo, int ocol0,
    int Kmain)
{
    constexpr int BK = 32;
    __shared__ __align__(16) unsigned short As[BM * BK];
    __shared__ __align__(16) unsigned short Bs[BN * BK];
    const int tid = threadIdx.x;
    const int lane = tid & 63;
    const int wid = tid >> 6;
    const int quad = lane >> 4;
    const int l16 = lane & 15;
    const int lr = lane >> 2;
    const int lc8 = (lane & 3) * 8;
    constexpr int TM = BM / 32;
    constexpr int TN = BN / 32;
    const int wm0 = (wid >> 1) * (BM / 2);
    const int wn0 = (wid & 1) * (BN / 2);

    f32x4 acc[TM][TN] = {};

    for (int k0 = 0; k0 < Kmain; k0 += BK) {
        #pragma unroll
        for (int c = 0; c < BM / 64; c++) {
            int chunk = wid * (BM / 64) + c;
            gld16(X + (size_t)(m0 + chunk * 16 + lr) * ldx + k0 + lc8,
                  As + chunk * 512);
        }
        #pragma unroll
        for (int c = 0; c < BN / 64; c++) {
            int chunk = wid * (BN / 64) + c;
            gld16(W + (size_t)(nrow0 + chunk * 16 + lr) * ldw + k0 + lc8,
                  Bs + chunk * 512);
        }
        __syncthreads();
        bf16x8 af[TM], bfr[TN];
        #pragma unroll
        for (int i = 0; i < TM; i++)
            af[i] = *(const bf16x8*)&As[(wm0 + i * 16 + l16) * BK + quad * 8];
        #pragma unroll
        for (int j = 0; j < TN; j++)
            bfr[j] = *(const bf16x8*)&Bs[(wn0 + j * 16 + l16) * BK + quad * 8];
        #pragma unroll
        for (int i = 0; i < TM; i++)
            #pragma unroll
            for (int j = 0; j < TN; j++)
                acc[i][j] = __builtin_amdgcn_mfma_f32_16x16x32_bf16(af[i], bfr[j], acc[i][j], 0, 0, 0);
        __syncthreads();
    }

    #pragma unroll
    for (int i = 0; i < TM; i++) {
        #pragma unroll
        for (int j = 0; j < TN; j++) {
            const int col = ocol0 + wn0 + j * 16 + l16;
            #pragma unroll
            for (int r = 0; r < 4; r++) {
                const size_t row = (size_t)(m0 + wm0 + i * 16 + quad * 4 + r);
                if (OUTF)
                    ((float*)Out)[row * ldo + col] = acc[i][j][r];
                else
                    ((unsigned short*)Out)[row * ldo + col] = f2bf(acc[i][j][r]);
            }
        }
    }
}

template<int BM, int BN, bool OUTF>
__global__ __launch_bounds__(256) void gemm_generic(
    const unsigned short* __restrict__ X, int ldx,
    const unsigned short* __restrict__ W, int ldw,
    void* __restrict__ Out, int ldo, int Kmain)
{
    gemm_core<BM, BN, OUTF>(X, ldx, blockIdx.x * BM, W, ldw, blockIdx.y * BN,
                            Out, ldo, blockIdx.y * BN, Kmain);
}

// ---------------------------------------------------------------------------
// RoPE, vectorized (validated r9).
// ---------------------------------------------------------------------------
__global__ __launch_bounds__(256) void rope_vec_k(
    unsigned short* __restrict__ Qb, unsigned short* __restrict__ Kb)
{
    int idx = blockIdx.x * 256 + threadIdx.x;
    const int npq = (B_ * S_LEN) * NH * 16;
    unsigned short* ptr;
    int m, tg;
    if (idx < npq) {
        tg = idx & 15;
        int h = (idx >> 4) & (NH - 1);
        m = idx >> 8;
        ptr = Qb + (size_t)m * (NH * HD) + h * HD + tg * 8;
    } else {
        idx -= npq;
        if (idx >= (B_ * S_LEN) * NKVH * 16) return;
        tg = idx & 15;
        int h = (idx >> 4) & (NKVH - 1);
        m = idx >> 6;
        ptr = Kb + (size_t)m * (NKVH * HD) + h * HD + tg * 8;
    }
    float pos = (float)(m & (S_LEN - 1));
    uint4 u = *(const uint4*)ptr;
    unsigned int w[4] = {u.x, u.y, u.z, u.w};
    #pragma unroll
    for (int j = 0; j < 4; j++) {
        int t = tg * 4 + j;
        float inv_freq = __expf(-(float)t * (13.815510557964274f / 64.0f));
        float ang = pos * inv_freq;
        float c, s;
        __sincosf(ang, &s, &c);
        float xr = __uint_as_float(w[j] << 16);
        float xi = __uint_as_float(w[j] & 0xffff0000u);
        w[j] = pack2bf(xr * c - xi * s, xr * s + xi * c);
    }
    *(uint4*)ptr = make_uint4(w[0], w[1], w[2], w[3]);
}

// ---------------------------------------------------------------------------
// MFMA flash attention v4 (R1): LDS-staged K/V shared by the whole block.
// (unchanged; ~47us est., left the top-5)
// ---------------------------------------------------------------------------
__global__ __launch_bounds__(256, 2) void attn_mfma(
    const unsigned short* __restrict__ Q,
    const unsigned short* __restrict__ K,
    const unsigned short* __restrict__ Vt,
    unsigned short* __restrict__ O)
{
    __shared__ __align__(16) unsigned short kvbuf[2][8192];
    __shared__ unsigned short plds[4][32 * 40];
    const int tid = threadIdx.x, lane = tid & 63, wid = tid >> 6;
    const int l16 = lane & 15, quad = lane >> 4;
    const int bid = blockIdx.x;
    const int g   = bid & 7;
    const int kvh = g & 3;
    const int b   = g >> 2;
    const int qt  = 63 - (bid >> 3);
    const int q0  = qt * 32;
    const int h   = kvh * 4 + wid;

    const unsigned short* qrow0 = Q + ((size_t)(b * S_LEN + q0 + l16)) * DMODEL + h * HD;
    bf16x8 qf0[4], qf1[4];
    #pragma unroll
    for (int c = 0; c < 4; c++) {
        qf0[c] = *(const bf16x8*)(qrow0 + c * 32 + quad * 8);
        qf1[c] = *(const bf16x8*)(qrow0 + (size_t)16 * DMODEL + c * 32 + quad * 8);
    }

    const unsigned short* Kbase  = K + ((size_t)(b * S_LEN)) * (NKVH * HD) + kvh * HD;
    const unsigned short* Vplane = Vt + ((size_t)(b * NKVH + kvh) * HD) * S_LEN;
    unsigned short* pw = &plds[wid][0];

    const unsigned short* Ksrc[2];
    const unsigned short* Vsrc[2];
    #pragma unroll
    for (int c = 0; c < 2; c++) {
        const int o = wid * 2048 + c * 1024 + lane * 16;
        const int kkey = o >> 8;
        const int kdim = (o & 255) ^ ((kkey & 15) << 4);
        Ksrc[c] = Kbase + (size_t)kkey * (NKVH * HD) + (kdim >> 1);
        const int vd = o >> 6;
        const int vkb = (o & 63) ^ ((vd & 3) << 4);
        Vsrc[c] = Vplane + (size_t)vd * S_LEN + (vkb >> 1);
    }

    f32x4 oacc0[8] = {}, oacc1[8] = {};
    f32x4 lrow0 = {0.f, 0.f, 0.f, 0.f}, lrow1 = {0.f, 0.f, 0.f, 0.f};
    const float c2 = 0.12753102f;

    const int kthi = (q0 + 31) >> 5;
    int wlo = q0 - (WINDOW_ - 1); if (wlo < 0) wlo = 0;
    const int ktw = wlo >> 5;

    auto nexttile = [&](int t) -> int {
        if (t < ktw) { int u = t + 1; return (u < 2 && u < ktw) ? u : ktw; }
        return t + 1;
    };

    auto stage = [&](int buf, int ktb) {
        #pragma unroll
        for (int c = 0; c < 2; c++) {
            gld16(Ksrc[c] + (size_t)ktb * (NKVH * HD),
                  &kvbuf[buf][wid * 1024 + c * 512]);
            gld16(Vsrc[c] + ktb,
                  &kvbuf[buf][4096 + wid * 1024 + c * 512]);
        }
    };

    int kt = 0;
    stage(0, 0);
    __syncthreads();
    int cur = 0;

    while (true) {
        const int ktb = kt * 32;
        const int ktn = nexttile(kt);
        const bool last = (ktn > kthi);
        if (!last) stage(cur ^ 1, ktn * 32);

        const unsigned short* kb  = kvbuf[cur];
        const unsigned short* vbp = kvbuf[cur] + 4096;

        bf16x8 kf0[4], kf1[4];
        #pragma unroll
        for (int c = 0; c < 4; c++) {
            const int koff = (l16 * 256 + ((c * 64 + quad * 16) ^ (l16 << 4))) >> 1;
            kf0[c] = *(const bf16x8*)&kb[koff];
            kf1[c] = *(const bf16x8*)&kb[koff + 2048];
        }

        f32x4 s00 = {}, s01 = {}, s10 = {}, s11 = {};
        __builtin_amdgcn_s_setprio(1);
        #pragma unroll
        for (int c = 0; c < 4; c++) {
            s00 = __builtin_amdgcn_mfma_f32_16x16x32_bf16(qf0[c], kf0[c], s00, 0, 0, 0);
            s01 = __builtin_amdgcn_mfma_f32_16x16x32_bf16(qf0[c], kf1[c], s01, 0, 0, 0);
            s10 = __builtin_amdgcn_mfma_f32_16x16x32_bf16(qf1[c], kf0[c], s10, 0, 0, 0);
            s11 = __builtin_amdgcn_mfma_f32_16x16x32_bf16(qf1[c], kf1[c], s11, 0, 0, 0);
        }
        __builtin_amdgcn_s_setprio(0);

        #pragma unroll
        for (int s = 0; s < 2; s++) {
            const f32x4 sa0 = s ? s10 : s00;
            const f32x4 sa1 = s ? s11 : s01;
            const int qs = q0 + s * 16;
            const bool full = (ktb + 31 <= qs) &&
                              (((qs + 15) - ktb < WINDOW_) || (ktb + 31 < NGLOBAL));
            f32x4& lr = s ? lrow1 : lrow0;
            #pragma unroll
            for (int rr = 0; rr < 4; rr++) {
                float p0 = exp2f(sa0[rr] * c2);
                float p1 = exp2f(sa1[rr] * c2);
                if (!full) {
                    const int i = qs + quad * 4 + rr;
                    const int j0 = ktb + l16, j1 = j0 + 16;
                    bool a0 = (j0 <= i) && ((i - j0 < WINDOW_) || (j0 < NGLOBAL));
                    bool a1 = (j1 <= i) && ((i - j1 < WINDOW_) || (j1 < NGLOBAL));
                    p0 = a0 ? p0 : 0.f;
                    p1 = a1 ? p1 : 0.f;
                }
                lr[rr] += p0 + p1;
                pw[(s * 16 + quad * 4 + rr) * 40 + l16]      = f2bf(p0);
                pw[(s * 16 + quad * 4 + rr) * 40 + 16 + l16] = f2bf(p1);
            }
        }
        bf16x8 pa0 = *(const bf16x8*)(pw + l16 * 40 + quad * 8);
        bf16x8 pa1 = *(const bf16x8*)(pw + (16 + l16) * 40 + quad * 8);

        {
            bf16x8 va[4];
            #pragma unroll
            for (int ds = 0; ds < 4; ds++) {
                const int d = ds * 16 + l16;
                va[ds] = *(const bf16x8*)&vbp[(d * 64 + ((quad * 16) ^ ((l16 & 3) << 4))) >> 1];
            }
            __builtin_amdgcn_s_setprio(1);
            #pragma unroll
            for (int ds = 0; ds < 4; ds++) {
                oacc0[ds] = __builtin_amdgcn_mfma_f32_16x16x32_bf16(pa0, va[ds], oacc0[ds], 0, 0, 0);
                oacc1[ds] = __builtin_amdgcn_mfma_f32_16x16x32_bf16(pa1, va[ds], oacc1[ds], 0, 0, 0);
            }
            __builtin_amdgcn_s_setprio(0);
        }
        {
            bf16x8 vb[4];
            #pragma unroll
            for (int ds = 0; ds < 4; ds++) {
                const int d = (ds + 4) * 16 + l16;
                vb[ds] = *(const bf16x8*)&vbp[(d * 64 + ((quad * 16) ^ ((l16 & 3) << 4))) >> 1];
            }
            __builtin_amdgcn_s_setprio(1);
            #pragma unroll
            for (int ds = 0; ds < 4; ds++) {
                oacc0[ds + 4] = __builtin_amdgcn_mfma_f32_16x16x32_bf16(pa0, vb[ds], oacc0[ds + 4], 0, 0, 0);
                oacc1[ds + 4] = __builtin_amdgcn_mfma_f32_16x16x32_bf16(pa1, vb[ds], oacc1[ds + 4], 0, 0, 0);
            }
            __builtin_amdgcn_s_setprio(0);
        }

        if (last) break;
        __syncthreads();
        cur ^= 1;
        kt = ktn;
    }

    #pragma unroll
    for (int off = 1; off <= 8; off <<= 1) {
        #pragma unroll
        for (int rr = 0; rr < 4; rr++) {
            lrow0[rr] += __shfl_xor(lrow0[rr], off);
            lrow1[rr] += __shfl_xor(lrow1[rr], off);
        }
    }

    #pragma unroll
    for (int s = 0; s < 2; s++) {
        const f32x4& lr = s ? lrow1 : lrow0;
        #pragma unroll
        for (int rr = 0; rr < 4; rr++) {
            float inv = 1.f / lr[rr];
            unsigned short* orow = O + ((size_t)(b * S_LEN + q0 + s * 16 + quad * 4 + rr)) * DMODEL + h * HD;
            #pragma unroll
            for (int ds = 0; ds < 8; ds++) {
                float v = s ? oacc1[ds][rr] : oacc0[ds][rr];
                orow[ds * 16 + l16] = f2bf(v * inv);
            }
        }
    }
}

// ---------------------------------------------------------------------------
extern "C" void kernel_launch(void* const* d_in, const int* in_sizes, int n_in,
                              void* d_out, int out_size, void* d_ws, size_t ws_size,
                              hipStream_t stream)
{
    const float* x    = (const float*)d_in[0];
    const float* wq_w = (const float*)d_in[1];
    const float* wq_a = (const float*)d_in[2];
    const float* wq_b = (const float*)d_in[3];
    const float* wk_w = (const float*)d_in[4];
    const float* wk_a = (const float*)d_in[5];
    const float* wk_b = (const float*)d_in[6];
    const float* wv_w = (const float*)d_in[7];
    const float* wv_a = (const float*)d_in[8];
    const float* wv_b = (const float*)d_in[9];
    const float* wo_w = (const float*)d_in[10];
    const float* wo_a = (const float*)d_in[11];
    const float* wo_b = (const float*)d_in[12];

    char* ws = (char*)d_ws;
    unsigned short* wqkvb = (unsigned short*)(ws);
    unsigned short* apack = (unsigned short*)(ws + 12582912);
    unsigned short* bqkvb = (unsigned short*)(ws + 14155776);
    unsigned short* Tbuf  = (unsigned short*)(ws + 14942208);
    unsigned short* Qbuf  = (unsigned short*)(ws + 18087936);
    unsigned short* Kbuf  = (unsigned short*)(ws + 34865152);
    unsigned short* Vtbuf = (unsigned short*)(ws + 39059456);
    unsigned short* wowb  = (unsigned short*)(ws);
    unsigned short* woab  = (unsigned short*)(ws + 8388608);
    unsigned short* wobb  = (unsigned short*)(ws + 8912896);
    unsigned short* T2buf = Tbuf;
    unsigned short* xb = (unsigned short*)d_out;

    // conv1: x + QKV/LoRA weights -> bf16
    Conv12 c1;
    c1.s[0]  = x;    c1.d[0]  = xb;
    c1.s[1]  = wq_w; c1.d[1]  = wqkvb;
    c1.s[2]  = wk_w; c1.d[2]  = wqkvb + 2048 * 2048;
    c1.s[3]  = wv_w; c1.d[3]  = wqkvb + 2560 * 2048;
    c1.s[4]  = wq_a; c1.d[4]  = apack;
    c1.s[5]  = wk_a; c1.d[5]  = apack + 128 * 2048;
    c1.s[6]  = wv_a; c1.d[6]  = apack + 256 * 2048;
    c1.s[7]  = wq_b; c1.d[7]  = bqkvb;
    c1.s[8]  = wk_b; c1.d[8]  = bqkvb + 2048 * 128;
    c1.s[9]  = wv_b; c1.d[9]  = bqkvb + 2560 * 128;
    c1.s[10] = wv_b; c1.d[10] = bqkvb + 2560 * 128;
    c1.s[11] = wv_b; c1.d[11] = bqkvb + 2560 * 128;
    int cum1[13] = {0, 4096, 6144, 6656, 7168, 7296, 7424, 7552, 7680, 7712,
                    7744, 7744, 7744};
    for (int i = 0; i < 13; i++) c1.c[i] = cum1[i];
    convk<<<dim3(7744), dim3(256), 0, stream>>>(c1);

    // T = xb @ apack^T  (LoRA intermediate, N=384)
    gemm_generic<128, 128, false><<<dim3(32, 3), dim3(256), 0, stream>>>(
        xb, DMODEL, apack, DMODEL, Tbuf, 3 * RLORA, DMODEL);

    // Q/K/V (V transposed into Vt) - 8-phase 256^2 core
    gemm256_qkv<<<dim3(16, 12), dim3(512), 0, stream>>>(
        xb, wqkvb, Tbuf, bqkvb, Qbuf, Kbuf, Vtbuf);

    // conv2: output-proj weights -> bf16
    Conv12 c2;
    c2.s[0] = wo_w; c2.d[0] = wowb;
    c2.s[1] = wo_a; c2.d[1] = woab;
    c2.s[2] = wo_b; c2.d[2] = wobb;
    for (int i = 3; i < 12; i++) { c2.s[i] = wo_b; c2.d[i] = wobb; }
    int cum2[13] = {0, 2048, 2176, 2304, 2304, 2304, 2304, 2304, 2304, 2304,
                    2304, 2304, 2304};
    for (int i = 0; i < 13; i++) c2.c[i] = cum2[i];
    convk<<<dim3(2304), dim3(256), 0, stream>>>(c2);

    rope_vec_k<<<dim3(5120), dim3(256), 0, stream>>>(Qbuf, Kbuf);

    attn_mfma<<<dim3(512), dim3(256), 0, stream>>>(Qbuf, Kbuf, Vtbuf, Qbuf);

    // T2 = attn_out @ woab^T  (N=128)
    gemm_generic<128, 128, false><<<dim3(32, 1), dim3(256), 0, stream>>>(
        Qbuf, DMODEL, woab, DMODEL, T2buf, RLORA, DMODEL);

    // final: out = attn_out @ wowb^T + T2 @ wobb^T  (fp32) - 8-phase core
    gemm256_out<<<dim3(16, 8), dim3(512), 0, stream>>>(
        Qbuf, wowb, T2buf, wobb, (float*)d_out);
}

// Round 6
// 391.646 us; speedup vs baseline: 1.0615x; 1.0615x over previous
//
#include <hip/hip_runtime.h>

#define B_ 2
#define S_LEN 2048
#define DMODEL 2048
#define NH 16
#define NKVH 4
#define HD 128
#define RLORA 128
#define WINDOW_ 512
#define NGLOBAL 64

#define FENCE asm volatile("" ::: "memory")

typedef __bf16 bf16x8 __attribute__((ext_vector_type(8)));
typedef float f32x4 __attribute__((ext_vector_type(4)));

__device__ __forceinline__ float bf2f(unsigned short h) {
    return __uint_as_float(((unsigned int)h) << 16);
}
__device__ __forceinline__ unsigned short f2bf(float f) {
    unsigned int u = __float_as_uint(f);
    unsigned int r = u + 0x7fffu + ((u >> 16) & 1u);
    return (unsigned short)(r >> 16);
}
__device__ __forceinline__ unsigned int pack2bf(float a, float b) {
    return (unsigned int)f2bf(a) | ((unsigned int)f2bf(b) << 16);
}
__device__ __forceinline__ uint4 load8f(const float* p) {
    float4 f0 = *(const float4*)p;
    float4 f1 = *(const float4*)(p + 4);
    uint4 u;
    u.x = pack2bf(f0.x, f0.y);
    u.y = pack2bf(f0.z, f0.w);
    u.z = pack2bf(f1.x, f1.y);
    u.w = pack2bf(f1.z, f1.w);
    return u;
}

// Async global->LDS, 16 B per lane. LDS dest = wave-uniform base + lane*16.
__device__ __forceinline__ void gld16(const unsigned short* g, unsigned short* l) {
    __builtin_amdgcn_global_load_lds(
        (const __attribute__((address_space(1))) unsigned int*)g,
        (__attribute__((address_space(3))) unsigned int*)l,
        16, 0, 0);
}

// ---------------------------------------------------------------------------
// Batched fp32 -> bf16 conversion over up to 12 tensors. 2048 elems/block.
// ---------------------------------------------------------------------------
struct Conv12 {
    const float* s[12];
    unsigned short* d[12];
    int c[13];
};
__global__ __launch_bounds__(256) void convk(Conv12 a)
{
    int b = blockIdx.x;
    int seg = 0;
    while (b >= a.c[seg + 1]) seg++;
    int off = (b - a.c[seg]) * 2048 + threadIdx.x * 8;
    *(uint4*)(a.d[seg] + off) = load8f(a.s[seg] + off);
}

// ---------------------------------------------------------------------------
// R5 GEMM core (resubmitted R6 unchanged after infra failure): BM=128,
// BN=256, BK=32, 8 waves (2Mx4N -> wave 64x64), 48 KiB LDS dbuf ->
// 2 blocks/CU (TLP hides barrier/latency residue, m114).
// One phase per K-tile: {vmcnt(3) counted; bar; 8 ds_read_b128; 16 MFMA
// (setprio); bar; stage(t+2)}. 2-deep prefetch, vmcnt never 0 in-loop.
// Swizzle both-sides: linear LDS dest, global src byte^((row&3)<<4) within
// 64B rows; same XOR on read -> 2-way bank aliasing (free).
// LoRA tail merged: nt = Kmain/32 + 4.
// Layouts (validated): A-frag lane=A[m=l16][k=quad*8+j]; B-frag
// lane=B[k][n=l16]; C/D col=l16, row=quad*4+r.
// vmcnt ledger (3 loads/thread/stage): steady-state outstanding at wait =
// {t:3, t+1:3} -> vmcnt(3) retires tile t exactly; tail t=nt-1 drains 0.
// ---------------------------------------------------------------------------
__device__ __forceinline__ void gemm128_acc(
    const unsigned short* __restrict__ A, int lda, int m0,
    const unsigned short* __restrict__ W, int ldw, int n0,
    const unsigned short* __restrict__ TA, int ldt,
    const unsigned short* __restrict__ BL,
    int Kmain, f32x4 (&acc)[4][4])
{
    __shared__ __align__(16) unsigned short As[2][128 * 32];
    __shared__ __align__(16) unsigned short Bs[2][256 * 32];
    const int tid = threadIdx.x;
    const int lane = tid & 63, wid = tid >> 6;
    const int quad = lane >> 4, l16 = lane & 15;
    const int wm = (wid >> 2) * 64, wn = (wid & 3) * 64;

    // staging source map: LDS linear; src col pre-swizzled (involution).
    const int arow = tid >> 2;                                  // 0..127
    const int acol = (((tid & 3) * 16) ^ ((arow & 3) << 4)) >> 1; // shorts

    const int ntm = Kmain >> 5;
    const int nt = ntm + 4;

    auto stage = [&](int bb, int j) {
        const unsigned short* sa;
        const unsigned short* sb;
        int la, lb, k0;
        if (j < ntm) { sa = A + (size_t)m0 * lda;  la = lda;
                       sb = W + (size_t)n0 * ldw;  lb = ldw;  k0 = j << 5; }
        else         { sa = TA + (size_t)m0 * ldt; la = ldt;
                       sb = BL + (size_t)n0 * RLORA; lb = RLORA;
                       k0 = (j - ntm) << 5; }
        gld16(sa + (size_t)arow * la + k0 + acol, &As[bb][tid * 8]);
        gld16(sb + (size_t)arow * lb + k0 + acol, &Bs[bb][tid * 8]);
        gld16(sb + (size_t)(arow + 128) * lb + k0 + acol, &Bs[bb][tid * 8 + 4096]);
    };

    // fragment read offset (shorts): slot XOR with row&3 (= l16&3).
    const int xoff = (((quad * 16) ^ ((l16 & 3) << 4)) >> 1);
    const int ard = (wm + l16) * 32 + xoff;
    const int brd = (wn + l16) * 32 + xoff;

    stage(0, 0);
    stage(1, 1);

    for (int t = 0; t < nt; t++) {
        const int bb = t & 1;
        if (t < nt - 1) {
            asm volatile("s_waitcnt vmcnt(3)" ::: "memory");
        } else {
            asm volatile("s_waitcnt vmcnt(0)" ::: "memory");
        }
        __builtin_amdgcn_sched_barrier(0);
        FENCE; __builtin_amdgcn_s_barrier(); FENCE;

        bf16x8 af[4], bfn[4];
        #pragma unroll
        for (int mi = 0; mi < 4; mi++)
            af[mi] = *(const bf16x8*)&As[bb][ard + mi * 512];
        #pragma unroll
        for (int ni = 0; ni < 4; ni++)
            bfn[ni] = *(const bf16x8*)&Bs[bb][brd + ni * 512];

        __builtin_amdgcn_s_setprio(1);
        #pragma unroll
        for (int mi = 0; mi < 4; mi++)
            #pragma unroll
            for (int ni = 0; ni < 4; ni++)
                acc[mi][ni] = __builtin_amdgcn_mfma_f32_16x16x32_bf16(
                    af[mi], bfn[ni], acc[mi][ni], 0, 0, 0);
        __builtin_amdgcn_s_setprio(0);

        FENCE; __builtin_amdgcn_s_barrier(); FENCE;
        if (t + 2 < nt) stage(bb, t + 2);
    }
}

// Fused QKV on the R5 core. Grid (32, 12): by<8 Q, 8-9 K, 10-11 V.
__global__ __launch_bounds__(512, 4) void gemm128_qkv(
    const unsigned short* __restrict__ Xb,
    const unsigned short* __restrict__ Wqkv,
    const unsigned short* __restrict__ T,
    const unsigned short* __restrict__ Bqkv,
    unsigned short* __restrict__ Qo, unsigned short* __restrict__ Ko,
    unsigned short* __restrict__ Vt)
{
    const int m0 = blockIdx.x * 128;
    const int n0 = blockIdx.y * 256;
    const unsigned short* Ts =
        T + ((n0 < 2048) ? 0 : (n0 < 2560) ? RLORA : 2 * RLORA);
    f32x4 acc[4][4] = {};
    gemm128_acc(Xb, DMODEL, m0, Wqkv, DMODEL, n0, Ts, 3 * RLORA, Bqkv,
                DMODEL, acc);

    const int tid = threadIdx.x, lane = tid & 63, wid = tid >> 6;
    const int l16 = lane & 15, quad = lane >> 4;
    const int wm = (wid >> 2) * 64, wn = (wid & 3) * 64;

    if (n0 < 2048) {
        #pragma unroll
        for (int mi = 0; mi < 4; mi++)
            #pragma unroll
            for (int ni = 0; ni < 4; ni++) {
                const int col = n0 + wn + ni * 16 + l16;
                const size_t rb = (size_t)(m0 + wm + mi * 16 + quad * 4);
                #pragma unroll
                for (int r = 0; r < 4; r++)
                    Qo[(rb + r) * DMODEL + col] = f2bf(acc[mi][ni][r]);
            }
    } else if (n0 < 2560) {
        #pragma unroll
        for (int mi = 0; mi < 4; mi++)
            #pragma unroll
            for (int ni = 0; ni < 4; ni++) {
                const int col = n0 - 2048 + wn + ni * 16 + l16;
                const size_t rb = (size_t)(m0 + wm + mi * 16 + quad * 4);
                #pragma unroll
                for (int r = 0; r < 4; r++)
                    Ko[(rb + r) * 512 + col] = f2bf(acc[mi][ni][r]);
            }
    } else {
        const int b = m0 >> 11;
        #pragma unroll
        for (int mi = 0; mi < 4; mi++)
            #pragma unroll
            for (int ni = 0; ni < 4; ni++) {
                const int ncol = n0 - 2560 + wn + ni * 16 + l16;
                const int head = ncol >> 7, dd = ncol & 127;
                const int srow = (m0 & (S_LEN - 1)) + wm + mi * 16 + quad * 4;
                uint2 pk;
                pk.x = pack2bf(acc[mi][ni][0], acc[mi][ni][1]);
                pk.y = pack2bf(acc[mi][ni][2], acc[mi][ni][3]);
                *(uint2*)(Vt + ((size_t)(b * NKVH + head) * HD + dd) * S_LEN + srow) = pk;
            }
    }
}

// Output projection on the R5 core. Grid (32, 8) = 256 blocks, fp32 out.
__global__ __launch_bounds__(512, 4) void gemm128_out(
    const unsigned short* __restrict__ Xb,
    const unsigned short* __restrict__ Ww,
    const unsigned short* __restrict__ T2,
    const unsigned short* __restrict__ Bl,
    float* __restrict__ Out)
{
    const int m0 = blockIdx.x * 128;
    const int n0 = blockIdx.y * 256;
    f32x4 acc[4][4] = {};
    gemm128_acc(Xb, DMODEL, m0, Ww, DMODEL, n0, T2, RLORA, Bl, DMODEL, acc);

    const int tid = threadIdx.x, lane = tid & 63, wid = tid >> 6;
    const int l16 = lane & 15, quad = lane >> 4;
    const int wm = (wid >> 2) * 64, wn = (wid & 3) * 64;
    #pragma unroll
    for (int mi = 0; mi < 4; mi++)
        #pragma unroll
        for (int ni = 0; ni < 4; ni++) {
            const int col = n0 + wn + ni * 16 + l16;
            const size_t rb = (size_t)(m0 + wm + mi * 16 + quad * 4);
            #pragma unroll
            for (int r = 0; r < 4; r++)
                Out[(rb + r) * DMODEL + col] = acc[mi][ni][r];
        }
}

// ---------------------------------------------------------------------------
// 128x128 2-barrier GEMM (small T / T2 LoRA projections).
// ---------------------------------------------------------------------------
template<int BM, int BN, bool OUTF>
__device__ __forceinline__ void gemm_core(
    const unsigned short* __restrict__ X, int ldx, int m0,
    const unsigned short* __restrict__ W, int ldw, int nrow0,
    void* __restrict__ Out, int ldo, int ocol0,
    int Kmain)
{
    constexpr int BK = 32;
    __shared__ __align__(16) unsigned short As[BM * BK];
    __shared__ __align__(16) unsigned short Bs[BN * BK];
    const int tid = threadIdx.x;
    const int lane = tid & 63;
    const int wid = tid >> 6;
    const int quad = lane >> 4;
    const int l16 = lane & 15;
    const int lr = lane >> 2;
    const int lc8 = (lane & 3) * 8;
    constexpr int TM = BM / 32;
    constexpr int TN = BN / 32;
    const int wm0 = (wid >> 1) * (BM / 2);
    const int wn0 = (wid & 1) * (BN / 2);

    f32x4 acc[TM][TN] = {};

    for (int k0 = 0; k0 < Kmain; k0 += BK) {
        #pragma unroll
        for (int c = 0; c < BM / 64; c++) {
            int chunk = wid * (BM / 64) + c;
            gld16(X + (size_t)(m0 + chunk * 16 + lr) * ldx + k0 + lc8,
                  As + chunk * 512);
        }
        #pragma unroll
        for (int c = 0; c < BN / 64; c++) {
            int chunk = wid * (BN / 64) + c;
            gld16(W + (size_t)(nrow0 + chunk * 16 + lr) * ldw + k0 + lc8,
                  Bs + chunk * 512);
        }
        __syncthreads();
        bf16x8 af[TM], bfr[TN];
        #pragma unroll
        for (int i = 0; i < TM; i++)
            af[i] = *(const bf16x8*)&As[(wm0 + i * 16 + l16) * BK + quad * 8];
        #pragma unroll
        for (int j = 0; j < TN; j++)
            bfr[j] = *(const bf16x8*)&Bs[(wn0 + j * 16 + l16) * BK + quad * 8];
        #pragma unroll
        for (int i = 0; i < TM; i++)
            #pragma unroll
            for (int j = 0; j < TN; j++)
                acc[i][j] = __builtin_amdgcn_mfma_f32_16x16x32_bf16(af[i], bfr[j], acc[i][j], 0, 0, 0);
        __syncthreads();
    }

    #pragma unroll
    for (int i = 0; i < TM; i++) {
        #pragma unroll
        for (int j = 0; j < TN; j++) {
            const int col = ocol0 + wn0 + j * 16 + l16;
            #pragma unroll
            for (int r = 0; r < 4; r++) {
                const size_t row = (size_t)(m0 + wm0 + i * 16 + quad * 4 + r);
                if (OUTF)
                    ((float*)Out)[row * ldo + col] = acc[i][j][r];
                else
                    ((unsigned short*)Out)[row * ldo + col] = f2bf(acc[i][j][r]);
            }
        }
    }
}

template<int BM, int BN, bool OUTF>
__global__ __launch_bounds__(256) void gemm_generic(
    const unsigned short* __restrict__ X, int ldx,
    const unsigned short* __restrict__ W, int ldw,
    void* __restrict__ Out, int ldo, int Kmain)
{
    gemm_core<BM, BN, OUTF>(X, ldx, blockIdx.x * BM, W, ldw, blockIdx.y * BN,
                            Out, ldo, blockIdx.y * BN, Kmain);
}

// ---------------------------------------------------------------------------
// RoPE, vectorized (validated r9).
// ---------------------------------------------------------------------------
__global__ __launch_bounds__(256) void rope_vec_k(
    unsigned short* __restrict__ Qb, unsigned short* __restrict__ Kb)
{
    int idx = blockIdx.x * 256 + threadIdx.x;
    const int npq = (B_ * S_LEN) * NH * 16;
    unsigned short* ptr;
    int m, tg;
    if (idx < npq) {
        tg = idx & 15;
        int h = (idx >> 4) & (NH - 1);
        m = idx >> 8;
        ptr = Qb + (size_t)m * (NH * HD) + h * HD + tg * 8;
    } else {
        idx -= npq;
        if (idx >= (B_ * S_LEN) * NKVH * 16) return;
        tg = idx & 15;
        int h = (idx >> 4) & (NKVH - 1);
        m = idx >> 6;
        ptr = Kb + (size_t)m * (NKVH * HD) + h * HD + tg * 8;
    }
    float pos = (float)(m & (S_LEN - 1));
    uint4 u = *(const uint4*)ptr;
    unsigned int w[4] = {u.x, u.y, u.z, u.w};
    #pragma unroll
    for (int j = 0; j < 4; j++) {
        int t = tg * 4 + j;
        float inv_freq = __expf(-(float)t * (13.815510557964274f / 64.0f));
        float ang = pos * inv_freq;
        float c, s;
        __sincosf(ang, &s, &c);
        float xr = __uint_as_float(w[j] << 16);
        float xi = __uint_as_float(w[j] & 0xffff0000u);
        w[j] = pack2bf(xr * c - xi * s, xr * s + xi * c);
    }
    *(uint4*)ptr = make_uint4(w[0], w[1], w[2], w[3]);
}

// ---------------------------------------------------------------------------
// MFMA flash attention v4 (R1): LDS-staged K/V shared by the whole block.
// ---------------------------------------------------------------------------
__global__ __launch_bounds__(256, 2) void attn_mfma(
    const unsigned short* __restrict__ Q,
    const unsigned short* __restrict__ K,
    const unsigned short* __restrict__ Vt,
    unsigned short* __restrict__ O)
{
    __shared__ __align__(16) unsigned short kvbuf[2][8192];
    __shared__ unsigned short plds[4][32 * 40];
    const int tid = threadIdx.x, lane = tid & 63, wid = tid >> 6;
    const int l16 = lane & 15, quad = lane >> 4;
    const int bid = blockIdx.x;
    const int g   = bid & 7;
    const int kvh = g & 3;
    const int b   = g >> 2;
    const int qt  = 63 - (bid >> 3);
    const int q0  = qt * 32;
    const int h   = kvh * 4 + wid;

    const unsigned short* qrow0 = Q + ((size_t)(b * S_LEN + q0 + l16)) * DMODEL + h * HD;
    bf16x8 qf0[4], qf1[4];
    #pragma unroll
    for (int c = 0; c < 4; c++) {
        qf0[c] = *(const bf16x8*)(qrow0 + c * 32 + quad * 8);
        qf1[c] = *(const bf16x8*)(qrow0 + (size_t)16 * DMODEL + c * 32 + quad * 8);
    }

    const unsigned short* Kbase  = K + ((size_t)(b * S_LEN)) * (NKVH * HD) + kvh * HD;
    const unsigned short* Vplane = Vt + ((size_t)(b * NKVH + kvh) * HD) * S_LEN;
    unsigned short* pw = &plds[wid][0];

    const unsigned short* Ksrc[2];
    const unsigned short* Vsrc[2];
    #pragma unroll
    for (int c = 0; c < 2; c++) {
        const int o = wid * 2048 + c * 1024 + lane * 16;
        const int kkey = o >> 8;
        const int kdim = (o & 255) ^ ((kkey & 15) << 4);
        Ksrc[c] = Kbase + (size_t)kkey * (NKVH * HD) + (kdim >> 1);
        const int vd = o >> 6;
        const int vkb = (o & 63) ^ ((vd & 3) << 4);
        Vsrc[c] = Vplane + (size_t)vd * S_LEN + (vkb >> 1);
    }

    f32x4 oacc0[8] = {}, oacc1[8] = {};
    f32x4 lrow0 = {0.f, 0.f, 0.f, 0.f}, lrow1 = {0.f, 0.f, 0.f, 0.f};
    const float c2 = 0.12753102f;

    const int kthi = (q0 + 31) >> 5;
    int wlo = q0 - (WINDOW_ - 1); if (wlo < 0) wlo = 0;
    const int ktw = wlo >> 5;

    auto nexttile = [&](int t) -> int {
        if (t < ktw) { int u = t + 1; return (u < 2 && u < ktw) ? u : ktw; }
        return t + 1;
    };

    auto stage = [&](int buf, int ktb) {
        #pragma unroll
        for (int c = 0; c < 2; c++) {
            gld16(Ksrc[c] + (size_t)ktb * (NKVH * HD),
                  &kvbuf[buf][wid * 1024 + c * 512]);
            gld16(Vsrc[c] + ktb,
                  &kvbuf[buf][4096 + wid * 1024 + c * 512]);
        }
    };

    int kt = 0;
    stage(0, 0);
    __syncthreads();
    int cur = 0;

    while (true) {
        const int ktb = kt * 32;
        const int ktn = nexttile(kt);
        const bool last = (ktn > kthi);
        if (!last) stage(cur ^ 1, ktn * 32);

        const unsigned short* kb  = kvbuf[cur];
        const unsigned short* vbp = kvbuf[cur] + 4096;

        bf16x8 kf0[4], kf1[4];
        #pragma unroll
        for (int c = 0; c < 4; c++) {
            const int koff = (l16 * 256 + ((c * 64 + quad * 16) ^ (l16 << 4))) >> 1;
            kf0[c] = *(const bf16x8*)&kb[koff];
            kf1[c] = *(const bf16x8*)&kb[koff + 2048];
        }

        f32x4 s00 = {}, s01 = {}, s10 = {}, s11 = {};
        __builtin_amdgcn_s_setprio(1);
        #pragma unroll
        for (int c = 0; c < 4; c++) {
            s00 = __builtin_amdgcn_mfma_f32_16x16x32_bf16(qf0[c], kf0[c], s00, 0, 0, 0);
            s01 = __builtin_amdgcn_mfma_f32_16x16x32_bf16(qf0[c], kf1[c], s01, 0, 0, 0);
            s10 = __builtin_amdgcn_mfma_f32_16x16x32_bf16(qf1[c], kf0[c], s10, 0, 0, 0);
            s11 = __builtin_amdgcn_mfma_f32_16x16x32_bf16(qf1[c], kf1[c], s11, 0, 0, 0);
        }
        __builtin_amdgcn_s_setprio(0);

        #pragma unroll
        for (int s = 0; s < 2; s++) {
            const f32x4 sa0 = s ? s10 : s00;
            const f32x4 sa1 = s ? s11 : s01;
            const int qs = q0 + s * 16;
            const bool full = (ktb + 31 <= qs) &&
                              (((qs + 15) - ktb < WINDOW_) || (ktb + 31 < NGLOBAL));
            f32x4& lr = s ? lrow1 : lrow0;
            #pragma unroll
            for (int rr = 0; rr < 4; rr++) {
                float p0 = exp2f(sa0[rr] * c2);
                float p1 = exp2f(sa1[rr] * c2);
                if (!full) {
                    const int i = qs + quad * 4 + rr;
                    const int j0 = ktb + l16, j1 = j0 + 16;
                    bool a0 = (j0 <= i) && ((i - j0 < WINDOW_) || (j0 < NGLOBAL));
                    bool a1 = (j1 <= i) && ((i - j1 < WINDOW_) || (j1 < NGLOBAL));
                    p0 = a0 ? p0 : 0.f;
                    p1 = a1 ? p1 : 0.f;
                }
                lr[rr] += p0 + p1;
                pw[(s * 16 + quad * 4 + rr) * 40 + l16]      = f2bf(p0);
                pw[(s * 16 + quad * 4 + rr) * 40 + 16 + l16] = f2bf(p1);
            }
        }
        bf16x8 pa0 = *(const bf16x8*)(pw + l16 * 40 + quad * 8);
        bf16x8 pa1 = *(const bf16x8*)(pw + (16 + l16) * 40 + quad * 8);

        {
            bf16x8 va[4];
            #pragma unroll
            for (int ds = 0; ds < 4; ds++) {
                const int d = ds * 16 + l16;
                va[ds] = *(const bf16x8*)&vbp[(d * 64 + ((quad * 16) ^ ((l16 & 3) << 4))) >> 1];
            }
            __builtin_amdgcn_s_setprio(1);
            #pragma unroll
            for (int ds = 0; ds < 4; ds++) {
                oacc0[ds] = __builtin_amdgcn_mfma_f32_16x16x32_bf16(pa0, va[ds], oacc0[ds], 0, 0, 0);
                oacc1[ds] = __builtin_amdgcn_mfma_f32_16x16x32_bf16(pa1, va[ds], oacc1[ds], 0, 0, 0);
            }
            __builtin_amdgcn_s_setprio(0);
        }
        {
            bf16x8 vb[4];
            #pragma unroll
            for (int ds = 0; ds < 4; ds++) {
                const int d = (ds + 4) * 16 + l16;
                vb[ds] = *(const bf16x8*)&vbp[(d * 64 + ((quad * 16) ^ ((l16 & 3) << 4))) >> 1];
            }
            __builtin_amdgcn_s_setprio(1);
            #pragma unroll
            for (int ds = 0; ds < 4; ds++) {
                oacc0[ds + 4] = __builtin_amdgcn_mfma_f32_16x16x32_bf16(pa0, vb[ds], oacc0[ds + 4], 0, 0, 0);
                oacc1[ds + 4] = __builtin_amdgcn_mfma_f32_16x16x32_bf16(pa1, vb[ds], oacc1[ds + 4], 0, 0, 0);
            }
            __builtin_amdgcn_s_setprio(0);
        }

        if (last) break;
        __syncthreads();
        cur ^= 1;
        kt = ktn;
    }

    #pragma unroll
    for (int off = 1; off <= 8; off <<= 1) {
        #pragma unroll
        for (int rr = 0; rr < 4; rr++) {
            lrow0[rr] += __shfl_xor(lrow0[rr], off);
            lrow1[rr] += __shfl_xor(lrow1[rr], off);
        }
    }

    #pragma unroll
    for (int s = 0; s < 2; s++) {
        const f32x4& lr = s ? lrow1 : lrow0;
        #pragma unroll
        for (int rr = 0; rr < 4; rr++) {
            float inv = 1.f / lr[rr];
            unsigned short* orow = O + ((size_t)(b * S_LEN + q0 + s * 16 + quad * 4 + rr)) * DMODEL + h * HD;
            #pragma unroll
            for (int ds = 0; ds < 8; ds++) {
                float v = s ? oacc1[ds][rr] : oacc0[ds][rr];
                orow[ds * 16 + l16] = f2bf(v * inv);
            }
        }
    }
}

// ---------------------------------------------------------------------------
extern "C" void kernel_launch(void* const* d_in, const int* in_sizes, int n_in,
                              void* d_out, int out_size, void* d_ws, size_t ws_size,
                              hipStream_t stream)
{
    const float* x    = (const float*)d_in[0];
    const float* wq_w = (const float*)d_in[1];
    const float* wq_a = (const float*)d_in[2];
    const float* wq_b = (const float*)d_in[3];
    const float* wk_w = (const float*)d_in[4];
    const float* wk_a = (const float*)d_in[5];
    const float* wk_b = (const float*)d_in[6];
    const float* wv_w = (const float*)d_in[7];
    const float* wv_a = (const float*)d_in[8];
    const float* wv_b = (const float*)d_in[9];
    const float* wo_w = (const float*)d_in[10];
    const float* wo_a = (const float*)d_in[11];
    const float* wo_b = (const float*)d_in[12];

    char* ws = (char*)d_ws;
    unsigned short* wqkvb = (unsigned short*)(ws);
    unsigned short* apack = (unsigned short*)(ws + 12582912);
    unsigned short* bqkvb = (unsigned short*)(ws + 14155776);
    unsigned short* Tbuf  = (unsigned short*)(ws + 14942208);
    unsigned short* Qbuf  = (unsigned short*)(ws + 18087936);
    unsigned short* Kbuf  = (unsigned short*)(ws + 34865152);
    unsigned short* Vtbuf = (unsigned short*)(ws + 39059456);
    unsigned short* wowb  = (unsigned short*)(ws);
    unsigned short* woab  = (unsigned short*)(ws + 8388608);
    unsigned short* wobb  = (unsigned short*)(ws + 8912896);
    unsigned short* T2buf = Tbuf;
    unsigned short* xb = (unsigned short*)d_out;

    // conv1: x + QKV/LoRA weights -> bf16
    Conv12 c1;
    c1.s[0]  = x;    c1.d[0]  = xb;
    c1.s[1]  = wq_w; c1.d[1]  = wqkvb;
    c1.s[2]  = wk_w; c1.d[2]  = wqkvb + 2048 * 2048;
    c1.s[3]  = wv_w; c1.d[3]  = wqkvb + 2560 * 2048;
    c1.s[4]  = wq_a; c1.d[4]  = apack;
    c1.s[5]  = wk_a; c1.d[5]  = apack + 128 * 2048;
    c1.s[6]  = wv_a; c1.d[6]  = apack + 256 * 2048;
    c1.s[7]  = wq_b; c1.d[7]  = bqkvb;
    c1.s[8]  = wk_b; c1.d[8]  = bqkvb + 2048 * 128;
    c1.s[9]  = wv_b; c1.d[9]  = bqkvb + 2560 * 128;
    c1.s[10] = wv_b; c1.d[10] = bqkvb + 2560 * 128;
    c1.s[11] = wv_b; c1.d[11] = bqkvb + 2560 * 128;
    int cum1[13] = {0, 4096, 6144, 6656, 7168, 7296, 7424, 7552, 7680, 7712,
                    7744, 7744, 7744};
    for (int i = 0; i < 13; i++) c1.c[i] = cum1[i];
    convk<<<dim3(7744), dim3(256), 0, stream>>>(c1);

    // T = xb @ apack^T  (LoRA intermediate, N=384)
    gemm_generic<128, 128, false><<<dim3(32, 3), dim3(256), 0, stream>>>(
        xb, DMODEL, apack, DMODEL, Tbuf, 3 * RLORA, DMODEL);

    // Q/K/V (V transposed into Vt) - R5 core, 384 blocks, 2/CU
    gemm128_qkv<<<dim3(32, 12), dim3(512), 0, stream>>>(
        xb, wqkvb, Tbuf, bqkvb, Qbuf, Kbuf, Vtbuf);

    // conv2: output-proj weights -> bf16
    Conv12 c2;
    c2.s[0] = wo_w; c2.d[0] = wowb;
    c2.s[1] = wo_a; c2.d[1] = woab;
    c2.s[2] = wo_b; c2.d[2] = wobb;
    for (int i = 3; i < 12; i++) { c2.s[i] = wo_b; c2.d[i] = wobb; }
    int cum2[13] = {0, 2048, 2176, 2304, 2304, 2304, 2304, 2304, 2304, 2304,
                    2304, 2304, 2304};
    for (int i = 0; i < 13; i++) c2.c[i] = cum2[i];
    convk<<<dim3(2304), dim3(256), 0, stream>>>(c2);

    rope_vec_k<<<dim3(5120), dim3(256), 0, stream>>>(Qbuf, Kbuf);

    attn_mfma<<<dim3(512), dim3(256), 0, stream>>>(Qbuf, Kbuf, Vtbuf, Qbuf);

    // T2 = attn_out @ woab^T  (N=128)
    gemm_generic<128, 128, false><<<dim3(32, 1), dim3(256), 0, stream>>>(
        Qbuf, DMODEL, woab, DMODEL, T2buf, RLORA, DMODEL);

    // final: out = attn_out @ wowb^T + T2 @ wobb^T  (fp32) - R5 core, 256 blocks
    gemm128_out<<<dim3(32, 8), dim3(512), 0, stream>>>(
        Qbuf, wowb, T2buf, wobb, (float*)d_out);
}

// Round 7
// 336.402 us; speedup vs baseline: 1.2359x; 1.1642x over previous
//
#include <hip/hip_runtime.h>

#define B_ 2
#define S_LEN 2048
#define DMODEL 2048
#define NH 16
#define NKVH 4
#define HD 128
#define RLORA 128
#define WINDOW_ 512
#define NGLOBAL 64

#define FENCE asm volatile("" ::: "memory")

typedef __bf16 bf16x8 __attribute__((ext_vector_type(8)));
typedef float f32x4 __attribute__((ext_vector_type(4)));

__device__ __forceinline__ float bf2f(unsigned short h) {
    return __uint_as_float(((unsigned int)h) << 16);
}
__device__ __forceinline__ unsigned short f2bf(float f) {
    unsigned int u = __float_as_uint(f);
    unsigned int r = u + 0x7fffu + ((u >> 16) & 1u);
    return (unsigned short)(r >> 16);
}
__device__ __forceinline__ unsigned int pack2bf(float a, float b) {
    return (unsigned int)f2bf(a) | ((unsigned int)f2bf(b) << 16);
}
__device__ __forceinline__ uint4 load8f(const float* p) {
    float4 f0 = *(const float4*)p;
    float4 f1 = *(const float4*)(p + 4);
    uint4 u;
    u.x = pack2bf(f0.x, f0.y);
    u.y = pack2bf(f0.z, f0.w);
    u.z = pack2bf(f1.x, f1.y);
    u.w = pack2bf(f1.z, f1.w);
    return u;
}

// Async global->LDS, 16 B per lane. LDS dest = wave-uniform base + lane*16.
__device__ __forceinline__ void gld16(const unsigned short* g, unsigned short* l) {
    __builtin_amdgcn_global_load_lds(
        (const __attribute__((address_space(1))) unsigned int*)g,
        (__attribute__((address_space(3))) unsigned int*)l,
        16, 0, 0);
}

// ---------------------------------------------------------------------------
// Batched fp32 -> bf16 conversion over up to 12 tensors. 2048 elems/block.
// ---------------------------------------------------------------------------
struct Conv12 {
    const float* s[12];
    unsigned short* d[12];
    int c[13];
};
__global__ __launch_bounds__(256) void convk(Conv12 a)
{
    int b = blockIdx.x;
    int seg = 0;
    while (b >= a.c[seg + 1]) seg++;
    int off = (b - a.c[seg]) * 2048 + threadIdx.x * 8;
    *(uint4*)(a.d[seg] + off) = load8f(a.s[seg] + off);
}

// ---------------------------------------------------------------------------
// Transpose-convert: A (128 x 2048 fp32) -> At (2048 x 128 bf16).
// 128 tile-blocks per matrix (tile = 32 rows x 64 cols).
// ---------------------------------------------------------------------------
struct TransA4 { const float* s[4]; unsigned short* d[4]; };
__global__ __launch_bounds__(256) void transAk(TransA4 a)
{
    __shared__ float tile[32][65];
    const int bid = blockIdx.x;
    const int mat = bid >> 7;
    const int tl = bid & 127;
    const int rt = tl & 3, ct = tl >> 2;
    const float* src = a.s[mat];
    unsigned short* dst = a.d[mat];
    const int t = threadIdx.x;
    #pragma unroll
    for (int p = 0; p < 2; p++) {
        int r = p * 16 + (t >> 4);
        int c = (t & 15) * 4;
        float4 v = *(const float4*)(src + (size_t)(rt * 32 + r) * 2048 + ct * 64 + c);
        tile[r][c] = v.x; tile[r][c + 1] = v.y;
        tile[r][c + 2] = v.z; tile[r][c + 3] = v.w;
    }
    __syncthreads();
    const int n = t >> 2, r8 = (t & 3) * 8;
    uint4 u;
    u.x = pack2bf(tile[r8 + 0][n], tile[r8 + 1][n]);
    u.y = pack2bf(tile[r8 + 2][n], tile[r8 + 3][n]);
    u.z = pack2bf(tile[r8 + 4][n], tile[r8 + 5][n]);
    u.w = pack2bf(tile[r8 + 6][n], tile[r8 + 7][n]);
    *(uint4*)(dst + (size_t)(ct * 64 + n) * 128 + rt * 32 + r8) = u;
}

// ---------------------------------------------------------------------------
// LoRA weight fold: C[m][n] += sum_r Bm[m][r] * At[n][r]  (bf16 in/out,
// fp32 accum). Tile 128x128, K=128 (4 x BK=32). seg: 1 = qkv row-segmented
// At select, 0 = single At. In-place C read-modify-write (block-exclusive).
// ---------------------------------------------------------------------------
__global__ __launch_bounds__(256) void weffk(
    unsigned short* __restrict__ C, int ldc,
    const unsigned short* __restrict__ Bm,
    const unsigned short* __restrict__ At,
    int seg)
{
    const int m0 = blockIdx.x * 128;
    const int n0 = blockIdx.y * 128;
    const unsigned short* Atb = At;
    if (seg)
        Atb = At + ((m0 < 2048) ? 0 : (m0 < 2560) ? (2048 * 128) : (2 * 2048 * 128));
    __shared__ __align__(16) unsigned short As_[128 * 32];
    __shared__ __align__(16) unsigned short Bs_[128 * 32];
    const int tid = threadIdx.x, lane = tid & 63, wid = tid >> 6;
    const int quad = lane >> 4, l16 = lane & 15;
    const int lr = lane >> 2, lc8 = (lane & 3) * 8;
    const int wm0 = (wid >> 1) * 64, wn0 = (wid & 1) * 64;
    f32x4 acc[4][4] = {};
    for (int k0 = 0; k0 < 128; k0 += 32) {
        #pragma unroll
        for (int c = 0; c < 2; c++) {
            int chunk = wid * 2 + c;
            gld16(Bm + (size_t)(m0 + chunk * 16 + lr) * 128 + k0 + lc8, As_ + chunk * 512);
            gld16(Atb + (size_t)(n0 + chunk * 16 + lr) * 128 + k0 + lc8, Bs_ + chunk * 512);
        }
        __syncthreads();
        bf16x8 af[4], bf[4];
        #pragma unroll
        for (int i = 0; i < 4; i++)
            af[i] = *(const bf16x8*)&As_[(wm0 + i * 16 + l16) * 32 + quad * 8];
        #pragma unroll
        for (int j = 0; j < 4; j++)
            bf[j] = *(const bf16x8*)&Bs_[(wn0 + j * 16 + l16) * 32 + quad * 8];
        #pragma unroll
        for (int i = 0; i < 4; i++)
            #pragma unroll
            for (int j = 0; j < 4; j++)
                acc[i][j] = __builtin_amdgcn_mfma_f32_16x16x32_bf16(af[i], bf[j], acc[i][j], 0, 0, 0);
        __syncthreads();
    }
    #pragma unroll
    for (int i = 0; i < 4; i++)
        #pragma unroll
        for (int j = 0; j < 4; j++) {
            const int col = n0 + wn0 + j * 16 + l16;
            #pragma unroll
            for (int r = 0; r < 4; r++) {
                size_t idx = (size_t)(m0 + wm0 + i * 16 + quad * 4 + r) * ldc + col;
                C[idx] = f2bf(bf2f(C[idx]) + acc[i][j][r]);
            }
        }
}

// ---------------------------------------------------------------------------
// R7 GEMM core: BM=128, BN=256, BK=32, 8 waves (2Mx4N -> wave 64x64),
// 48 KiB LDS dbuf -> 2+ blocks/CU. One phase per K-tile: {vmcnt(3); bar;
// 8 ds_read_b128; 16 MFMA (setprio); bar; stage(t+2)}. 2-deep prefetch.
// R6->R7 swizzle fix: fold row bits [2:1] into the 16B-slot index
// (f(row) = (row>>1)&3). R6's (row&3) only permuted WITHIN a 4-bank group
// (64B row stride spans 16 banks; group index = (l16&1)*4 + slot) -> 8-way
// alias, conflicts identical to unswizzled. With [2:1]: group =
// (l16&1)*4 + (quad ^ ((l16>>1)&3)) -> 8 groups x 2 lanes = free (m136).
// LoRA is pre-folded into weights (weffk) -> no tail; nt = Kmain/32.
// Layouts (validated): A-frag lane=A[m=l16][k=quad*8+j]; B-frag
// lane=B[k][n=l16]; C/D col=l16, row=quad*4+r.
// vmcnt ledger (3 loads/thread/stage): at wait, outstanding = {t:3, t+1:3}
// -> vmcnt(3) retires tile t exactly; tail drains vmcnt(0).
// ---------------------------------------------------------------------------
__device__ __forceinline__ void gemm128_acc(
    const unsigned short* __restrict__ A, int lda, int m0,
    const unsigned short* __restrict__ W, int ldw, int n0,
    int Kmain, f32x4 (&acc)[4][4])
{
    __shared__ __align__(16) unsigned short As[2][128 * 32];
    __shared__ __align__(16) unsigned short Bs[2][256 * 32];
    const int tid = threadIdx.x;
    const int lane = tid & 63, wid = tid >> 6;
    const int quad = lane >> 4, l16 = lane & 15;
    const int wm = (wid >> 2) * 64, wn = (wid & 3) * 64;

    // staging source map: LDS linear; src 16B-slot pre-swizzled with row
    // bits [2:1] (involution; read applies the same XOR).
    const int arow = tid >> 2;                                       // 0..127
    const int acol = (((tid & 3) * 16) ^ (((arow >> 1) & 3) << 4)) >> 1; // shorts

    const int nt = Kmain >> 5;

    auto stage = [&](int bb, int j) {
        const int k0 = j << 5;
        gld16(A + (size_t)(m0 + arow) * lda + k0 + acol, &As[bb][tid * 8]);
        gld16(W + (size_t)(n0 + arow) * ldw + k0 + acol, &Bs[bb][tid * 8]);
        gld16(W + (size_t)(n0 + arow + 128) * ldw + k0 + acol, &Bs[bb][tid * 8 + 4096]);
    };

    // fragment read offset (shorts): slot XOR with row bits [2:1] (= l16>>1).
    const int xoff = (((quad * 16) ^ (((l16 >> 1) & 3) << 4)) >> 1);
    const int ard = (wm + l16) * 32 + xoff;
    const int brd = (wn + l16) * 32 + xoff;

    stage(0, 0);
    stage(1, 1);

    for (int t = 0; t < nt; t++) {
        const int bb = t & 1;
        if (t < nt - 1) {
            asm volatile("s_waitcnt vmcnt(3)" ::: "memory");
        } else {
            asm volatile("s_waitcnt vmcnt(0)" ::: "memory");
        }
        __builtin_amdgcn_sched_barrier(0);
        FENCE; __builtin_amdgcn_s_barrier(); FENCE;

        bf16x8 af[4], bfn[4];
        #pragma unroll
        for (int mi = 0; mi < 4; mi++)
            af[mi] = *(const bf16x8*)&As[bb][ard + mi * 512];
        #pragma unroll
        for (int ni = 0; ni < 4; ni++)
            bfn[ni] = *(const bf16x8*)&Bs[bb][brd + ni * 512];

        __builtin_amdgcn_s_setprio(1);
        #pragma unroll
        for (int mi = 0; mi < 4; mi++)
            #pragma unroll
            for (int ni = 0; ni < 4; ni++)
                acc[mi][ni] = __builtin_amdgcn_mfma_f32_16x16x32_bf16(
                    af[mi], bfn[ni], acc[mi][ni], 0, 0, 0);
        __builtin_amdgcn_s_setprio(0);

        FENCE; __builtin_amdgcn_s_barrier(); FENCE;
        if (t + 2 < nt) stage(bb, t + 2);
    }
}

// Fused QKV on the R7 core. Grid (32, 12): by<8 Q, 8-9 K, 10-11 V.
__global__ __launch_bounds__(512, 4) void gemm128_qkv(
    const unsigned short* __restrict__ Xb,
    const unsigned short* __restrict__ Wqkv,
    unsigned short* __restrict__ Qo, unsigned short* __restrict__ Ko,
    unsigned short* __restrict__ Vt)
{
    const int m0 = blockIdx.x * 128;
    const int n0 = blockIdx.y * 256;
    f32x4 acc[4][4] = {};
    gemm128_acc(Xb, DMODEL, m0, Wqkv, DMODEL, n0, DMODEL, acc);

    const int tid = threadIdx.x, lane = tid & 63, wid = tid >> 6;
    const int l16 = lane & 15, quad = lane >> 4;
    const int wm = (wid >> 2) * 64, wn = (wid & 3) * 64;

    if (n0 < 2048) {
        #pragma unroll
        for (int mi = 0; mi < 4; mi++)
            #pragma unroll
            for (int ni = 0; ni < 4; ni++) {
                const int col = n0 + wn + ni * 16 + l16;
                const size_t rb = (size_t)(m0 + wm + mi * 16 + quad * 4);
                #pragma unroll
                for (int r = 0; r < 4; r++)
                    Qo[(rb + r) * DMODEL + col] = f2bf(acc[mi][ni][r]);
            }
    } else if (n0 < 2560) {
        #pragma unroll
        for (int mi = 0; mi < 4; mi++)
            #pragma unroll
            for (int ni = 0; ni < 4; ni++) {
                const int col = n0 - 2048 + wn + ni * 16 + l16;
                const size_t rb = (size_t)(m0 + wm + mi * 16 + quad * 4);
                #pragma unroll
                for (int r = 0; r < 4; r++)
                    Ko[(rb + r) * 512 + col] = f2bf(acc[mi][ni][r]);
            }
    } else {
        const int b = m0 >> 11;
        #pragma unroll
        for (int mi = 0; mi < 4; mi++)
            #pragma unroll
            for (int ni = 0; ni < 4; ni++) {
                const int ncol = n0 - 2560 + wn + ni * 16 + l16;
                const int head = ncol >> 7, dd = ncol & 127;
                const int srow = (m0 & (S_LEN - 1)) + wm + mi * 16 + quad * 4;
                uint2 pk;
                pk.x = pack2bf(acc[mi][ni][0], acc[mi][ni][1]);
                pk.y = pack2bf(acc[mi][ni][2], acc[mi][ni][3]);
                *(uint2*)(Vt + ((size_t)(b * NKVH + head) * HD + dd) * S_LEN + srow) = pk;
            }
    }
}

// Output projection on the R7 core. Grid (32, 8) = 256 blocks, fp32 out.
__global__ __launch_bounds__(512, 4) void gemm128_out(
    const unsigned short* __restrict__ Xb,
    const unsigned short* __restrict__ Ww,
    float* __restrict__ Out)
{
    const int m0 = blockIdx.x * 128;
    const int n0 = blockIdx.y * 256;
    f32x4 acc[4][4] = {};
    gemm128_acc(Xb, DMODEL, m0, Ww, DMODEL, n0, DMODEL, acc);

    const int tid = threadIdx.x, lane = tid & 63, wid = tid >> 6;
    const int l16 = lane & 15, quad = lane >> 4;
    const int wm = (wid >> 2) * 64, wn = (wid & 3) * 64;
    #pragma unroll
    for (int mi = 0; mi < 4; mi++)
        #pragma unroll
        for (int ni = 0; ni < 4; ni++) {
            const int col = n0 + wn + ni * 16 + l16;
            const size_t rb = (size_t)(m0 + wm + mi * 16 + quad * 4);
            #pragma unroll
            for (int r = 0; r < 4; r++)
                Out[(rb + r) * DMODEL + col] = acc[mi][ni][r];
        }
}

// ---------------------------------------------------------------------------
// RoPE, vectorized (validated r9).
// ---------------------------------------------------------------------------
__global__ __launch_bounds__(256) void rope_vec_k(
    unsigned short* __restrict__ Qb, unsigned short* __restrict__ Kb)
{
    int idx = blockIdx.x * 256 + threadIdx.x;
    const int npq = (B_ * S_LEN) * NH * 16;
    unsigned short* ptr;
    int m, tg;
    if (idx < npq) {
        tg = idx & 15;
        int h = (idx >> 4) & (NH - 1);
        m = idx >> 8;
        ptr = Qb + (size_t)m * (NH * HD) + h * HD + tg * 8;
    } else {
        idx -= npq;
        if (idx >= (B_ * S_LEN) * NKVH * 16) return;
        tg = idx & 15;
        int h = (idx >> 4) & (NKVH - 1);
        m = idx >> 6;
        ptr = Kb + (size_t)m * (NKVH * HD) + h * HD + tg * 8;
    }
    float pos = (float)(m & (S_LEN - 1));
    uint4 u = *(const uint4*)ptr;
    unsigned int w[4] = {u.x, u.y, u.z, u.w};
    #pragma unroll
    for (int j = 0; j < 4; j++) {
        int t = tg * 4 + j;
        float inv_freq = __expf(-(float)t * (13.815510557964274f / 64.0f));
        float ang = pos * inv_freq;
        float c, s;
        __sincosf(ang, &s, &c);
        float xr = __uint_as_float(w[j] << 16);
        float xi = __uint_as_float(w[j] & 0xffff0000u);
        w[j] = pack2bf(xr * c - xi * s, xr * s + xi * c);
    }
    *(uint4*)ptr = make_uint4(w[0], w[1], w[2], w[3]);
}

// ---------------------------------------------------------------------------
// MFMA flash attention v4 (R1): LDS-staged K/V shared by the whole block.
// ---------------------------------------------------------------------------
__global__ __launch_bounds__(256, 2) void attn_mfma(
    const unsigned short* __restrict__ Q,
    const unsigned short* __restrict__ K,
    const unsigned short* __restrict__ Vt,
    unsigned short* __restrict__ O)
{
    __shared__ __align__(16) unsigned short kvbuf[2][8192];
    __shared__ unsigned short plds[4][32 * 40];
    const int tid = threadIdx.x, lane = tid & 63, wid = tid >> 6;
    const int l16 = lane & 15, quad = lane >> 4;
    const int bid = blockIdx.x;
    const int g   = bid & 7;
    const int kvh = g & 3;
    const int b   = g >> 2;
    const int qt  = 63 - (bid >> 3);
    const int q0  = qt * 32;
    const int h   = kvh * 4 + wid;

    const unsigned short* qrow0 = Q + ((size_t)(b * S_LEN + q0 + l16)) * DMODEL + h * HD;
    bf16x8 qf0[4], qf1[4];
    #pragma unroll
    for (int c = 0; c < 4; c++) {
        qf0[c] = *(const bf16x8*)(qrow0 + c * 32 + quad * 8);
        qf1[c] = *(const bf16x8*)(qrow0 + (size_t)16 * DMODEL + c * 32 + quad * 8);
    }

    const unsigned short* Kbase  = K + ((size_t)(b * S_LEN)) * (NKVH * HD) + kvh * HD;
    const unsigned short* Vplane = Vt + ((size_t)(b * NKVH + kvh) * HD) * S_LEN;
    unsigned short* pw = &plds[wid][0];

    const unsigned short* Ksrc[2];
    const unsigned short* Vsrc[2];
    #pragma unroll
    for (int c = 0; c < 2; c++) {
        const int o = wid * 2048 + c * 1024 + lane * 16;
        const int kkey = o >> 8;
        const int kdim = (o & 255) ^ ((kkey & 15) << 4);
        Ksrc[c] = Kbase + (size_t)kkey * (NKVH * HD) + (kdim >> 1);
        const int vd = o >> 6;
        const int vkb = (o & 63) ^ ((vd & 3) << 4);
        Vsrc[c] = Vplane + (size_t)vd * S_LEN + (vkb >> 1);
    }

    f32x4 oacc0[8] = {}, oacc1[8] = {};
    f32x4 lrow0 = {0.f, 0.f, 0.f, 0.f}, lrow1 = {0.f, 0.f, 0.f, 0.f};
    const float c2 = 0.12753102f;

    const int kthi = (q0 + 31) >> 5;
    int wlo = q0 - (WINDOW_ - 1); if (wlo < 0) wlo = 0;
    const int ktw = wlo >> 5;

    auto nexttile = [&](int t) -> int {
        if (t < ktw) { int u = t + 1; return (u < 2 && u < ktw) ? u : ktw; }
        return t + 1;
    };

    auto stage = [&](int buf, int ktb) {
        #pragma unroll
        for (int c = 0; c < 2; c++) {
            gld16(Ksrc[c] + (size_t)ktb * (NKVH * HD),
                  &kvbuf[buf][wid * 1024 + c * 512]);
            gld16(Vsrc[c] + ktb,
                  &kvbuf[buf][4096 + wid * 1024 + c * 512]);
        }
    };

    int kt = 0;
    stage(0, 0);
    __syncthreads();
    int cur = 0;

    while (true) {
        const int ktb = kt * 32;
        const int ktn = nexttile(kt);
        const bool last = (ktn > kthi);
        if (!last) stage(cur ^ 1, ktn * 32);

        const unsigned short* kb  = kvbuf[cur];
        const unsigned short* vbp = kvbuf[cur] + 4096;

        bf16x8 kf0[4], kf1[4];
        #pragma unroll
        for (int c = 0; c < 4; c++) {
            const int koff = (l16 * 256 + ((c * 64 + quad * 16) ^ (l16 << 4))) >> 1;
            kf0[c] = *(const bf16x8*)&kb[koff];
            kf1[c] = *(const bf16x8*)&kb[koff + 2048];
        }

        f32x4 s00 = {}, s01 = {}, s10 = {}, s11 = {};
        __builtin_amdgcn_s_setprio(1);
        #pragma unroll
        for (int c = 0; c < 4; c++) {
            s00 = __builtin_amdgcn_mfma_f32_16x16x32_bf16(qf0[c], kf0[c], s00, 0, 0, 0);
            s01 = __builtin_amdgcn_mfma_f32_16x16x32_bf16(qf0[c], kf1[c], s01, 0, 0, 0);
            s10 = __builtin_amdgcn_mfma_f32_16x16x32_bf16(qf1[c], kf0[c], s10, 0, 0, 0);
            s11 = __builtin_amdgcn_mfma_f32_16x16x32_bf16(qf1[c], kf1[c], s11, 0, 0, 0);
        }
        __builtin_amdgcn_s_setprio(0);

        #pragma unroll
        for (int s = 0; s < 2; s++) {
            const f32x4 sa0 = s ? s10 : s00;
            const f32x4 sa1 = s ? s11 : s01;
            const int qs = q0 + s * 16;
            const bool full = (ktb + 31 <= qs) &&
                              (((qs + 15) - ktb < WINDOW_) || (ktb + 31 < NGLOBAL));
            f32x4& lr = s ? lrow1 : lrow0;
            #pragma unroll
            for (int rr = 0; rr < 4; rr++) {
                float p0 = exp2f(sa0[rr] * c2);
                float p1 = exp2f(sa1[rr] * c2);
                if (!full) {
                    const int i = qs + quad * 4 + rr;
                    const int j0 = ktb + l16, j1 = j0 + 16;
                    bool a0 = (j0 <= i) && ((i - j0 < WINDOW_) || (j0 < NGLOBAL));
                    bool a1 = (j1 <= i) && ((i - j1 < WINDOW_) || (j1 < NGLOBAL));
                    p0 = a0 ? p0 : 0.f;
                    p1 = a1 ? p1 : 0.f;
                }
                lr[rr] += p0 + p1;
                pw[(s * 16 + quad * 4 + rr) * 40 + l16]      = f2bf(p0);
                pw[(s * 16 + quad * 4 + rr) * 40 + 16 + l16] = f2bf(p1);
            }
        }
        bf16x8 pa0 = *(const bf16x8*)(pw + l16 * 40 + quad * 8);
        bf16x8 pa1 = *(const bf16x8*)(pw + (16 + l16) * 40 + quad * 8);

        {
            bf16x8 va[4];
            #pragma unroll
            for (int ds = 0; ds < 4; ds++) {
                const int d = ds * 16 + l16;
                va[ds] = *(const bf16x8*)&vbp[(d * 64 + ((quad * 16) ^ ((l16 & 3) << 4))) >> 1];
            }
            __builtin_amdgcn_s_setprio(1);
            #pragma unroll
            for (int ds = 0; ds < 4; ds++) {
                oacc0[ds] = __builtin_amdgcn_mfma_f32_16x16x32_bf16(pa0, va[ds], oacc0[ds], 0, 0, 0);
                oacc1[ds] = __builtin_amdgcn_mfma_f32_16x16x32_bf16(pa1, va[ds], oacc1[ds], 0, 0, 0);
            }
            __builtin_amdgcn_s_setprio(0);
        }
        {
            bf16x8 vb[4];
            #pragma unroll
            for (int ds = 0; ds < 4; ds++) {
                const int d = (ds + 4) * 16 + l16;
                vb[ds] = *(const bf16x8*)&vbp[(d * 64 + ((quad * 16) ^ ((l16 & 3) << 4))) >> 1];
            }
            __builtin_amdgcn_s_setprio(1);
            #pragma unroll
            for (int ds = 0; ds < 4; ds++) {
                oacc0[ds + 4] = __builtin_amdgcn_mfma_f32_16x16x32_bf16(pa0, vb[ds], oacc0[ds + 4], 0, 0, 0);
                oacc1[ds + 4] = __builtin_amdgcn_mfma_f32_16x16x32_bf16(pa1, vb[ds], oacc1[ds + 4], 0, 0, 0);
            }
            __builtin_amdgcn_s_setprio(0);
        }

        if (last) break;
        __syncthreads();
        cur ^= 1;
        kt = ktn;
    }

    #pragma unroll
    for (int off = 1; off <= 8; off <<= 1) {
        #pragma unroll
        for (int rr = 0; rr < 4; rr++) {
            lrow0[rr] += __shfl_xor(lrow0[rr], off);
            lrow1[rr] += __shfl_xor(lrow1[rr], off);
        }
    }

    #pragma unroll
    for (int s = 0; s < 2; s++) {
        const f32x4& lr = s ? lrow1 : lrow0;
        #pragma unroll
        for (int rr = 0; rr < 4; rr++) {
            float inv = 1.f / lr[rr];
            unsigned short* orow = O + ((size_t)(b * S_LEN + q0 + s * 16 + quad * 4 + rr)) * DMODEL + h * HD;
            #pragma unroll
            for (int ds = 0; ds < 8; ds++) {
                float v = s ? oacc1[ds][rr] : oacc0[ds][rr];
                orow[ds * 16 + l16] = f2bf(v * inv);
            }
        }
    }
}

// ---------------------------------------------------------------------------
extern "C" void kernel_launch(void* const* d_in, const int* in_sizes, int n_in,
                              void* d_out, int out_size, void* d_ws, size_t ws_size,
                              hipStream_t stream)
{
    const float* x    = (const float*)d_in[0];
    const float* wq_w = (const float*)d_in[1];
    const float* wq_a = (const float*)d_in[2];
    const float* wq_b = (const float*)d_in[3];
    const float* wk_w = (const float*)d_in[4];
    const float* wk_a = (const float*)d_in[5];
    const float* wk_b = (const float*)d_in[6];
    const float* wv_w = (const float*)d_in[7];
    const float* wv_a = (const float*)d_in[8];
    const float* wv_b = (const float*)d_in[9];
    const float* wo_w = (const float*)d_in[10];
    const float* wo_a = (const float*)d_in[11];
    const float* wo_b = (const float*)d_in[12];

    char* ws = (char*)d_ws;
    unsigned short* wqkvb  = (unsigned short*)(ws);                 // 3072x2048
    unsigned short* apackT = (unsigned short*)(ws + 12582912);      // 3x(2048x128)
    unsigned short* bqkvb  = (unsigned short*)(ws + 14155776);      // 3072x128
    unsigned short* Qbuf   = (unsigned short*)(ws + 18087936);      // 4096x2048
    unsigned short* Kbuf   = (unsigned short*)(ws + 34865152);      // 4096x512
    unsigned short* Vtbuf  = (unsigned short*)(ws + 39059456);      // 2x4x128x2048
    // post-qkv reuse of the dead wqkvb region:
    unsigned short* wowb   = (unsigned short*)(ws);                 // 2048x2048
    unsigned short* wobb   = (unsigned short*)(ws + 8388608);       // 2048x128
    unsigned short* woabT  = (unsigned short*)(ws + 8912896);       // 2048x128
    // x (bf16) lives in d_out's first 16 MB; dead before the final GEMM.
    unsigned short* xb = (unsigned short*)d_out;

    // conv1: x + QKV dense weights + B-matrices -> bf16
    Conv12 c1;
    c1.s[0] = x;    c1.d[0] = xb;                     // 4096
    c1.s[1] = wq_w; c1.d[1] = wqkvb;                  // 2048
    c1.s[2] = wk_w; c1.d[2] = wqkvb + 2048 * 2048;    // 512
    c1.s[3] = wv_w; c1.d[3] = wqkvb + 2560 * 2048;    // 512
    c1.s[4] = wq_b; c1.d[4] = bqkvb;                  // 128
    c1.s[5] = wk_b; c1.d[5] = bqkvb + 2048 * 128;     // 32
    c1.s[6] = wv_b; c1.d[6] = bqkvb + 2560 * 128;     // 32
    for (int i = 7; i < 12; i++) { c1.s[i] = wv_b; c1.d[i] = bqkvb + 2560 * 128; }
    int cum1[13] = {0, 4096, 6144, 6656, 7168, 7296, 7328, 7360, 7360, 7360,
                    7360, 7360, 7360};
    for (int i = 0; i < 13; i++) c1.c[i] = cum1[i];
    convk<<<dim3(7360), dim3(256), 0, stream>>>(c1);

    // A^T (bf16) for q,k,v
    TransA4 t1;
    t1.s[0] = wq_a; t1.d[0] = apackT;
    t1.s[1] = wk_a; t1.d[1] = apackT + 2048 * 128;
    t1.s[2] = wv_a; t1.d[2] = apackT + 2 * 2048 * 128;
    t1.s[3] = wq_a; t1.d[3] = apackT;
    transAk<<<dim3(384), dim3(256), 0, stream>>>(t1);

    // fold LoRA: Wqkv += Bqkv @ A
    weffk<<<dim3(24, 16), dim3(256), 0, stream>>>(wqkvb, DMODEL, bqkvb, apackT, 1);

    // Q/K/V (V transposed into Vt), plain GEMM (LoRA folded)
    gemm128_qkv<<<dim3(32, 12), dim3(512), 0, stream>>>(
        xb, wqkvb, Qbuf, Kbuf, Vtbuf);

    // conv2 (over dead wqkvb region): wo_w, wo_b
    Conv12 c2;
    c2.s[0] = wo_w; c2.d[0] = wowb;   // 2048
    c2.s[1] = wo_b; c2.d[1] = wobb;   // 128
    for (int i = 2; i < 12; i++) { c2.s[i] = wo_b; c2.d[i] = wobb; }
    int cum2[13] = {0, 2048, 2176, 2176, 2176, 2176, 2176, 2176, 2176, 2176,
                    2176, 2176, 2176};
    for (int i = 0; i < 13; i++) c2.c[i] = cum2[i];
    convk<<<dim3(2176), dim3(256), 0, stream>>>(c2);

    TransA4 t2;
    t2.s[0] = wo_a; t2.d[0] = woabT;
    t2.s[1] = wo_a; t2.d[1] = woabT;
    t2.s[2] = wo_a; t2.d[2] = woabT;
    t2.s[3] = wo_a; t2.d[3] = woabT;
    transAk<<<dim3(128), dim3(256), 0, stream>>>(t2);

    // fold LoRA: Wo += Bo @ Ao
    weffk<<<dim3(16, 16), dim3(256), 0, stream>>>(wowb, DMODEL, wobb, woabT, 0);

    rope_vec_k<<<dim3(5120), dim3(256), 0, stream>>>(Qbuf, Kbuf);

    attn_mfma<<<dim3(512), dim3(256), 0, stream>>>(Qbuf, Kbuf, Vtbuf, Qbuf);

    // final: out = attn_out @ Weff_o^T  (fp32), plain GEMM
    gemm128_out<<<dim3(32, 8), dim3(512), 0, stream>>>(
        Qbuf, wowb, (float*)d_out);
}

// Round 8
// 316.967 us; speedup vs baseline: 1.3116x; 1.0613x over previous
//
#include <hip/hip_runtime.h>

#define B_ 2
#define S_LEN 2048
#define DMODEL 2048
#define NH 16
#define NKVH 4
#define HD 128
#define RLORA 128
#define WINDOW_ 512
#define NGLOBAL 64

#define FENCE asm volatile("" ::: "memory")

typedef __bf16 bf16x8 __attribute__((ext_vector_type(8)));
typedef float f32x4 __attribute__((ext_vector_type(4)));

__device__ __forceinline__ float bf2f(unsigned short h) {
    return __uint_as_float(((unsigned int)h) << 16);
}
__device__ __forceinline__ unsigned short f2bf(float f) {
    unsigned int u = __float_as_uint(f);
    unsigned int r = u + 0x7fffu + ((u >> 16) & 1u);
    return (unsigned short)(r >> 16);
}
__device__ __forceinline__ unsigned int pack2bf(float a, float b) {
    return (unsigned int)f2bf(a) | ((unsigned int)f2bf(b) << 16);
}
__device__ __forceinline__ uint4 load8f(const float* p) {
    float4 f0 = *(const float4*)p;
    float4 f1 = *(const float4*)(p + 4);
    uint4 u;
    u.x = pack2bf(f0.x, f0.y);
    u.y = pack2bf(f0.z, f0.w);
    u.z = pack2bf(f1.x, f1.y);
    u.w = pack2bf(f1.z, f1.w);
    return u;
}

// Async global->LDS, 16 B per lane. LDS dest = wave-uniform base + lane*16.
__device__ __forceinline__ void gld16(const unsigned short* g, unsigned short* l) {
    __builtin_amdgcn_global_load_lds(
        (const __attribute__((address_space(1))) unsigned int*)g,
        (__attribute__((address_space(3))) unsigned int*)l,
        16, 0, 0);
}

// ---------------------------------------------------------------------------
// Batched fp32 -> bf16 conversion over up to 12 tensors. 2048 elems/block.
// ---------------------------------------------------------------------------
struct Conv12 {
    const float* s[12];
    unsigned short* d[12];
    int c[13];
};
__global__ __launch_bounds__(256) void convk(Conv12 a)
{
    int b = blockIdx.x;
    int seg = 0;
    while (b >= a.c[seg + 1]) seg++;
    int off = (b - a.c[seg]) * 2048 + threadIdx.x * 8;
    *(uint4*)(a.d[seg] + off) = load8f(a.s[seg] + off);
}

// ---------------------------------------------------------------------------
// Transpose-convert: A (128 x 2048 fp32) -> At (2048 x 128 bf16).
// ---------------------------------------------------------------------------
struct TransA4 { const float* s[4]; unsigned short* d[4]; };
__global__ __launch_bounds__(256) void transAk(TransA4 a)
{
    __shared__ float tile[32][65];
    const int bid = blockIdx.x;
    const int mat = bid >> 7;
    const int tl = bid & 127;
    const int rt = tl & 3, ct = tl >> 2;
    const float* src = a.s[mat];
    unsigned short* dst = a.d[mat];
    const int t = threadIdx.x;
    #pragma unroll
    for (int p = 0; p < 2; p++) {
        int r = p * 16 + (t >> 4);
        int c = (t & 15) * 4;
        float4 v = *(const float4*)(src + (size_t)(rt * 32 + r) * 2048 + ct * 64 + c);
        tile[r][c] = v.x; tile[r][c + 1] = v.y;
        tile[r][c + 2] = v.z; tile[r][c + 3] = v.w;
    }
    __syncthreads();
    const int n = t >> 2, r8 = (t & 3) * 8;
    uint4 u;
    u.x = pack2bf(tile[r8 + 0][n], tile[r8 + 1][n]);
    u.y = pack2bf(tile[r8 + 2][n], tile[r8 + 3][n]);
    u.z = pack2bf(tile[r8 + 4][n], tile[r8 + 5][n]);
    u.w = pack2bf(tile[r8 + 6][n], tile[r8 + 7][n]);
    *(uint4*)(dst + (size_t)(ct * 64 + n) * 128 + rt * 32 + r8) = u;
}

// ---------------------------------------------------------------------------
// LoRA weight fold: C[m][n] += sum_r Bm[m][r] * At[n][r]  (bf16 in/out,
// fp32 accum). Tile 128x128, K=128. seg: 1 = qkv row-segmented At select.
// ---------------------------------------------------------------------------
__global__ __launch_bounds__(256) void weffk(
    unsigned short* __restrict__ C, int ldc,
    const unsigned short* __restrict__ Bm,
    const unsigned short* __restrict__ At,
    int seg)
{
    const int m0 = blockIdx.x * 128;
    const int n0 = blockIdx.y * 128;
    const unsigned short* Atb = At;
    if (seg)
        Atb = At + ((m0 < 2048) ? 0 : (m0 < 2560) ? (2048 * 128) : (2 * 2048 * 128));
    __shared__ __align__(16) unsigned short As_[128 * 32];
    __shared__ __align__(16) unsigned short Bs_[128 * 32];
    const int tid = threadIdx.x, lane = tid & 63, wid = tid >> 6;
    const int quad = lane >> 4, l16 = lane & 15;
    const int lr = lane >> 2, lc8 = (lane & 3) * 8;
    const int wm0 = (wid >> 1) * 64, wn0 = (wid & 1) * 64;
    f32x4 acc[4][4] = {};
    for (int k0 = 0; k0 < 128; k0 += 32) {
        #pragma unroll
        for (int c = 0; c < 2; c++) {
            int chunk = wid * 2 + c;
            gld16(Bm + (size_t)(m0 + chunk * 16 + lr) * 128 + k0 + lc8, As_ + chunk * 512);
            gld16(Atb + (size_t)(n0 + chunk * 16 + lr) * 128 + k0 + lc8, Bs_ + chunk * 512);
        }
        __syncthreads();
        bf16x8 af[4], bf[4];
        #pragma unroll
        for (int i = 0; i < 4; i++)
            af[i] = *(const bf16x8*)&As_[(wm0 + i * 16 + l16) * 32 + quad * 8];
        #pragma unroll
        for (int j = 0; j < 4; j++)
            bf[j] = *(const bf16x8*)&Bs_[(wn0 + j * 16 + l16) * 32 + quad * 8];
        #pragma unroll
        for (int i = 0; i < 4; i++)
            #pragma unroll
            for (int j = 0; j < 4; j++)
                acc[i][j] = __builtin_amdgcn_mfma_f32_16x16x32_bf16(af[i], bf[j], acc[i][j], 0, 0, 0);
        __syncthreads();
    }
    #pragma unroll
    for (int i = 0; i < 4; i++)
        #pragma unroll
        for (int j = 0; j < 4; j++) {
            const int col = n0 + wn0 + j * 16 + l16;
            #pragma unroll
            for (int r = 0; r < 4; r++) {
                size_t idx = (size_t)(m0 + wm0 + i * 16 + quad * 4 + r) * ldc + col;
                C[idx] = f2bf(bf2f(C[idx]) + acc[i][j][r]);
            }
        }
}

// ---------------------------------------------------------------------------
// R8 GEMM core: BM=128, BN=128, BK=32, 4 waves (2x2 -> wave 64x64, 16
// MFMA/tile -- same ratio as R7), 32 KiB LDS dbuf. Grids sized for EXACT
// CU balance: qkv (32,24)=768 = 3/CU, out (32,16)=512 = 2/CU (R7's 384@2/CU
// left 25% of CU-slots idle; out's 256@1/CU had zero cross-block overlap).
// Counted vmcnt(4) (4 loads/thread/stage, 2-deep prefetch, never 0 in-loop).
// Swizzle both-sides with row bits [2:1] (R7-verified: conflicts = 0).
// Layouts (validated): A-frag lane=A[m=l16][k=quad*8+j]; B-frag
// lane=B[k][n=l16]; C/D col=l16, row=quad*4+r.
// ---------------------------------------------------------------------------
__device__ __forceinline__ void gemm128_acc(
    const unsigned short* __restrict__ A, int lda, int m0,
    const unsigned short* __restrict__ W, int ldw, int n0,
    int Kmain, f32x4 (&acc)[4][4])
{
    __shared__ __align__(16) unsigned short As[2][4096];
    __shared__ __align__(16) unsigned short Bs[2][4096];
    const int tid = threadIdx.x;
    const int lane = tid & 63, wid = tid >> 6;
    const int quad = lane >> 4, l16 = lane & 15;
    const int wm = (wid >> 1) * 64, wn = (wid & 1) * 64;

    // staging source map: LDS linear; src 16B-slot pre-swizzled (row[2:1]).
    int arow[2], acol[2];
    #pragma unroll
    for (int c = 0; c < 2; c++) {
        const int o = tid * 16 + c * 4096;          // byte offset in 8KB tile
        arow[c] = o >> 6;                           // row (64B rows)
        acol[c] = (((tid & 3) * 16) ^ (((arow[c] >> 1) & 3) << 4)) >> 1;
    }

    const int nt = Kmain >> 5;

    auto stage = [&](int bb, int j) {
        const int k0 = j << 5;
        #pragma unroll
        for (int c = 0; c < 2; c++)
            gld16(A + (size_t)(m0 + arow[c]) * lda + k0 + acol[c],
                  &As[bb][tid * 8 + c * 2048]);
        #pragma unroll
        for (int c = 0; c < 2; c++)
            gld16(W + (size_t)(n0 + arow[c]) * ldw + k0 + acol[c],
                  &Bs[bb][tid * 8 + c * 2048]);
    };

    // fragment read offset (shorts): slot XOR with row bits [2:1] (= l16>>1).
    const int xoff = (((quad * 16) ^ (((l16 >> 1) & 3) << 4)) >> 1);
    const int ard = (wm + l16) * 32 + xoff;
    const int brd = (wn + l16) * 32 + xoff;

    stage(0, 0);
    stage(1, 1);

    for (int t = 0; t < nt; t++) {
        const int bb = t & 1;
        if (t < nt - 1) {
            asm volatile("s_waitcnt vmcnt(4)" ::: "memory");
        } else {
            asm volatile("s_waitcnt vmcnt(0)" ::: "memory");
        }
        __builtin_amdgcn_sched_barrier(0);
        FENCE; __builtin_amdgcn_s_barrier(); FENCE;

        bf16x8 af[4], bfn[4];
        #pragma unroll
        for (int mi = 0; mi < 4; mi++)
            af[mi] = *(const bf16x8*)&As[bb][ard + mi * 512];
        #pragma unroll
        for (int ni = 0; ni < 4; ni++)
            bfn[ni] = *(const bf16x8*)&Bs[bb][brd + ni * 512];

        __builtin_amdgcn_s_setprio(1);
        #pragma unroll
        for (int mi = 0; mi < 4; mi++)
            #pragma unroll
            for (int ni = 0; ni < 4; ni++)
                acc[mi][ni] = __builtin_amdgcn_mfma_f32_16x16x32_bf16(
                    af[mi], bfn[ni], acc[mi][ni], 0, 0, 0);
        __builtin_amdgcn_s_setprio(0);

        FENCE; __builtin_amdgcn_s_barrier(); FENCE;
        if (t + 2 < nt) stage(bb, t + 2);
    }
}

// RoPE applied in-register to one acc column-vector (4 rows).
// Lane at col c pairs with lane^1 (col c^1): even lane out = xe*c - xo*s,
// odd lane out = xe*s + xo*c, with (s,c) from freq idx (col&127)>>1 and
// pos = row & 2047. Matches rope_vec_k (freq = exp(-t*ln(1e6)/64)).
__device__ __forceinline__ f32x4 rope4(f32x4 v, int col, int rowbase)
{
    const int t2 = col & 127;
    const float invf = __expf(-(float)(t2 >> 1) * (13.815510557964274f / 64.0f));
    const bool ev = (t2 & 1) == 0;
    f32x4 o;
    #pragma unroll
    for (int r = 0; r < 4; r++) {
        float self = v[r];
        float other = __shfl_xor(self, 1);
        float pos = (float)((rowbase + r) & (S_LEN - 1));
        float s, c;
        __sincosf(pos * invf, &s, &c);
        o[r] = ev ? (self * c - other * s) : (other * s + self * c);
    }
    return o;
}

// Fused QKV + RoPE on the R8 core. Grid (32, 24): by<16 Q, 16-19 K, 20-23 V.
__global__ __launch_bounds__(256, 3) void gemm128_qkv(
    const unsigned short* __restrict__ Xb,
    const unsigned short* __restrict__ Wqkv,
    unsigned short* __restrict__ Qo, unsigned short* __restrict__ Ko,
    unsigned short* __restrict__ Vt)
{
    const int m0 = blockIdx.x * 128;
    const int n0 = blockIdx.y * 128;
    f32x4 acc[4][4] = {};
    gemm128_acc(Xb, DMODEL, m0, Wqkv, DMODEL, n0, DMODEL, acc);

    const int tid = threadIdx.x, lane = tid & 63, wid = tid >> 6;
    const int l16 = lane & 15, quad = lane >> 4;
    const int wm = (wid >> 1) * 64, wn = (wid & 1) * 64;

    if (n0 < 2048) {
        #pragma unroll
        for (int mi = 0; mi < 4; mi++)
            #pragma unroll
            for (int ni = 0; ni < 4; ni++) {
                const int col = n0 + wn + ni * 16 + l16;
                const int rb = m0 + wm + mi * 16 + quad * 4;
                f32x4 v = rope4(acc[mi][ni], col, rb);
                #pragma unroll
                for (int r = 0; r < 4; r++)
                    Qo[(size_t)(rb + r) * DMODEL + col] = f2bf(v[r]);
            }
    } else if (n0 < 2560) {
        #pragma unroll
        for (int mi = 0; mi < 4; mi++)
            #pragma unroll
            for (int ni = 0; ni < 4; ni++) {
                const int col = n0 - 2048 + wn + ni * 16 + l16;
                const int rb = m0 + wm + mi * 16 + quad * 4;
                f32x4 v = rope4(acc[mi][ni], col, rb);
                #pragma unroll
                for (int r = 0; r < 4; r++)
                    Ko[(size_t)(rb + r) * 512 + col] = f2bf(v[r]);
            }
    } else {
        const int b = m0 >> 11;
        #pragma unroll
        for (int mi = 0; mi < 4; mi++)
            #pragma unroll
            for (int ni = 0; ni < 4; ni++) {
                const int ncol = n0 - 2560 + wn + ni * 16 + l16;
                const int head = ncol >> 7, dd = ncol & 127;
                const int srow = (m0 & (S_LEN - 1)) + wm + mi * 16 + quad * 4;
                uint2 pk;
                pk.x = pack2bf(acc[mi][ni][0], acc[mi][ni][1]);
                pk.y = pack2bf(acc[mi][ni][2], acc[mi][ni][3]);
                *(uint2*)(Vt + ((size_t)(b * NKVH + head) * HD + dd) * S_LEN + srow) = pk;
            }
    }
}

// Output projection on the R8 core. Grid (32, 16) = 512 blocks, fp32 out.
__global__ __launch_bounds__(256, 3) void gemm128_out(
    const unsigned short* __restrict__ Xb,
    const unsigned short* __restrict__ Ww,
    float* __restrict__ Out)
{
    const int m0 = blockIdx.x * 128;
    const int n0 = blockIdx.y * 128;
    f32x4 acc[4][4] = {};
    gemm128_acc(Xb, DMODEL, m0, Ww, DMODEL, n0, DMODEL, acc);

    const int tid = threadIdx.x, lane = tid & 63, wid = tid >> 6;
    const int l16 = lane & 15, quad = lane >> 4;
    const int wm = (wid >> 1) * 64, wn = (wid & 1) * 64;
    #pragma unroll
    for (int mi = 0; mi < 4; mi++)
        #pragma unroll
        for (int ni = 0; ni < 4; ni++) {
            const int col = n0 + wn + ni * 16 + l16;
            const size_t rb = (size_t)(m0 + wm + mi * 16 + quad * 4);
            #pragma unroll
            for (int r = 0; r < 4; r++)
                Out[(rb + r) * DMODEL + col] = acc[mi][ni][r];
        }
}

// ---------------------------------------------------------------------------
// MFMA flash attention v4 (R1): LDS-staged K/V shared by the whole block.
// ---------------------------------------------------------------------------
__global__ __launch_bounds__(256, 2) void attn_mfma(
    const unsigned short* __restrict__ Q,
    const unsigned short* __restrict__ K,
    const unsigned short* __restrict__ Vt,
    unsigned short* __restrict__ O)
{
    __shared__ __align__(16) unsigned short kvbuf[2][8192];
    __shared__ unsigned short plds[4][32 * 40];
    const int tid = threadIdx.x, lane = tid & 63, wid = tid >> 6;
    const int l16 = lane & 15, quad = lane >> 4;
    const int bid = blockIdx.x;
    const int g   = bid & 7;
    const int kvh = g & 3;
    const int b   = g >> 2;
    const int qt  = 63 - (bid >> 3);
    const int q0  = qt * 32;
    const int h   = kvh * 4 + wid;

    const unsigned short* qrow0 = Q + ((size_t)(b * S_LEN + q0 + l16)) * DMODEL + h * HD;
    bf16x8 qf0[4], qf1[4];
    #pragma unroll
    for (int c = 0; c < 4; c++) {
        qf0[c] = *(const bf16x8*)(qrow0 + c * 32 + quad * 8);
        qf1[c] = *(const bf16x8*)(qrow0 + (size_t)16 * DMODEL + c * 32 + quad * 8);
    }

    const unsigned short* Kbase  = K + ((size_t)(b * S_LEN)) * (NKVH * HD) + kvh * HD;
    const unsigned short* Vplane = Vt + ((size_t)(b * NKVH + kvh) * HD) * S_LEN;
    unsigned short* pw = &plds[wid][0];

    const unsigned short* Ksrc[2];
    const unsigned short* Vsrc[2];
    #pragma unroll
    for (int c = 0; c < 2; c++) {
        const int o = wid * 2048 + c * 1024 + lane * 16;
        const int kkey = o >> 8;
        const int kdim = (o & 255) ^ ((kkey & 15) << 4);
        Ksrc[c] = Kbase + (size_t)kkey * (NKVH * HD) + (kdim >> 1);
        const int vd = o >> 6;
        const int vkb = (o & 63) ^ ((vd & 3) << 4);
        Vsrc[c] = Vplane + (size_t)vd * S_LEN + (vkb >> 1);
    }

    f32x4 oacc0[8] = {}, oacc1[8] = {};
    f32x4 lrow0 = {0.f, 0.f, 0.f, 0.f}, lrow1 = {0.f, 0.f, 0.f, 0.f};
    const float c2 = 0.12753102f;

    const int kthi = (q0 + 31) >> 5;
    int wlo = q0 - (WINDOW_ - 1); if (wlo < 0) wlo = 0;
    const int ktw = wlo >> 5;

    auto nexttile = [&](int t) -> int {
        if (t < ktw) { int u = t + 1; return (u < 2 && u < ktw) ? u : ktw; }
        return t + 1;
    };

    auto stage = [&](int buf, int ktb) {
        #pragma unroll
        for (int c = 0; c < 2; c++) {
            gld16(Ksrc[c] + (size_t)ktb * (NKVH * HD),
                  &kvbuf[buf][wid * 1024 + c * 512]);
            gld16(Vsrc[c] + ktb,
                  &kvbuf[buf][4096 + wid * 1024 + c * 512]);
        }
    };

    int kt = 0;
    stage(0, 0);
    __syncthreads();
    int cur = 0;

    while (true) {
        const int ktb = kt * 32;
        const int ktn = nexttile(kt);
        const bool last = (ktn > kthi);
        if (!last) stage(cur ^ 1, ktn * 32);

        const unsigned short* kb  = kvbuf[cur];
        const unsigned short* vbp = kvbuf[cur] + 4096;

        bf16x8 kf0[4], kf1[4];
        #pragma unroll
        for (int c = 0; c < 4; c++) {
            const int koff = (l16 * 256 + ((c * 64 + quad * 16) ^ (l16 << 4))) >> 1;
            kf0[c] = *(const bf16x8*)&kb[koff];
            kf1[c] = *(const bf16x8*)&kb[koff + 2048];
        }

        f32x4 s00 = {}, s01 = {}, s10 = {}, s11 = {};
        __builtin_amdgcn_s_setprio(1);
        #pragma unroll
        for (int c = 0; c < 4; c++) {
            s00 = __builtin_amdgcn_mfma_f32_16x16x32_bf16(qf0[c], kf0[c], s00, 0, 0, 0);
            s01 = __builtin_amdgcn_mfma_f32_16x16x32_bf16(qf0[c], kf1[c], s01, 0, 0, 0);
            s10 = __builtin_amdgcn_mfma_f32_16x16x32_bf16(qf1[c], kf0[c], s10, 0, 0, 0);
            s11 = __builtin_amdgcn_mfma_f32_16x16x32_bf16(qf1[c], kf1[c], s11, 0, 0, 0);
        }
        __builtin_amdgcn_s_setprio(0);

        #pragma unroll
        for (int s = 0; s < 2; s++) {
            const f32x4 sa0 = s ? s10 : s00;
            const f32x4 sa1 = s ? s11 : s01;
            const int qs = q0 + s * 16;
            const bool full = (ktb + 31 <= qs) &&
                              (((qs + 15) - ktb < WINDOW_) || (ktb + 31 < NGLOBAL));
            f32x4& lr = s ? lrow1 : lrow0;
            #pragma unroll
            for (int rr = 0; rr < 4; rr++) {
                float p0 = exp2f(sa0[rr] * c2);
                float p1 = exp2f(sa1[rr] * c2);
                if (!full) {
                    const int i = qs + quad * 4 + rr;
                    const int j0 = ktb + l16, j1 = j0 + 16;
                    bool a0 = (j0 <= i) && ((i - j0 < WINDOW_) || (j0 < NGLOBAL));
                    bool a1 = (j1 <= i) && ((i - j1 < WINDOW_) || (j1 < NGLOBAL));
                    p0 = a0 ? p0 : 0.f;
                    p1 = a1 ? p1 : 0.f;
                }
                lr[rr] += p0 + p1;
                pw[(s * 16 + quad * 4 + rr) * 40 + l16]      = f2bf(p0);
                pw[(s * 16 + quad * 4 + rr) * 40 + 16 + l16] = f2bf(p1);
            }
        }
        bf16x8 pa0 = *(const bf16x8*)(pw + l16 * 40 + quad * 8);
        bf16x8 pa1 = *(const bf16x8*)(pw + (16 + l16) * 40 + quad * 8);

        {
            bf16x8 va[4];
            #pragma unroll
            for (int ds = 0; ds < 4; ds++) {
                const int d = ds * 16 + l16;
                va[ds] = *(const bf16x8*)&vbp[(d * 64 + ((quad * 16) ^ ((l16 & 3) << 4))) >> 1];
            }
            __builtin_amdgcn_s_setprio(1);
            #pragma unroll
            for (int ds = 0; ds < 4; ds++) {
                oacc0[ds] = __builtin_amdgcn_mfma_f32_16x16x32_bf16(pa0, va[ds], oacc0[ds], 0, 0, 0);
                oacc1[ds] = __builtin_amdgcn_mfma_f32_16x16x32_bf16(pa1, va[ds], oacc1[ds], 0, 0, 0);
            }
            __builtin_amdgcn_s_setprio(0);
        }
        {
            bf16x8 vb[4];
            #pragma unroll
            for (int ds = 0; ds < 4; ds++) {
                const int d = (ds + 4) * 16 + l16;
                vb[ds] = *(const bf16x8*)&vbp[(d * 64 + ((quad * 16) ^ ((l16 & 3) << 4))) >> 1];
            }
            __builtin_amdgcn_s_setprio(1);
            #pragma unroll
            for (int ds = 0; ds < 4; ds++) {
                oacc0[ds + 4] = __builtin_amdgcn_mfma_f32_16x16x32_bf16(pa0, vb[ds], oacc0[ds + 4], 0, 0, 0);
                oacc1[ds + 4] = __builtin_amdgcn_mfma_f32_16x16x32_bf16(pa1, vb[ds], oacc1[ds + 4], 0, 0, 0);
            }
            __builtin_amdgcn_s_setprio(0);
        }

        if (last) break;
        __syncthreads();
        cur ^= 1;
        kt = ktn;
    }

    #pragma unroll
    for (int off = 1; off <= 8; off <<= 1) {
        #pragma unroll
        for (int rr = 0; rr < 4; rr++) {
            lrow0[rr] += __shfl_xor(lrow0[rr], off);
            lrow1[rr] += __shfl_xor(lrow1[rr], off);
        }
    }

    #pragma unroll
    for (int s = 0; s < 2; s++) {
        const f32x4& lr = s ? lrow1 : lrow0;
        #pragma unroll
        for (int rr = 0; rr < 4; rr++) {
            float inv = 1.f / lr[rr];
            unsigned short* orow = O + ((size_t)(b * S_LEN + q0 + s * 16 + quad * 4 + rr)) * DMODEL + h * HD;
            #pragma unroll
            for (int ds = 0; ds < 8; ds++) {
                float v = s ? oacc1[ds][rr] : oacc0[ds][rr];
                orow[ds * 16 + l16] = f2bf(v * inv);
            }
        }
    }
}

// ---------------------------------------------------------------------------
extern "C" void kernel_launch(void* const* d_in, const int* in_sizes, int n_in,
                              void* d_out, int out_size, void* d_ws, size_t ws_size,
                              hipStream_t stream)
{
    const float* x    = (const float*)d_in[0];
    const float* wq_w = (const float*)d_in[1];
    const float* wq_a = (const float*)d_in[2];
    const float* wq_b = (const float*)d_in[3];
    const float* wk_w = (const float*)d_in[4];
    const float* wk_a = (const float*)d_in[5];
    const float* wk_b = (const float*)d_in[6];
    const float* wv_w = (const float*)d_in[7];
    const float* wv_a = (const float*)d_in[8];
    const float* wv_b = (const float*)d_in[9];
    const float* wo_w = (const float*)d_in[10];
    const float* wo_a = (const float*)d_in[11];
    const float* wo_b = (const float*)d_in[12];

    char* ws = (char*)d_ws;
    unsigned short* wqkvb  = (unsigned short*)(ws);                 // 3072x2048
    unsigned short* apackT = (unsigned short*)(ws + 12582912);      // 3x(2048x128)
    unsigned short* bqkvb  = (unsigned short*)(ws + 14155776);      // 3072x128
    unsigned short* Qbuf   = (unsigned short*)(ws + 18087936);      // 4096x2048
    unsigned short* Kbuf   = (unsigned short*)(ws + 34865152);      // 4096x512
    unsigned short* Vtbuf  = (unsigned short*)(ws + 39059456);      // 2x4x128x2048
    // post-qkv reuse of the dead wqkvb region:
    unsigned short* wowb   = (unsigned short*)(ws);                 // 2048x2048
    unsigned short* wobb   = (unsigned short*)(ws + 8388608);       // 2048x128
    unsigned short* woabT  = (unsigned short*)(ws + 8912896);       // 2048x128
    // x (bf16) lives in d_out's first 16 MB; dead before the final GEMM.
    unsigned short* xb = (unsigned short*)d_out;

    // conv1: x + QKV dense weights + B-matrices -> bf16
    Conv12 c1;
    c1.s[0] = x;    c1.d[0] = xb;                     // 4096
    c1.s[1] = wq_w; c1.d[1] = wqkvb;                  // 2048
    c1.s[2] = wk_w; c1.d[2] = wqkvb + 2048 * 2048;    // 512
    c1.s[3] = wv_w; c1.d[3] = wqkvb + 2560 * 2048;    // 512
    c1.s[4] = wq_b; c1.d[4] = bqkvb;                  // 128
    c1.s[5] = wk_b; c1.d[5] = bqkvb + 2048 * 128;     // 32
    c1.s[6] = wv_b; c1.d[6] = bqkvb + 2560 * 128;     // 32
    for (int i = 7; i < 12; i++) { c1.s[i] = wv_b; c1.d[i] = bqkvb + 2560 * 128; }
    int cum1[13] = {0, 4096, 6144, 6656, 7168, 7296, 7328, 7360, 7360, 7360,
                    7360, 7360, 7360};
    for (int i = 0; i < 13; i++) c1.c[i] = cum1[i];
    convk<<<dim3(7360), dim3(256), 0, stream>>>(c1);

    // A^T (bf16) for q,k,v
    TransA4 t1;
    t1.s[0] = wq_a; t1.d[0] = apackT;
    t1.s[1] = wk_a; t1.d[1] = apackT + 2048 * 128;
    t1.s[2] = wv_a; t1.d[2] = apackT + 2 * 2048 * 128;
    t1.s[3] = wq_a; t1.d[3] = apackT;
    transAk<<<dim3(384), dim3(256), 0, stream>>>(t1);

    // fold LoRA: Wqkv += Bqkv @ A
    weffk<<<dim3(24, 16), dim3(256), 0, stream>>>(wqkvb, DMODEL, bqkvb, apackT, 1);

    // Q/K/V + fused RoPE (V transposed into Vt)
    gemm128_qkv<<<dim3(32, 24), dim3(256), 0, stream>>>(
        xb, wqkvb, Qbuf, Kbuf, Vtbuf);

    // conv2 (over dead wqkvb region): wo_w, wo_b
    Conv12 c2;
    c2.s[0] = wo_w; c2.d[0] = wowb;   // 2048
    c2.s[1] = wo_b; c2.d[1] = wobb;   // 128
    for (int i = 2; i < 12; i++) { c2.s[i] = wo_b; c2.d[i] = wobb; }
    int cum2[13] = {0, 2048, 2176, 2176, 2176, 2176, 2176, 2176, 2176, 2176,
                    2176, 2176, 2176};
    for (int i = 0; i < 13; i++) c2.c[i] = cum2[i];
    convk<<<dim3(2176), dim3(256), 0, stream>>>(c2);

    TransA4 t2;
    t2.s[0] = wo_a; t2.d[0] = woabT;
    t2.s[1] = wo_a; t2.d[1] = woabT;
    t2.s[2] = wo_a; t2.d[2] = woabT;
    t2.s[3] = wo_a; t2.d[3] = woabT;
    transAk<<<dim3(128), dim3(256), 0, stream>>>(t2);

    // fold LoRA: Wo += Bo @ Ao
    weffk<<<dim3(16, 16), dim3(256), 0, stream>>>(wowb, DMODEL, wobb, woabT, 0);

    attn_mfma<<<dim3(512), dim3(256), 0, stream>>>(Qbuf, Kbuf, Vtbuf, Qbuf);

    // final: out = attn_out @ Weff_o^T  (fp32)
    gemm128_out<<<dim3(32, 16), dim3(256), 0, stream>>>(
        Qbuf, wowb, (float*)d_out);
}

// Round 9
// 308.119 us; speedup vs baseline: 1.3493x; 1.0287x over previous
//
#include <hip/hip_runtime.h>

#define B_ 2
#define S_LEN 2048
#define DMODEL 2048
#define NH 16
#define NKVH 4
#define HD 128
#define RLORA 128
#define WINDOW_ 512
#define NGLOBAL 64

#define FENCE asm volatile("" ::: "memory")

typedef __bf16 bf16x8 __attribute__((ext_vector_type(8)));
typedef float f32x4 __attribute__((ext_vector_type(4)));

__device__ __forceinline__ float bf2f(unsigned short h) {
    return __uint_as_float(((unsigned int)h) << 16);
}
__device__ __forceinline__ unsigned short f2bf(float f) {
    unsigned int u = __float_as_uint(f);
    unsigned int r = u + 0x7fffu + ((u >> 16) & 1u);
    return (unsigned short)(r >> 16);
}
__device__ __forceinline__ unsigned int pack2bf(float a, float b) {
    return (unsigned int)f2bf(a) | ((unsigned int)f2bf(b) << 16);
}
__device__ __forceinline__ uint4 load8f(const float* p) {
    float4 f0 = *(const float4*)p;
    float4 f1 = *(const float4*)(p + 4);
    uint4 u;
    u.x = pack2bf(f0.x, f0.y);
    u.y = pack2bf(f0.z, f0.w);
    u.z = pack2bf(f1.x, f1.y);
    u.w = pack2bf(f1.z, f1.w);
    return u;
}

// Async global->LDS, 16 B per lane. LDS dest = wave-uniform base + lane*16.
__device__ __forceinline__ void gld16(const unsigned short* g, unsigned short* l) {
    __builtin_amdgcn_global_load_lds(
        (const __attribute__((address_space(1))) unsigned int*)g,
        (__attribute__((address_space(3))) unsigned int*)l,
        16, 0, 0);
}

// ---------------------------------------------------------------------------
// Batched fp32 -> bf16 conversion over up to 12 tensors. 2048 elems/block.
// R9: only x + B-matrices go through here (dense W handled by weffk).
// ---------------------------------------------------------------------------
struct Conv12 {
    const float* s[12];
    unsigned short* d[12];
    int c[13];
};
__global__ __launch_bounds__(256) void convk(Conv12 a)
{
    int b = blockIdx.x;
    int seg = 0;
    while (b >= a.c[seg + 1]) seg++;
    int off = (b - a.c[seg]) * 2048 + threadIdx.x * 8;
    *(uint4*)(a.d[seg] + off) = load8f(a.s[seg] + off);
}

// ---------------------------------------------------------------------------
// Transpose-convert: A (128 x 2048 fp32) -> At (2048 x 128 bf16).
// ---------------------------------------------------------------------------
struct TransA4 { const float* s[4]; unsigned short* d[4]; };
__global__ __launch_bounds__(256) void transAk(TransA4 a)
{
    __shared__ float tile[32][65];
    const int bid = blockIdx.x;
    const int mat = bid >> 7;
    const int tl = bid & 127;
    const int rt = tl & 3, ct = tl >> 2;
    const float* src = a.s[mat];
    unsigned short* dst = a.d[mat];
    const int t = threadIdx.x;
    #pragma unroll
    for (int p = 0; p < 2; p++) {
        int r = p * 16 + (t >> 4);
        int c = (t & 15) * 4;
        float4 v = *(const float4*)(src + (size_t)(rt * 32 + r) * 2048 + ct * 64 + c);
        tile[r][c] = v.x; tile[r][c + 1] = v.y;
        tile[r][c + 2] = v.z; tile[r][c + 3] = v.w;
    }
    __syncthreads();
    const int n = t >> 2, r8 = (t & 3) * 8;
    uint4 u;
    u.x = pack2bf(tile[r8 + 0][n], tile[r8 + 1][n]);
    u.y = pack2bf(tile[r8 + 2][n], tile[r8 + 3][n]);
    u.z = pack2bf(tile[r8 + 4][n], tile[r8 + 5][n]);
    u.w = pack2bf(tile[r8 + 6][n], tile[r8 + 7][n]);
    *(uint4*)(dst + (size_t)(ct * 64 + n) * 128 + rt * 32 + r8) = u;
}

// ---------------------------------------------------------------------------
// LoRA weight fold + fp32 convert: C[m][n] = bf16(W_f32[m][n] + B@A).
// R9: reads dense W in fp32 directly (conv pass for W removed; one fewer
// rounding of W). Tile 128x128, K=128. seg: 1 = qkv row-segmented sources.
// ---------------------------------------------------------------------------
__global__ __launch_bounds__(256) void weffk(
    unsigned short* __restrict__ C, int ldc,
    const float* __restrict__ W0, const float* __restrict__ W1,
    const float* __restrict__ W2,
    const unsigned short* __restrict__ Bm,
    const unsigned short* __restrict__ At,
    int seg)
{
    const int m0 = blockIdx.x * 128;
    const int n0 = blockIdx.y * 128;
    const unsigned short* Atb = At;
    const float* Wsrc = W0;
    int wrow = m0;
    if (seg) {
        if (m0 >= 2560)      { Atb = At + 2 * 2048 * 128; Wsrc = W2; wrow = m0 - 2560; }
        else if (m0 >= 2048) { Atb = At + 2048 * 128;     Wsrc = W1; wrow = m0 - 2048; }
    }
    __shared__ __align__(16) unsigned short As_[128 * 32];
    __shared__ __align__(16) unsigned short Bs_[128 * 32];
    const int tid = threadIdx.x, lane = tid & 63, wid = tid >> 6;
    const int quad = lane >> 4, l16 = lane & 15;
    const int lr = lane >> 2, lc8 = (lane & 3) * 8;
    const int wm0 = (wid >> 1) * 64, wn0 = (wid & 1) * 64;
    f32x4 acc[4][4] = {};
    for (int k0 = 0; k0 < 128; k0 += 32) {
        #pragma unroll
        for (int c = 0; c < 2; c++) {
            int chunk = wid * 2 + c;
            gld16(Bm + (size_t)(m0 + chunk * 16 + lr) * 128 + k0 + lc8, As_ + chunk * 512);
            gld16(Atb + (size_t)(n0 + chunk * 16 + lr) * 128 + k0 + lc8, Bs_ + chunk * 512);
        }
        __syncthreads();
        bf16x8 af[4], bf[4];
        #pragma unroll
        for (int i = 0; i < 4; i++)
            af[i] = *(const bf16x8*)&As_[(wm0 + i * 16 + l16) * 32 + quad * 8];
        #pragma unroll
        for (int j = 0; j < 4; j++)
            bf[j] = *(const bf16x8*)&Bs_[(wn0 + j * 16 + l16) * 32 + quad * 8];
        #pragma unroll
        for (int i = 0; i < 4; i++)
            #pragma unroll
            for (int j = 0; j < 4; j++)
                acc[i][j] = __builtin_amdgcn_mfma_f32_16x16x32_bf16(af[i], bf[j], acc[i][j], 0, 0, 0);
        __syncthreads();
    }
    #pragma unroll
    for (int i = 0; i < 4; i++)
        #pragma unroll
        for (int j = 0; j < 4; j++) {
            const int col = n0 + wn0 + j * 16 + l16;
            #pragma unroll
            for (int r = 0; r < 4; r++) {
                const int row = wm0 + i * 16 + quad * 4 + r;
                float w = Wsrc[(size_t)(wrow + row) * 2048 + col];
                C[(size_t)(m0 + row) * ldc + col] = f2bf(w + acc[i][j][r]);
            }
        }
}

// ---------------------------------------------------------------------------
// R9 GEMM core: BM=128, BN=128, BK=32, 4 waves (2x2 -> wave 64x64),
// 48 KiB LDS = 3-buffer rotation -> ONE barrier per K-tile (the 2nd barrier
// only protected stage(t+2) overwriting the just-read buffer; with 3 bufs
// stage targets (bb+2)%3, whose last readers finished before this tile's
// top barrier). Still 3 blocks/CU (144 KiB). Counted vmcnt(4): at tile-t
// top, outstanding = {stage(t):4, stage(t+1):4}; vmcnt(4) retires stage(t);
// own-drain-then-barrier => all waves' tile-t loads landed after barrier.
// Swizzle both-sides with row bits [2:1] (R7-verified: conflicts = 0).
// Layouts (validated): A-frag lane=A[m=l16][k=quad*8+j]; B-frag
// lane=B[k][n=l16]; C/D col=l16, row=quad*4+r.
// ---------------------------------------------------------------------------
__device__ __forceinline__ void gemm128_acc(
    const unsigned short* __restrict__ A, int lda, int m0,
    const unsigned short* __restrict__ W, int ldw, int n0,
    int Kmain, f32x4 (&acc)[4][4])
{
    __shared__ __align__(16) unsigned short As[3][4096];
    __shared__ __align__(16) unsigned short Bs[3][4096];
    const int tid = threadIdx.x;
    const int lane = tid & 63, wid = tid >> 6;
    const int quad = lane >> 4, l16 = lane & 15;
    const int wm = (wid >> 1) * 64, wn = (wid & 1) * 64;

    // staging source map: LDS linear; src 16B-slot pre-swizzled (row[2:1]).
    int arow[2], acol[2];
    #pragma unroll
    for (int c = 0; c < 2; c++) {
        const int o = tid * 16 + c * 4096;          // byte offset in 8KB tile
        arow[c] = o >> 6;                           // row (64B rows)
        acol[c] = (((tid & 3) * 16) ^ (((arow[c] >> 1) & 3) << 4)) >> 1;
    }

    const int nt = Kmain >> 5;

    auto stage = [&](int bb, int j) {
        const int k0 = j << 5;
        #pragma unroll
        for (int c = 0; c < 2; c++)
            gld16(A + (size_t)(m0 + arow[c]) * lda + k0 + acol[c],
                  &As[bb][tid * 8 + c * 2048]);
        #pragma unroll
        for (int c = 0; c < 2; c++)
            gld16(W + (size_t)(n0 + arow[c]) * ldw + k0 + acol[c],
                  &Bs[bb][tid * 8 + c * 2048]);
    };

    // fragment read offset (shorts): slot XOR with row bits [2:1] (= l16>>1).
    const int xoff = (((quad * 16) ^ (((l16 >> 1) & 3) << 4)) >> 1);
    const int ard = (wm + l16) * 32 + xoff;
    const int brd = (wn + l16) * 32 + xoff;

    stage(0, 0);
    stage(1, 1);

    int bb = 0;
    for (int t = 0; t < nt; t++) {
        if (t < nt - 1) {
            asm volatile("s_waitcnt vmcnt(4)" ::: "memory");
        } else {
            asm volatile("s_waitcnt vmcnt(0)" ::: "memory");
        }
        __builtin_amdgcn_sched_barrier(0);
        FENCE; __builtin_amdgcn_s_barrier(); FENCE;

        bf16x8 af[4], bfn[4];
        #pragma unroll
        for (int mi = 0; mi < 4; mi++)
            af[mi] = *(const bf16x8*)&As[bb][ard + mi * 512];
        #pragma unroll
        for (int ni = 0; ni < 4; ni++)
            bfn[ni] = *(const bf16x8*)&Bs[bb][brd + ni * 512];

        __builtin_amdgcn_s_setprio(1);
        #pragma unroll
        for (int mi = 0; mi < 4; mi++)
            #pragma unroll
            for (int ni = 0; ni < 4; ni++)
                acc[mi][ni] = __builtin_amdgcn_mfma_f32_16x16x32_bf16(
                    af[mi], bfn[ni], acc[mi][ni], 0, 0, 0);
        __builtin_amdgcn_s_setprio(0);

        if (t + 2 < nt) {
            int sb = bb + 2; if (sb >= 3) sb -= 3;
            stage(sb, t + 2);
        }
        bb = (bb == 2) ? 0 : bb + 1;
    }
}

// RoPE applied in-register to one acc column-vector (4 rows).
__device__ __forceinline__ f32x4 rope4(f32x4 v, int col, int rowbase)
{
    const int t2 = col & 127;
    const float invf = __expf(-(float)(t2 >> 1) * (13.815510557964274f / 64.0f));
    const bool ev = (t2 & 1) == 0;
    f32x4 o;
    #pragma unroll
    for (int r = 0; r < 4; r++) {
        float self = v[r];
        float other = __shfl_xor(self, 1);
        float pos = (float)((rowbase + r) & (S_LEN - 1));
        float s, c;
        __sincosf(pos * invf, &s, &c);
        o[r] = ev ? (self * c - other * s) : (other * s + self * c);
    }
    return o;
}

// Fused QKV + RoPE on the R9 core. Grid (32, 24): by<16 Q, 16-19 K, 20-23 V.
__global__ __launch_bounds__(256, 3) void gemm128_qkv(
    const unsigned short* __restrict__ Xb,
    const unsigned short* __restrict__ Wqkv,
    unsigned short* __restrict__ Qo, unsigned short* __restrict__ Ko,
    unsigned short* __restrict__ Vt)
{
    const int m0 = blockIdx.x * 128;
    const int n0 = blockIdx.y * 128;
    f32x4 acc[4][4] = {};
    gemm128_acc(Xb, DMODEL, m0, Wqkv, DMODEL, n0, DMODEL, acc);

    const int tid = threadIdx.x, lane = tid & 63, wid = tid >> 6;
    const int l16 = lane & 15, quad = lane >> 4;
    const int wm = (wid >> 1) * 64, wn = (wid & 1) * 64;

    if (n0 < 2048) {
        #pragma unroll
        for (int mi = 0; mi < 4; mi++)
            #pragma unroll
            for (int ni = 0; ni < 4; ni++) {
                const int col = n0 + wn + ni * 16 + l16;
                const int rb = m0 + wm + mi * 16 + quad * 4;
                f32x4 v = rope4(acc[mi][ni], col, rb);
                #pragma unroll
                for (int r = 0; r < 4; r++)
                    Qo[(size_t)(rb + r) * DMODEL + col] = f2bf(v[r]);
            }
    } else if (n0 < 2560) {
        #pragma unroll
        for (int mi = 0; mi < 4; mi++)
            #pragma unroll
            for (int ni = 0; ni < 4; ni++) {
                const int col = n0 - 2048 + wn + ni * 16 + l16;
                const int rb = m0 + wm + mi * 16 + quad * 4;
                f32x4 v = rope4(acc[mi][ni], col, rb);
                #pragma unroll
                for (int r = 0; r < 4; r++)
                    Ko[(size_t)(rb + r) * 512 + col] = f2bf(v[r]);
            }
    } else {
        const int b = m0 >> 11;
        #pragma unroll
        for (int mi = 0; mi < 4; mi++)
            #pragma unroll
            for (int ni = 0; ni < 4; ni++) {
                const int ncol = n0 - 2560 + wn + ni * 16 + l16;
                const int head = ncol >> 7, dd = ncol & 127;
                const int srow = (m0 & (S_LEN - 1)) + wm + mi * 16 + quad * 4;
                uint2 pk;
                pk.x = pack2bf(acc[mi][ni][0], acc[mi][ni][1]);
                pk.y = pack2bf(acc[mi][ni][2], acc[mi][ni][3]);
                *(uint2*)(Vt + ((size_t)(b * NKVH + head) * HD + dd) * S_LEN + srow) = pk;
            }
    }
}

// Output projection on the R9 core. Grid (32, 16) = 512 blocks, fp32 out.
__global__ __launch_bounds__(256, 3) void gemm128_out(
    const unsigned short* __restrict__ Xb,
    const unsigned short* __restrict__ Ww,
    float* __restrict__ Out)
{
    const int m0 = blockIdx.x * 128;
    const int n0 = blockIdx.y * 128;
    f32x4 acc[4][4] = {};
    gemm128_acc(Xb, DMODEL, m0, Ww, DMODEL, n0, DMODEL, acc);

    const int tid = threadIdx.x, lane = tid & 63, wid = tid >> 6;
    const int l16 = lane & 15, quad = lane >> 4;
    const int wm = (wid >> 1) * 64, wn = (wid & 1) * 64;
    #pragma unroll
    for (int mi = 0; mi < 4; mi++)
        #pragma unroll
        for (int ni = 0; ni < 4; ni++) {
            const int col = n0 + wn + ni * 16 + l16;
            const size_t rb = (size_t)(m0 + wm + mi * 16 + quad * 4);
            #pragma unroll
            for (int r = 0; r < 4; r++)
                Out[(rb + r) * DMODEL + col] = acc[mi][ni][r];
        }
}

// ---------------------------------------------------------------------------
// MFMA flash attention v4: LDS-staged K/V shared by the whole block.
// R9: occupancy cap 2->3 blocks/CU (42 KiB LDS; dynamic tail balancing).
// ---------------------------------------------------------------------------
__global__ __launch_bounds__(256, 3) void attn_mfma(
    const unsigned short* __restrict__ Q,
    const unsigned short* __restrict__ K,
    const unsigned short* __restrict__ Vt,
    unsigned short* __restrict__ O)
{
    __shared__ __align__(16) unsigned short kvbuf[2][8192];
    __shared__ unsigned short plds[4][32 * 40];
    const int tid = threadIdx.x, lane = tid & 63, wid = tid >> 6;
    const int l16 = lane & 15, quad = lane >> 4;
    const int bid = blockIdx.x;
    const int g   = bid & 7;
    const int kvh = g & 3;
    const int b   = g >> 2;
    const int qt  = 63 - (bid >> 3);
    const int q0  = qt * 32;
    const int h   = kvh * 4 + wid;

    const unsigned short* qrow0 = Q + ((size_t)(b * S_LEN + q0 + l16)) * DMODEL + h * HD;
    bf16x8 qf0[4], qf1[4];
    #pragma unroll
    for (int c = 0; c < 4; c++) {
        qf0[c] = *(const bf16x8*)(qrow0 + c * 32 + quad * 8);
        qf1[c] = *(const bf16x8*)(qrow0 + (size_t)16 * DMODEL + c * 32 + quad * 8);
    }

    const unsigned short* Kbase  = K + ((size_t)(b * S_LEN)) * (NKVH * HD) + kvh * HD;
    const unsigned short* Vplane = Vt + ((size_t)(b * NKVH + kvh) * HD) * S_LEN;
    unsigned short* pw = &plds[wid][0];

    const unsigned short* Ksrc[2];
    const unsigned short* Vsrc[2];
    #pragma unroll
    for (int c = 0; c < 2; c++) {
        const int o = wid * 2048 + c * 1024 + lane * 16;
        const int kkey = o >> 8;
        const int kdim = (o & 255) ^ ((kkey & 15) << 4);
        Ksrc[c] = Kbase + (size_t)kkey * (NKVH * HD) + (kdim >> 1);
        const int vd = o >> 6;
        const int vkb = (o & 63) ^ ((vd & 3) << 4);
        Vsrc[c] = Vplane + (size_t)vd * S_LEN + (vkb >> 1);
    }

    f32x4 oacc0[8] = {}, oacc1[8] = {};
    f32x4 lrow0 = {0.f, 0.f, 0.f, 0.f}, lrow1 = {0.f, 0.f, 0.f, 0.f};
    const float c2 = 0.12753102f;

    const int kthi = (q0 + 31) >> 5;
    int wlo = q0 - (WINDOW_ - 1); if (wlo < 0) wlo = 0;
    const int ktw = wlo >> 5;

    auto nexttile = [&](int t) -> int {
        if (t < ktw) { int u = t + 1; return (u < 2 && u < ktw) ? u : ktw; }
        return t + 1;
    };

    auto stage = [&](int buf, int ktb) {
        #pragma unroll
        for (int c = 0; c < 2; c++) {
            gld16(Ksrc[c] + (size_t)ktb * (NKVH * HD),
                  &kvbuf[buf][wid * 1024 + c * 512]);
            gld16(Vsrc[c] + ktb,
                  &kvbuf[buf][4096 + wid * 1024 + c * 512]);
        }
    };

    int kt = 0;
    stage(0, 0);
    __syncthreads();
    int cur = 0;

    while (true) {
        const int ktb = kt * 32;
        const int ktn = nexttile(kt);
        const bool last = (ktn > kthi);
        if (!last) stage(cur ^ 1, ktn * 32);

        const unsigned short* kb  = kvbuf[cur];
        const unsigned short* vbp = kvbuf[cur] + 4096;

        bf16x8 kf0[4], kf1[4];
        #pragma unroll
        for (int c = 0; c < 4; c++) {
            const int koff = (l16 * 256 + ((c * 64 + quad * 16) ^ (l16 << 4))) >> 1;
            kf0[c] = *(const bf16x8*)&kb[koff];
            kf1[c] = *(const bf16x8*)&kb[koff + 2048];
        }

        f32x4 s00 = {}, s01 = {}, s10 = {}, s11 = {};
        __builtin_amdgcn_s_setprio(1);
        #pragma unroll
        for (int c = 0; c < 4; c++) {
            s00 = __builtin_amdgcn_mfma_f32_16x16x32_bf16(qf0[c], kf0[c], s00, 0, 0, 0);
            s01 = __builtin_amdgcn_mfma_f32_16x16x32_bf16(qf0[c], kf1[c], s01, 0, 0, 0);
            s10 = __builtin_amdgcn_mfma_f32_16x16x32_bf16(qf1[c], kf0[c], s10, 0, 0, 0);
            s11 = __builtin_amdgcn_mfma_f32_16x16x32_bf16(qf1[c], kf1[c], s11, 0, 0, 0);
        }
        __builtin_amdgcn_s_setprio(0);

        #pragma unroll
        for (int s = 0; s < 2; s++) {
            const f32x4 sa0 = s ? s10 : s00;
            const f32x4 sa1 = s ? s11 : s01;
            const int qs = q0 + s * 16;
            const bool full = (ktb + 31 <= qs) &&
                              (((qs + 15) - ktb < WINDOW_) || (ktb + 31 < NGLOBAL));
            f32x4& lr = s ? lrow1 : lrow0;
            #pragma unroll
            for (int rr = 0; rr < 4; rr++) {
                float p0 = exp2f(sa0[rr] * c2);
                float p1 = exp2f(sa1[rr] * c2);
                if (!full) {
                    const int i = qs + quad * 4 + rr;
                    const int j0 = ktb + l16, j1 = j0 + 16;
                    bool a0 = (j0 <= i) && ((i - j0 < WINDOW_) || (j0 < NGLOBAL));
                    bool a1 = (j1 <= i) && ((i - j1 < WINDOW_) || (j1 < NGLOBAL));
                    p0 = a0 ? p0 : 0.f;
                    p1 = a1 ? p1 : 0.f;
                }
                lr[rr] += p0 + p1;
                pw[(s * 16 + quad * 4 + rr) * 40 + l16]      = f2bf(p0);
                pw[(s * 16 + quad * 4 + rr) * 40 + 16 + l16] = f2bf(p1);
            }
        }
        bf16x8 pa0 = *(const bf16x8*)(pw + l16 * 40 + quad * 8);
        bf16x8 pa1 = *(const bf16x8*)(pw + (16 + l16) * 40 + quad * 8);

        {
            bf16x8 va[4];
            #pragma unroll
            for (int ds = 0; ds < 4; ds++) {
                const int d = ds * 16 + l16;
                va[ds] = *(const bf16x8*)&vbp[(d * 64 + ((quad * 16) ^ ((l16 & 3) << 4))) >> 1];
            }
            __builtin_amdgcn_s_setprio(1);
            #pragma unroll
            for (int ds = 0; ds < 4; ds++) {
                oacc0[ds] = __builtin_amdgcn_mfma_f32_16x16x32_bf16(pa0, va[ds], oacc0[ds], 0, 0, 0);
                oacc1[ds] = __builtin_amdgcn_mfma_f32_16x16x32_bf16(pa1, va[ds], oacc1[ds], 0, 0, 0);
            }
            __builtin_amdgcn_s_setprio(0);
        }
        {
            bf16x8 vb[4];
            #pragma unroll
            for (int ds = 0; ds < 4; ds++) {
                const int d = (ds + 4) * 16 + l16;
                vb[ds] = *(const bf16x8*)&vbp[(d * 64 + ((quad * 16) ^ ((l16 & 3) << 4))) >> 1];
            }
            __builtin_amdgcn_s_setprio(1);
            #pragma unroll
            for (int ds = 0; ds < 4; ds++) {
                oacc0[ds + 4] = __builtin_amdgcn_mfma_f32_16x16x32_bf16(pa0, vb[ds], oacc0[ds + 4], 0, 0, 0);
                oacc1[ds + 4] = __builtin_amdgcn_mfma_f32_16x16x32_bf16(pa1, vb[ds], oacc1[ds + 4], 0, 0, 0);
            }
            __builtin_amdgcn_s_setprio(0);
        }

        if (last) break;
        __syncthreads();
        cur ^= 1;
        kt = ktn;
    }

    #pragma unroll
    for (int off = 1; off <= 8; off <<= 1) {
        #pragma unroll
        for (int rr = 0; rr < 4; rr++) {
            lrow0[rr] += __shfl_xor(lrow0[rr], off);
            lrow1[rr] += __shfl_xor(lrow1[rr], off);
        }
    }

    #pragma unroll
    for (int s = 0; s < 2; s++) {
        const f32x4& lr = s ? lrow1 : lrow0;
        #pragma unroll
        for (int rr = 0; rr < 4; rr++) {
            float inv = 1.f / lr[rr];
            unsigned short* orow = O + ((size_t)(b * S_LEN + q0 + s * 16 + quad * 4 + rr)) * DMODEL + h * HD;
            #pragma unroll
            for (int ds = 0; ds < 8; ds++) {
                float v = s ? oacc1[ds][rr] : oacc0[ds][rr];
                orow[ds * 16 + l16] = f2bf(v * inv);
            }
        }
    }
}

// ---------------------------------------------------------------------------
extern "C" void kernel_launch(void* const* d_in, const int* in_sizes, int n_in,
                              void* d_out, int out_size, void* d_ws, size_t ws_size,
                              hipStream_t stream)
{
    const float* x    = (const float*)d_in[0];
    const float* wq_w = (const float*)d_in[1];
    const float* wq_a = (const float*)d_in[2];
    const float* wq_b = (const float*)d_in[3];
    const float* wk_w = (const float*)d_in[4];
    const float* wk_a = (const float*)d_in[5];
    const float* wk_b = (const float*)d_in[6];
    const float* wv_w = (const float*)d_in[7];
    const float* wv_a = (const float*)d_in[8];
    const float* wv_b = (const float*)d_in[9];
    const float* wo_w = (const float*)d_in[10];
    const float* wo_a = (const float*)d_in[11];
    const float* wo_b = (const float*)d_in[12];

    char* ws = (char*)d_ws;
    unsigned short* wqkvb  = (unsigned short*)(ws);                 // 3072x2048
    unsigned short* apackT = (unsigned short*)(ws + 12582912);      // 3x(2048x128)
    unsigned short* bqkvb  = (unsigned short*)(ws + 14155776);      // 3072x128
    unsigned short* Qbuf   = (unsigned short*)(ws + 18087936);      // 4096x2048
    unsigned short* Kbuf   = (unsigned short*)(ws + 34865152);      // 4096x512
    unsigned short* Vtbuf  = (unsigned short*)(ws + 39059456);      // 2x4x128x2048
    // post-qkv reuse of the dead wqkvb region:
    unsigned short* wowb   = (unsigned short*)(ws);                 // 2048x2048
    unsigned short* wobb   = (unsigned short*)(ws + 8388608);       // 2048x128
    unsigned short* woabT  = (unsigned short*)(ws + 8912896);       // 2048x128
    // x (bf16) lives in d_out's first 16 MB; dead before the final GEMM.
    unsigned short* xb = (unsigned short*)d_out;

    // conv1: x + qkv B-matrices -> bf16 (dense W handled inside weffk)
    Conv12 c1;
    c1.s[0] = x;    c1.d[0] = xb;                     // 4096
    c1.s[1] = wq_b; c1.d[1] = bqkvb;                  // 128
    c1.s[2] = wk_b; c1.d[2] = bqkvb + 2048 * 128;     // 32
    c1.s[3] = wv_b; c1.d[3] = bqkvb + 2560 * 128;     // 32
    for (int i = 4; i < 12; i++) { c1.s[i] = wv_b; c1.d[i] = bqkvb + 2560 * 128; }
    int cum1[13] = {0, 4096, 4224, 4256, 4288, 4288, 4288, 4288, 4288, 4288,
                    4288, 4288, 4288};
    for (int i = 0; i < 13; i++) c1.c[i] = cum1[i];
    convk<<<dim3(4288), dim3(256), 0, stream>>>(c1);

    // A^T (bf16) for q,k,v
    TransA4 t1;
    t1.s[0] = wq_a; t1.d[0] = apackT;
    t1.s[1] = wk_a; t1.d[1] = apackT + 2048 * 128;
    t1.s[2] = wv_a; t1.d[2] = apackT + 2 * 2048 * 128;
    t1.s[3] = wq_a; t1.d[3] = apackT;
    transAk<<<dim3(384), dim3(256), 0, stream>>>(t1);

    // Weff_qkv = fp32(Wqkv) + Bqkv @ A  -> bf16
    weffk<<<dim3(24, 16), dim3(256), 0, stream>>>(
        wqkvb, DMODEL, wq_w, wk_w, wv_w, bqkvb, apackT, 1);

    // Q/K/V + fused RoPE (V transposed into Vt)
    gemm128_qkv<<<dim3(32, 24), dim3(256), 0, stream>>>(
        xb, wqkvb, Qbuf, Kbuf, Vtbuf);

    // conv2 (over dead wqkvb region): wo_b only
    Conv12 c2;
    c2.s[0] = wo_b; c2.d[0] = wobb;   // 128
    for (int i = 1; i < 12; i++) { c2.s[i] = wo_b; c2.d[i] = wobb; }
    int cum2[13] = {0, 128, 128, 128, 128, 128, 128, 128, 128, 128,
                    128, 128, 128};
    for (int i = 0; i < 13; i++) c2.c[i] = cum2[i];
    convk<<<dim3(128), dim3(256), 0, stream>>>(c2);

    TransA4 t2;
    t2.s[0] = wo_a; t2.d[0] = woabT;
    t2.s[1] = wo_a; t2.d[1] = woabT;
    t2.s[2] = wo_a; t2.d[2] = woabT;
    t2.s[3] = wo_a; t2.d[3] = woabT;
    transAk<<<dim3(128), dim3(256), 0, stream>>>(t2);

    // Weff_o = fp32(Wo) + Bo @ Ao -> bf16
    weffk<<<dim3(16, 16), dim3(256), 0, stream>>>(
        wowb, DMODEL, wo_w, wo_w, wo_w, wobb, woabT, 0);

    attn_mfma<<<dim3(512), dim3(256), 0, stream>>>(Qbuf, Kbuf, Vtbuf, Qbuf);

    // final: out = attn_out @ Weff_o^T  (fp32)
    gemm128_out<<<dim3(32, 16), dim3(256), 0, stream>>>(
        Qbuf, wowb, (float*)d_out);
}

// Round 10
// 305.410 us; speedup vs baseline: 1.3613x; 1.0089x over previous
//
#include <hip/hip_runtime.h>

#define B_ 2
#define S_LEN 2048
#define DMODEL 2048
#define NH 16
#define NKVH 4
#define HD 128
#define RLORA 128
#define WINDOW_ 512
#define NGLOBAL 64

#define FENCE asm volatile("" ::: "memory")

typedef __bf16 bf16x8 __attribute__((ext_vector_type(8)));
typedef float f32x4 __attribute__((ext_vector_type(4)));

__device__ __forceinline__ float bf2f(unsigned short h) {
    return __uint_as_float(((unsigned int)h) << 16);
}
__device__ __forceinline__ unsigned short f2bf(float f) {
    unsigned int u = __float_as_uint(f);
    unsigned int r = u + 0x7fffu + ((u >> 16) & 1u);
    return (unsigned short)(r >> 16);
}
__device__ __forceinline__ unsigned int pack2bf(float a, float b) {
    return (unsigned int)f2bf(a) | ((unsigned int)f2bf(b) << 16);
}
__device__ __forceinline__ uint4 load8f(const float* p) {
    float4 f0 = *(const float4*)p;
    float4 f1 = *(const float4*)(p + 4);
    uint4 u;
    u.x = pack2bf(f0.x, f0.y);
    u.y = pack2bf(f0.z, f0.w);
    u.z = pack2bf(f1.x, f1.y);
    u.w = pack2bf(f1.z, f1.w);
    return u;
}

// Async global->LDS, 16 B per lane. LDS dest = wave-uniform base + lane*16.
__device__ __forceinline__ void gld16(const unsigned short* g, unsigned short* l) {
    __builtin_amdgcn_global_load_lds(
        (const __attribute__((address_space(1))) unsigned int*)g,
        (__attribute__((address_space(3))) unsigned int*)l,
        16, 0, 0);
}

// ---------------------------------------------------------------------------
// Batched fp32 -> bf16 conversion (x + B-matrices only).
// ---------------------------------------------------------------------------
struct Conv12 {
    const float* s[12];
    unsigned short* d[12];
    int c[13];
};
__global__ __launch_bounds__(256) void convk(Conv12 a)
{
    int b = blockIdx.x;
    int seg = 0;
    while (b >= a.c[seg + 1]) seg++;
    int off = (b - a.c[seg]) * 2048 + threadIdx.x * 8;
    *(uint4*)(a.d[seg] + off) = load8f(a.s[seg] + off);
}

// ---------------------------------------------------------------------------
// Transpose-convert: A (128 x 2048 fp32) -> At (2048 x 128 bf16).
// ---------------------------------------------------------------------------
struct TransA4 { const float* s[4]; unsigned short* d[4]; };
__global__ __launch_bounds__(256) void transAk(TransA4 a)
{
    __shared__ float tile[32][65];
    const int bid = blockIdx.x;
    const int mat = bid >> 7;
    const int tl = bid & 127;
    const int rt = tl & 3, ct = tl >> 2;
    const float* src = a.s[mat];
    unsigned short* dst = a.d[mat];
    const int t = threadIdx.x;
    #pragma unroll
    for (int p = 0; p < 2; p++) {
        int r = p * 16 + (t >> 4);
        int c = (t & 15) * 4;
        float4 v = *(const float4*)(src + (size_t)(rt * 32 + r) * 2048 + ct * 64 + c);
        tile[r][c] = v.x; tile[r][c + 1] = v.y;
        tile[r][c + 2] = v.z; tile[r][c + 3] = v.w;
    }
    __syncthreads();
    const int n = t >> 2, r8 = (t & 3) * 8;
    uint4 u;
    u.x = pack2bf(tile[r8 + 0][n], tile[r8 + 1][n]);
    u.y = pack2bf(tile[r8 + 2][n], tile[r8 + 3][n]);
    u.z = pack2bf(tile[r8 + 4][n], tile[r8 + 5][n]);
    u.w = pack2bf(tile[r8 + 6][n], tile[r8 + 7][n]);
    *(uint4*)(dst + (size_t)(ct * 64 + n) * 128 + rt * 32 + r8) = u;
}

// ---------------------------------------------------------------------------
// LoRA weight fold + fp32 convert: C[m][n] = bf16(W_f32[m][n] + B@A).
// Tile 128x128, K=128. seg: 1 = qkv row-segmented sources.
// ---------------------------------------------------------------------------
__global__ __launch_bounds__(256) void weffk(
    unsigned short* __restrict__ C, int ldc,
    const float* __restrict__ W0, const float* __restrict__ W1,
    const float* __restrict__ W2,
    const unsigned short* __restrict__ Bm,
    const unsigned short* __restrict__ At,
    int seg)
{
    const int m0 = blockIdx.x * 128;
    const int n0 = blockIdx.y * 128;
    const unsigned short* Atb = At;
    const float* Wsrc = W0;
    int wrow = m0;
    if (seg) {
        if (m0 >= 2560)      { Atb = At + 2 * 2048 * 128; Wsrc = W2; wrow = m0 - 2560; }
        else if (m0 >= 2048) { Atb = At + 2048 * 128;     Wsrc = W1; wrow = m0 - 2048; }
    }
    __shared__ __align__(16) unsigned short As_[128 * 32];
    __shared__ __align__(16) unsigned short Bs_[128 * 32];
    const int tid = threadIdx.x, lane = tid & 63, wid = tid >> 6;
    const int quad = lane >> 4, l16 = lane & 15;
    const int lr = lane >> 2, lc8 = (lane & 3) * 8;
    const int wm0 = (wid >> 1) * 64, wn0 = (wid & 1) * 64;
    f32x4 acc[4][4] = {};
    for (int k0 = 0; k0 < 128; k0 += 32) {
        #pragma unroll
        for (int c = 0; c < 2; c++) {
            int chunk = wid * 2 + c;
            gld16(Bm + (size_t)(m0 + chunk * 16 + lr) * 128 + k0 + lc8, As_ + chunk * 512);
            gld16(Atb + (size_t)(n0 + chunk * 16 + lr) * 128 + k0 + lc8, Bs_ + chunk * 512);
        }
        __syncthreads();
        bf16x8 af[4], bf[4];
        #pragma unroll
        for (int i = 0; i < 4; i++)
            af[i] = *(const bf16x8*)&As_[(wm0 + i * 16 + l16) * 32 + quad * 8];
        #pragma unroll
        for (int j = 0; j < 4; j++)
            bf[j] = *(const bf16x8*)&Bs_[(wn0 + j * 16 + l16) * 32 + quad * 8];
        #pragma unroll
        for (int i = 0; i < 4; i++)
            #pragma unroll
            for (int j = 0; j < 4; j++)
                acc[i][j] = __builtin_amdgcn_mfma_f32_16x16x32_bf16(af[i], bf[j], acc[i][j], 0, 0, 0);
        __syncthreads();
    }
    #pragma unroll
    for (int i = 0; i < 4; i++)
        #pragma unroll
        for (int j = 0; j < 4; j++) {
            const int col = n0 + wn0 + j * 16 + l16;
            #pragma unroll
            for (int r = 0; r < 4; r++) {
                const int row = wm0 + i * 16 + quad * 4 + r;
                float w = Wsrc[(size_t)(wrow + row) * 2048 + col];
                C[(size_t)(m0 + row) * ldc + col] = f2bf(w + acc[i][j][r]);
            }
        }
}

// ---------------------------------------------------------------------------
// R10 GEMM core == R8 core (REVERT of R9's 1-barrier/3-buffer experiment,
// which regressed qkv 64.6->72.0 us: the 2nd barrier phase-aligns all
// waves' stage-issue after compute; removing it lets stage drift per-wave
// and lengthens the next tile's vmcnt wait).
// BM=128, BN=128, BK=32, 4 waves (2x2 -> wave 64x64), 32 KiB LDS dbuf,
// 3 blocks/CU. Per tile: {vmcnt(4); bar; 8 ds_read_b128; 16 MFMA (setprio);
// bar; stage(t+2)}. Swizzle both-sides row[2:1] (conflicts = 0, R7).
// Layouts (validated): A-frag lane=A[m=l16][k=quad*8+j]; B-frag
// lane=B[k][n=l16]; C/D col=l16, row=quad*4+r.
// ---------------------------------------------------------------------------
__device__ __forceinline__ void gemm128_acc(
    const unsigned short* __restrict__ A, int lda, int m0,
    const unsigned short* __restrict__ W, int ldw, int n0,
    int Kmain, f32x4 (&acc)[4][4])
{
    __shared__ __align__(16) unsigned short As[2][4096];
    __shared__ __align__(16) unsigned short Bs[2][4096];
    const int tid = threadIdx.x;
    const int lane = tid & 63, wid = tid >> 6;
    const int quad = lane >> 4, l16 = lane & 15;
    const int wm = (wid >> 1) * 64, wn = (wid & 1) * 64;

    // staging source map: LDS linear; src 16B-slot pre-swizzled (row[2:1]).
    int arow[2], acol[2];
    #pragma unroll
    for (int c = 0; c < 2; c++) {
        const int o = tid * 16 + c * 4096;          // byte offset in 8KB tile
        arow[c] = o >> 6;                           // row (64B rows)
        acol[c] = (((tid & 3) * 16) ^ (((arow[c] >> 1) & 3) << 4)) >> 1;
    }

    const int nt = Kmain >> 5;

    auto stage = [&](int bb, int j) {
        const int k0 = j << 5;
        #pragma unroll
        for (int c = 0; c < 2; c++)
            gld16(A + (size_t)(m0 + arow[c]) * lda + k0 + acol[c],
                  &As[bb][tid * 8 + c * 2048]);
        #pragma unroll
        for (int c = 0; c < 2; c++)
            gld16(W + (size_t)(n0 + arow[c]) * ldw + k0 + acol[c],
                  &Bs[bb][tid * 8 + c * 2048]);
    };

    // fragment read offset (shorts): slot XOR with row bits [2:1] (= l16>>1).
    const int xoff = (((quad * 16) ^ (((l16 >> 1) & 3) << 4)) >> 1);
    const int ard = (wm + l16) * 32 + xoff;
    const int brd = (wn + l16) * 32 + xoff;

    stage(0, 0);
    stage(1, 1);

    for (int t = 0; t < nt; t++) {
        const int bb = t & 1;
        if (t < nt - 1) {
            asm volatile("s_waitcnt vmcnt(4)" ::: "memory");
        } else {
            asm volatile("s_waitcnt vmcnt(0)" ::: "memory");
        }
        __builtin_amdgcn_sched_barrier(0);
        FENCE; __builtin_amdgcn_s_barrier(); FENCE;

        bf16x8 af[4], bfn[4];
        #pragma unroll
        for (int mi = 0; mi < 4; mi++)
            af[mi] = *(const bf16x8*)&As[bb][ard + mi * 512];
        #pragma unroll
        for (int ni = 0; ni < 4; ni++)
            bfn[ni] = *(const bf16x8*)&Bs[bb][brd + ni * 512];

        __builtin_amdgcn_s_setprio(1);
        #pragma unroll
        for (int mi = 0; mi < 4; mi++)
            #pragma unroll
            for (int ni = 0; ni < 4; ni++)
                acc[mi][ni] = __builtin_amdgcn_mfma_f32_16x16x32_bf16(
                    af[mi], bfn[ni], acc[mi][ni], 0, 0, 0);
        __builtin_amdgcn_s_setprio(0);

        FENCE; __builtin_amdgcn_s_barrier(); FENCE;
        if (t + 2 < nt) stage(bb, t + 2);
    }
}

// RoPE applied in-register to one acc column-vector (4 rows).
__device__ __forceinline__ f32x4 rope4(f32x4 v, int col, int rowbase)
{
    const int t2 = col & 127;
    const float invf = __expf(-(float)(t2 >> 1) * (13.815510557964274f / 64.0f));
    const bool ev = (t2 & 1) == 0;
    f32x4 o;
    #pragma unroll
    for (int r = 0; r < 4; r++) {
        float self = v[r];
        float other = __shfl_xor(self, 1);
        float pos = (float)((rowbase + r) & (S_LEN - 1));
        float s, c;
        __sincosf(pos * invf, &s, &c);
        o[r] = ev ? (self * c - other * s) : (other * s + self * c);
    }
    return o;
}

// Fused QKV + RoPE. Grid (32, 24): by<16 Q, 16-19 K, 20-23 V.
__global__ __launch_bounds__(256, 3) void gemm128_qkv(
    const unsigned short* __restrict__ Xb,
    const unsigned short* __restrict__ Wqkv,
    unsigned short* __restrict__ Qo, unsigned short* __restrict__ Ko,
    unsigned short* __restrict__ Vt)
{
    const int m0 = blockIdx.x * 128;
    const int n0 = blockIdx.y * 128;
    f32x4 acc[4][4] = {};
    gemm128_acc(Xb, DMODEL, m0, Wqkv, DMODEL, n0, DMODEL, acc);

    const int tid = threadIdx.x, lane = tid & 63, wid = tid >> 6;
    const int l16 = lane & 15, quad = lane >> 4;
    const int wm = (wid >> 1) * 64, wn = (wid & 1) * 64;

    if (n0 < 2048) {
        #pragma unroll
        for (int mi = 0; mi < 4; mi++)
            #pragma unroll
            for (int ni = 0; ni < 4; ni++) {
                const int col = n0 + wn + ni * 16 + l16;
                const int rb = m0 + wm + mi * 16 + quad * 4;
                f32x4 v = rope4(acc[mi][ni], col, rb);
                #pragma unroll
                for (int r = 0; r < 4; r++)
                    Qo[(size_t)(rb + r) * DMODEL + col] = f2bf(v[r]);
            }
    } else if (n0 < 2560) {
        #pragma unroll
        for (int mi = 0; mi < 4; mi++)
            #pragma unroll
            for (int ni = 0; ni < 4; ni++) {
                const int col = n0 - 2048 + wn + ni * 16 + l16;
                const int rb = m0 + wm + mi * 16 + quad * 4;
                f32x4 v = rope4(acc[mi][ni], col, rb);
                #pragma unroll
                for (int r = 0; r < 4; r++)
                    Ko[(size_t)(rb + r) * 512 + col] = f2bf(v[r]);
            }
    } else {
        const int b = m0 >> 11;
        #pragma unroll
        for (int mi = 0; mi < 4; mi++)
            #pragma unroll
            for (int ni = 0; ni < 4; ni++) {
                const int ncol = n0 - 2560 + wn + ni * 16 + l16;
                const int head = ncol >> 7, dd = ncol & 127;
                const int srow = (m0 & (S_LEN - 1)) + wm + mi * 16 + quad * 4;
                uint2 pk;
                pk.x = pack2bf(acc[mi][ni][0], acc[mi][ni][1]);
                pk.y = pack2bf(acc[mi][ni][2], acc[mi][ni][3]);
                *(uint2*)(Vt + ((size_t)(b * NKVH + head) * HD + dd) * S_LEN + srow) = pk;
            }
    }
}

// Output projection. Grid (32, 16) = 512 blocks, fp32 out.
__global__ __launch_bounds__(256, 3) void gemm128_out(
    const unsigned short* __restrict__ Xb,
    const unsigned short* __restrict__ Ww,
    float* __restrict__ Out)
{
    const int m0 = blockIdx.x * 128;
    const int n0 = blockIdx.y * 128;
    f32x4 acc[4][4] = {};
    gemm128_acc(Xb, DMODEL, m0, Ww, DMODEL, n0, DMODEL, acc);

    const int tid = threadIdx.x, lane = tid & 63, wid = tid >> 6;
    const int l16 = lane & 15, quad = lane >> 4;
    const int wm = (wid >> 1) * 64, wn = (wid & 1) * 64;
    #pragma unroll
    for (int mi = 0; mi < 4; mi++)
        #pragma unroll
        for (int ni = 0; ni < 4; ni++) {
            const int col = n0 + wn + ni * 16 + l16;
            const size_t rb = (size_t)(m0 + wm + mi * 16 + quad * 4);
            #pragma unroll
            for (int r = 0; r < 4; r++)
                Out[(rb + r) * DMODEL + col] = acc[mi][ni][r];
        }
}

// ---------------------------------------------------------------------------
// MFMA flash attention v4: LDS-staged K/V shared by the whole block.
// Occupancy 3 blocks/CU (R9-verified gain).
// ---------------------------------------------------------------------------
__global__ __launch_bounds__(256, 3) void attn_mfma(
    const unsigned short* __restrict__ Q,
    const unsigned short* __restrict__ K,
    const unsigned short* __restrict__ Vt,
    unsigned short* __restrict__ O)
{
    __shared__ __align__(16) unsigned short kvbuf[2][8192];
    __shared__ unsigned short plds[4][32 * 40];
    const int tid = threadIdx.x, lane = tid & 63, wid = tid >> 6;
    const int l16 = lane & 15, quad = lane >> 4;
    const int bid = blockIdx.x;
    const int g   = bid & 7;
    const int kvh = g & 3;
    const int b   = g >> 2;
    const int qt  = 63 - (bid >> 3);
    const int q0  = qt * 32;
    const int h   = kvh * 4 + wid;

    const unsigned short* qrow0 = Q + ((size_t)(b * S_LEN + q0 + l16)) * DMODEL + h * HD;
    bf16x8 qf0[4], qf1[4];
    #pragma unroll
    for (int c = 0; c < 4; c++) {
        qf0[c] = *(const bf16x8*)(qrow0 + c * 32 + quad * 8);
        qf1[c] = *(const bf16x8*)(qrow0 + (size_t)16 * DMODEL + c * 32 + quad * 8);
    }

    const unsigned short* Kbase  = K + ((size_t)(b * S_LEN)) * (NKVH * HD) + kvh * HD;
    const unsigned short* Vplane = Vt + ((size_t)(b * NKVH + kvh) * HD) * S_LEN;
    unsigned short* pw = &plds[wid][0];

    const unsigned short* Ksrc[2];
    const unsigned short* Vsrc[2];
    #pragma unroll
    for (int c = 0; c < 2; c++) {
        const int o = wid * 2048 + c * 1024 + lane * 16;
        const int kkey = o >> 8;
        const int kdim = (o & 255) ^ ((kkey & 15) << 4);
        Ksrc[c] = Kbase + (size_t)kkey * (NKVH * HD) + (kdim >> 1);
        const int vd = o >> 6;
        const int vkb = (o & 63) ^ ((vd & 3) << 4);
        Vsrc[c] = Vplane + (size_t)vd * S_LEN + (vkb >> 1);
    }

    f32x4 oacc0[8] = {}, oacc1[8] = {};
    f32x4 lrow0 = {0.f, 0.f, 0.f, 0.f}, lrow1 = {0.f, 0.f, 0.f, 0.f};
    const float c2 = 0.12753102f;

    const int kthi = (q0 + 31) >> 5;
    int wlo = q0 - (WINDOW_ - 1); if (wlo < 0) wlo = 0;
    const int ktw = wlo >> 5;

    auto nexttile = [&](int t) -> int {
        if (t < ktw) { int u = t + 1; return (u < 2 && u < ktw) ? u : ktw; }
        return t + 1;
    };

    auto stage = [&](int buf, int ktb) {
        #pragma unroll
        for (int c = 0; c < 2; c++) {
            gld16(Ksrc[c] + (size_t)ktb * (NKVH * HD),
                  &kvbuf[buf][wid * 1024 + c * 512]);
            gld16(Vsrc[c] + ktb,
                  &kvbuf[buf][4096 + wid * 1024 + c * 512]);
        }
    };

    int kt = 0;
    stage(0, 0);
    __syncthreads();
    int cur = 0;

    while (true) {
        const int ktb = kt * 32;
        const int ktn = nexttile(kt);
        const bool last = (ktn > kthi);
        if (!last) stage(cur ^ 1, ktn * 32);

        const unsigned short* kb  = kvbuf[cur];
        const unsigned short* vbp = kvbuf[cur] + 4096;

        bf16x8 kf0[4], kf1[4];
        #pragma unroll
        for (int c = 0; c < 4; c++) {
            const int koff = (l16 * 256 + ((c * 64 + quad * 16) ^ (l16 << 4))) >> 1;
            kf0[c] = *(const bf16x8*)&kb[koff];
            kf1[c] = *(const bf16x8*)&kb[koff + 2048];
        }

        f32x4 s00 = {}, s01 = {}, s10 = {}, s11 = {};
        __builtin_amdgcn_s_setprio(1);
        #pragma unroll
        for (int c = 0; c < 4; c++) {
            s00 = __builtin_amdgcn_mfma_f32_16x16x32_bf16(qf0[c], kf0[c], s00, 0, 0, 0);
            s01 = __builtin_amdgcn_mfma_f32_16x16x32_bf16(qf0[c], kf1[c], s01, 0, 0, 0);
            s10 = __builtin_amdgcn_mfma_f32_16x16x32_bf16(qf1[c], kf0[c], s10, 0, 0, 0);
            s11 = __builtin_amdgcn_mfma_f32_16x16x32_bf16(qf1[c], kf1[c], s11, 0, 0, 0);
        }
        __builtin_amdgcn_s_setprio(0);

        #pragma unroll
        for (int s = 0; s < 2; s++) {
            const f32x4 sa0 = s ? s10 : s00;
            const f32x4 sa1 = s ? s11 : s01;
            const int qs = q0 + s * 16;
            const bool full = (ktb + 31 <= qs) &&
                              (((qs + 15) - ktb < WINDOW_) || (ktb + 31 < NGLOBAL));
            f32x4& lr = s ? lrow1 : lrow0;
            #pragma unroll
            for (int rr = 0; rr < 4; rr++) {
                float p0 = exp2f(sa0[rr] * c2);
                float p1 = exp2f(sa1[rr] * c2);
                if (!full) {
                    const int i = qs + quad * 4 + rr;
                    const int j0 = ktb + l16, j1 = j0 + 16;
                    bool a0 = (j0 <= i) && ((i - j0 < WINDOW_) || (j0 < NGLOBAL));
                    bool a1 = (j1 <= i) && ((i - j1 < WINDOW_) || (j1 < NGLOBAL));
                    p0 = a0 ? p0 : 0.f;
                    p1 = a1 ? p1 : 0.f;
                }
                lr[rr] += p0 + p1;
                pw[(s * 16 + quad * 4 + rr) * 40 + l16]      = f2bf(p0);
                pw[(s * 16 + quad * 4 + rr) * 40 + 16 + l16] = f2bf(p1);
            }
        }
        bf16x8 pa0 = *(const bf16x8*)(pw + l16 * 40 + quad * 8);
        bf16x8 pa1 = *(const bf16x8*)(pw + (16 + l16) * 40 + quad * 8);

        {
            bf16x8 va[4];
            #pragma unroll
            for (int ds = 0; ds < 4; ds++) {
                const int d = ds * 16 + l16;
                va[ds] = *(const bf16x8*)&vbp[(d * 64 + ((quad * 16) ^ ((l16 & 3) << 4))) >> 1];
            }
            __builtin_amdgcn_s_setprio(1);
            #pragma unroll
            for (int ds = 0; ds < 4; ds++) {
                oacc0[ds] = __builtin_amdgcn_mfma_f32_16x16x32_bf16(pa0, va[ds], oacc0[ds], 0, 0, 0);
                oacc1[ds] = __builtin_amdgcn_mfma_f32_16x16x32_bf16(pa1, va[ds], oacc1[ds], 0, 0, 0);
            }
            __builtin_amdgcn_s_setprio(0);
        }
        {
            bf16x8 vb[4];
            #pragma unroll
            for (int ds = 0; ds < 4; ds++) {
                const int d = (ds + 4) * 16 + l16;
                vb[ds] = *(const bf16x8*)&vbp[(d * 64 + ((quad * 16) ^ ((l16 & 3) << 4))) >> 1];
            }
            __builtin_amdgcn_s_setprio(1);
            #pragma unroll
            for (int ds = 0; ds < 4; ds++) {
                oacc0[ds + 4] = __builtin_amdgcn_mfma_f32_16x16x32_bf16(pa0, vb[ds], oacc0[ds + 4], 0, 0, 0);
                oacc1[ds + 4] = __builtin_amdgcn_mfma_f32_16x16x32_bf16(pa1, vb[ds], oacc1[ds + 4], 0, 0, 0);
            }
            __builtin_amdgcn_s_setprio(0);
        }

        if (last) break;
        __syncthreads();
        cur ^= 1;
        kt = ktn;
    }

    #pragma unroll
    for (int off = 1; off <= 8; off <<= 1) {
        #pragma unroll
        for (int rr = 0; rr < 4; rr++) {
            lrow0[rr] += __shfl_xor(lrow0[rr], off);
            lrow1[rr] += __shfl_xor(lrow1[rr], off);
        }
    }

    #pragma unroll
    for (int s = 0; s < 2; s++) {
        const f32x4& lr = s ? lrow1 : lrow0;
        #pragma unroll
        for (int rr = 0; rr < 4; rr++) {
            float inv = 1.f / lr[rr];
            unsigned short* orow = O + ((size_t)(b * S_LEN + q0 + s * 16 + quad * 4 + rr)) * DMODEL + h * HD;
            #pragma unroll
            for (int ds = 0; ds < 8; ds++) {
                float v = s ? oacc1[ds][rr] : oacc0[ds][rr];
                orow[ds * 16 + l16] = f2bf(v * inv);
            }
        }
    }
}

// ---------------------------------------------------------------------------
extern "C" void kernel_launch(void* const* d_in, const int* in_sizes, int n_in,
                              void* d_out, int out_size, void* d_ws, size_t ws_size,
                              hipStream_t stream)
{
    const float* x    = (const float*)d_in[0];
    const float* wq_w = (const float*)d_in[1];
    const float* wq_a = (const float*)d_in[2];
    const float* wq_b = (const float*)d_in[3];
    const float* wk_w = (const float*)d_in[4];
    const float* wk_a = (const float*)d_in[5];
    const float* wk_b = (const float*)d_in[6];
    const float* wv_w = (const float*)d_in[7];
    const float* wv_a = (const float*)d_in[8];
    const float* wv_b = (const float*)d_in[9];
    const float* wo_w = (const float*)d_in[10];
    const float* wo_a = (const float*)d_in[11];
    const float* wo_b = (const float*)d_in[12];

    char* ws = (char*)d_ws;
    unsigned short* wqkvb  = (unsigned short*)(ws);                 // 3072x2048
    unsigned short* apackT = (unsigned short*)(ws + 12582912);      // 3x(2048x128)
    unsigned short* bqkvb  = (unsigned short*)(ws + 14155776);      // 3072x128
    unsigned short* Qbuf   = (unsigned short*)(ws + 18087936);      // 4096x2048
    unsigned short* Kbuf   = (unsigned short*)(ws + 34865152);      // 4096x512
    unsigned short* Vtbuf  = (unsigned short*)(ws + 39059456);      // 2x4x128x2048
    // post-qkv reuse of the dead wqkvb region:
    unsigned short* wowb   = (unsigned short*)(ws);                 // 2048x2048
    unsigned short* wobb   = (unsigned short*)(ws + 8388608);       // 2048x128
    unsigned short* woabT  = (unsigned short*)(ws + 8912896);       // 2048x128
    // x (bf16) lives in d_out's first 16 MB; dead before the final GEMM.
    unsigned short* xb = (unsigned short*)d_out;

    // conv1: x + qkv B-matrices -> bf16 (dense W handled inside weffk)
    Conv12 c1;
    c1.s[0] = x;    c1.d[0] = xb;                     // 4096
    c1.s[1] = wq_b; c1.d[1] = bqkvb;                  // 128
    c1.s[2] = wk_b; c1.d[2] = bqkvb + 2048 * 128;     // 32
    c1.s[3] = wv_b; c1.d[3] = bqkvb + 2560 * 128;     // 32
    for (int i = 4; i < 12; i++) { c1.s[i] = wv_b; c1.d[i] = bqkvb + 2560 * 128; }
    int cum1[13] = {0, 4096, 4224, 4256, 4288, 4288, 4288, 4288, 4288, 4288,
                    4288, 4288, 4288};
    for (int i = 0; i < 13; i++) c1.c[i] = cum1[i];
    convk<<<dim3(4288), dim3(256), 0, stream>>>(c1);

    // A^T (bf16) for q,k,v
    TransA4 t1;
    t1.s[0] = wq_a; t1.d[0] = apackT;
    t1.s[1] = wk_a; t1.d[1] = apackT + 2048 * 128;
    t1.s[2] = wv_a; t1.d[2] = apackT + 2 * 2048 * 128;
    t1.s[3] = wq_a; t1.d[3] = apackT;
    transAk<<<dim3(384), dim3(256), 0, stream>>>(t1);

    // Weff_qkv = fp32(Wqkv) + Bqkv @ A  -> bf16
    weffk<<<dim3(24, 16), dim3(256), 0, stream>>>(
        wqkvb, DMODEL, wq_w, wk_w, wv_w, bqkvb, apackT, 1);

    // Q/K/V + fused RoPE (V transposed into Vt)
    gemm128_qkv<<<dim3(32, 24), dim3(256), 0, stream>>>(
        xb, wqkvb, Qbuf, Kbuf, Vtbuf);

    // conv2 (over dead wqkvb region): wo_b only
    Conv12 c2;
    c2.s[0] = wo_b; c2.d[0] = wobb;   // 128
    for (int i = 1; i < 12; i++) { c2.s[i] = wo_b; c2.d[i] = wobb; }
    int cum2[13] = {0, 128, 128, 128, 128, 128, 128, 128, 128, 128,
                    128, 128, 128};
    for (int i = 0; i < 13; i++) c2.c[i] = cum2[i];
    convk<<<dim3(128), dim3(256), 0, stream>>>(c2);

    TransA4 t2;
    t2.s[0] = wo_a; t2.d[0] = woabT;
    t2.s[1] = wo_a; t2.d[1] = woabT;
    t2.s[2] = wo_a; t2.d[2] = woabT;
    t2.s[3] = wo_a; t2.d[3] = woabT;
    transAk<<<dim3(128), dim3(256), 0, stream>>>(t2);

    // Weff_o = fp32(Wo) + Bo @ Ao -> bf16
    weffk<<<dim3(16, 16), dim3(256), 0, stream>>>(
        wowb, DMODEL, wo_w, wo_w, wo_w, wobb, woabT, 0);

    attn_mfma<<<dim3(512), dim3(256), 0, stream>>>(Qbuf, Kbuf, Vtbuf, Qbuf);

    // final: out = attn_out @ Weff_o^T  (fp32)
    gemm128_out<<<dim3(32, 16), dim3(256), 0, stream>>>(
        Qbuf, wowb, (float*)d_out);
}

// Round 11
// 302.260 us; speedup vs baseline: 1.3754x; 1.0104x over previous
//
#include <hip/hip_runtime.h>

#define B_ 2
#define S_LEN 2048
#define DMODEL 2048
#define NH 16
#define NKVH 4
#define HD 128
#define RLORA 128
#define WINDOW_ 512
#define NGLOBAL 64

#define FENCE asm volatile("" ::: "memory")

typedef __bf16 bf16x8 __attribute__((ext_vector_type(8)));
typedef float f32x4 __attribute__((ext_vector_type(4)));

__device__ __forceinline__ float bf2f(unsigned short h) {
    return __uint_as_float(((unsigned int)h) << 16);
}
__device__ __forceinline__ unsigned short f2bf(float f) {
    unsigned int u = __float_as_uint(f);
    unsigned int r = u + 0x7fffu + ((u >> 16) & 1u);
    return (unsigned short)(r >> 16);
}
__device__ __forceinline__ unsigned int pack2bf(float a, float b) {
    return (unsigned int)f2bf(a) | ((unsigned int)f2bf(b) << 16);
}
__device__ __forceinline__ uint4 load8f(const float* p) {
    float4 f0 = *(const float4*)p;
    float4 f1 = *(const float4*)(p + 4);
    uint4 u;
    u.x = pack2bf(f0.x, f0.y);
    u.y = pack2bf(f0.z, f0.w);
    u.z = pack2bf(f1.x, f1.y);
    u.w = pack2bf(f1.z, f1.w);
    return u;
}

// Async global->LDS, 16 B per lane. LDS dest = wave-uniform base + lane*16.
__device__ __forceinline__ void gld16(const unsigned short* g, unsigned short* l) {
    __builtin_amdgcn_global_load_lds(
        (const __attribute__((address_space(1))) unsigned int*)g,
        (__attribute__((address_space(3))) unsigned int*)l,
        16, 0, 0);
}

// ---------------------------------------------------------------------------
// R11 unified prep kernel (launch-count reduction: 9 -> 6 launches; ~10us
// per launch gap, R10 accounting audit). Block ranges, each the VALIDATED
// body from the former standalone kernels:
//   [0,4096)        x fp32 -> bf16
//   [4096,4608)     transAk x4: wq_a,wk_a,wv_a -> apackT ; wo_a -> woabT
//   [4608,4800)     wq_b/wk_b/wv_b fp32 -> bqkvb bf16
//   [4800,4928)     wo_b fp32 -> wobb bf16
// ---------------------------------------------------------------------------
struct PrepA {
    const float* x;
    const float* aq; const float* ak; const float* av; const float* ao;
    const float* bq; const float* bk; const float* bv; const float* bo;
    unsigned short* xb; unsigned short* apT; unsigned short* aoT;
    unsigned short* bqkv; unsigned short* bob;
};
__global__ __launch_bounds__(256) void prepk(PrepA a)
{
    __shared__ float tile[32][65];
    int b = blockIdx.x;
    const int t = threadIdx.x;
    if (b < 4096) {
        int off = b * 2048 + t * 8;
        *(uint4*)(a.xb + off) = load8f(a.x + off);
        return;
    }
    b -= 4096;
    if (b < 512) {
        const int mat = b >> 7;
        const int tl = b & 127;
        const int rt = tl & 3, ct = tl >> 2;
        const float* src = (mat == 0) ? a.aq : (mat == 1) ? a.ak :
                           (mat == 2) ? a.av : a.ao;
        unsigned short* dst = (mat == 3) ? a.aoT : a.apT + mat * 2048 * 128;
        #pragma unroll
        for (int p = 0; p < 2; p++) {
            int r = p * 16 + (t >> 4);
            int c = (t & 15) * 4;
            float4 v = *(const float4*)(src + (size_t)(rt * 32 + r) * 2048 + ct * 64 + c);
            tile[r][c] = v.x; tile[r][c + 1] = v.y;
            tile[r][c + 2] = v.z; tile[r][c + 3] = v.w;
        }
        __syncthreads();
        const int n = t >> 2, r8 = (t & 3) * 8;
        uint4 u;
        u.x = pack2bf(tile[r8 + 0][n], tile[r8 + 1][n]);
        u.y = pack2bf(tile[r8 + 2][n], tile[r8 + 3][n]);
        u.z = pack2bf(tile[r8 + 4][n], tile[r8 + 5][n]);
        u.w = pack2bf(tile[r8 + 6][n], tile[r8 + 7][n]);
        *(uint4*)(dst + (size_t)(ct * 64 + n) * 128 + rt * 32 + r8) = u;
        return;
    }
    b -= 512;
    if (b < 192) {
        const float* s; unsigned short* d; int off;
        if (b < 128)      { s = a.bq; d = a.bqkv;              off = b * 2048; }
        else if (b < 160) { s = a.bk; d = a.bqkv + 2048 * 128; off = (b - 128) * 2048; }
        else              { s = a.bv; d = a.bqkv + 2560 * 128; off = (b - 160) * 2048; }
        *(uint4*)(d + off + t * 8) = load8f(s + off + t * 8);
        return;
    }
    b -= 192;
    {
        int off = b * 2048 + t * 8;
        *(uint4*)(a.bob + off) = load8f(a.bo + off);
    }
}

// ---------------------------------------------------------------------------
// LoRA weight fold + fp32 convert: C[m][n] = bf16(W_f32[m][n] + B@A).
// Tile 128x128, K=128. seg: 1 = qkv row-segmented sources. (unchanged)
// ---------------------------------------------------------------------------
__global__ __launch_bounds__(256) void weffk(
    unsigned short* __restrict__ C, int ldc,
    const float* __restrict__ W0, const float* __restrict__ W1,
    const float* __restrict__ W2,
    const unsigned short* __restrict__ Bm,
    const unsigned short* __restrict__ At,
    int seg)
{
    const int m0 = blockIdx.x * 128;
    const int n0 = blockIdx.y * 128;
    const unsigned short* Atb = At;
    const float* Wsrc = W0;
    int wrow = m0;
    if (seg) {
        if (m0 >= 2560)      { Atb = At + 2 * 2048 * 128; Wsrc = W2; wrow = m0 - 2560; }
        else if (m0 >= 2048) { Atb = At + 2048 * 128;     Wsrc = W1; wrow = m0 - 2048; }
    }
    __shared__ __align__(16) unsigned short As_[128 * 32];
    __shared__ __align__(16) unsigned short Bs_[128 * 32];
    const int tid = threadIdx.x, lane = tid & 63, wid = tid >> 6;
    const int quad = lane >> 4, l16 = lane & 15;
    const int lr = lane >> 2, lc8 = (lane & 3) * 8;
    const int wm0 = (wid >> 1) * 64, wn0 = (wid & 1) * 64;
    f32x4 acc[4][4] = {};
    for (int k0 = 0; k0 < 128; k0 += 32) {
        #pragma unroll
        for (int c = 0; c < 2; c++) {
            int chunk = wid * 2 + c;
            gld16(Bm + (size_t)(m0 + chunk * 16 + lr) * 128 + k0 + lc8, As_ + chunk * 512);
            gld16(Atb + (size_t)(n0 + chunk * 16 + lr) * 128 + k0 + lc8, Bs_ + chunk * 512);
        }
        __syncthreads();
        bf16x8 af[4], bf[4];
        #pragma unroll
        for (int i = 0; i < 4; i++)
            af[i] = *(const bf16x8*)&As_[(wm0 + i * 16 + l16) * 32 + quad * 8];
        #pragma unroll
        for (int j = 0; j < 4; j++)
            bf[j] = *(const bf16x8*)&Bs_[(wn0 + j * 16 + l16) * 32 + quad * 8];
        #pragma unroll
        for (int i = 0; i < 4; i++)
            #pragma unroll
            for (int j = 0; j < 4; j++)
                acc[i][j] = __builtin_amdgcn_mfma_f32_16x16x32_bf16(af[i], bf[j], acc[i][j], 0, 0, 0);
        __syncthreads();
    }
    #pragma unroll
    for (int i = 0; i < 4; i++)
        #pragma unroll
        for (int j = 0; j < 4; j++) {
            const int col = n0 + wn0 + j * 16 + l16;
            #pragma unroll
            for (int r = 0; r < 4; r++) {
                const int row = wm0 + i * 16 + quad * 4 + r;
                float w = Wsrc[(size_t)(wrow + row) * 2048 + col];
                C[(size_t)(m0 + row) * ldc + col] = f2bf(w + acc[i][j][r]);
            }
        }
}

// ---------------------------------------------------------------------------
// GEMM core (R8-validated, best measured: qkv 64.6-65.7us, MfmaUtil 33%,
// conflicts 0). BM=128, BN=128, BK=32, 4 waves (2x2 -> wave 64x64),
// 32 KiB LDS dbuf, 3 blocks/CU. Per tile: {vmcnt(4); bar; 8 ds_read_b128;
// 16 MFMA (setprio); bar; stage(t+2)}. The 2nd barrier phase-aligns all
// waves' stage-issue (R9's 1-barrier/3-buffer variant regressed +11%).
// Swizzle both-sides row[2:1]. Layouts validated.
// ---------------------------------------------------------------------------
__device__ __forceinline__ void gemm128_acc(
    const unsigned short* __restrict__ A, int lda, int m0,
    const unsigned short* __restrict__ W, int ldw, int n0,
    int Kmain, f32x4 (&acc)[4][4])
{
    __shared__ __align__(16) unsigned short As[2][4096];
    __shared__ __align__(16) unsigned short Bs[2][4096];
    const int tid = threadIdx.x;
    const int lane = tid & 63, wid = tid >> 6;
    const int quad = lane >> 4, l16 = lane & 15;
    const int wm = (wid >> 1) * 64, wn = (wid & 1) * 64;

    int arow[2], acol[2];
    #pragma unroll
    for (int c = 0; c < 2; c++) {
        const int o = tid * 16 + c * 4096;
        arow[c] = o >> 6;
        acol[c] = (((tid & 3) * 16) ^ (((arow[c] >> 1) & 3) << 4)) >> 1;
    }

    const int nt = Kmain >> 5;

    auto stage = [&](int bb, int j) {
        const int k0 = j << 5;
        #pragma unroll
        for (int c = 0; c < 2; c++)
            gld16(A + (size_t)(m0 + arow[c]) * lda + k0 + acol[c],
                  &As[bb][tid * 8 + c * 2048]);
        #pragma unroll
        for (int c = 0; c < 2; c++)
            gld16(W + (size_t)(n0 + arow[c]) * ldw + k0 + acol[c],
                  &Bs[bb][tid * 8 + c * 2048]);
    };

    const int xoff = (((quad * 16) ^ (((l16 >> 1) & 3) << 4)) >> 1);
    const int ard = (wm + l16) * 32 + xoff;
    const int brd = (wn + l16) * 32 + xoff;

    stage(0, 0);
    stage(1, 1);

    for (int t = 0; t < nt; t++) {
        const int bb = t & 1;
        if (t < nt - 1) {
            asm volatile("s_waitcnt vmcnt(4)" ::: "memory");
        } else {
            asm volatile("s_waitcnt vmcnt(0)" ::: "memory");
        }
        __builtin_amdgcn_sched_barrier(0);
        FENCE; __builtin_amdgcn_s_barrier(); FENCE;

        bf16x8 af[4], bfn[4];
        #pragma unroll
        for (int mi = 0; mi < 4; mi++)
            af[mi] = *(const bf16x8*)&As[bb][ard + mi * 512];
        #pragma unroll
        for (int ni = 0; ni < 4; ni++)
            bfn[ni] = *(const bf16x8*)&Bs[bb][brd + ni * 512];

        __builtin_amdgcn_s_setprio(1);
        #pragma unroll
        for (int mi = 0; mi < 4; mi++)
            #pragma unroll
            for (int ni = 0; ni < 4; ni++)
                acc[mi][ni] = __builtin_amdgcn_mfma_f32_16x16x32_bf16(
                    af[mi], bfn[ni], acc[mi][ni], 0, 0, 0);
        __builtin_amdgcn_s_setprio(0);

        FENCE; __builtin_amdgcn_s_barrier(); FENCE;
        if (t + 2 < nt) stage(bb, t + 2);
    }
}

// RoPE applied in-register to one acc column-vector (4 rows).
__device__ __forceinline__ f32x4 rope4(f32x4 v, int col, int rowbase)
{
    const int t2 = col & 127;
    const float invf = __expf(-(float)(t2 >> 1) * (13.815510557964274f / 64.0f));
    const bool ev = (t2 & 1) == 0;
    f32x4 o;
    #pragma unroll
    for (int r = 0; r < 4; r++) {
        float self = v[r];
        float other = __shfl_xor(self, 1);
        float pos = (float)((rowbase + r) & (S_LEN - 1));
        float s, c;
        __sincosf(pos * invf, &s, &c);
        o[r] = ev ? (self * c - other * s) : (other * s + self * c);
    }
    return o;
}

// Fused QKV + RoPE. Grid (32, 24): by<16 Q, 16-19 K, 20-23 V.
__global__ __launch_bounds__(256, 3) void gemm128_qkv(
    const unsigned short* __restrict__ Xb,
    const unsigned short* __restrict__ Wqkv,
    unsigned short* __restrict__ Qo, unsigned short* __restrict__ Ko,
    unsigned short* __restrict__ Vt)
{
    const int m0 = blockIdx.x * 128;
    const int n0 = blockIdx.y * 128;
    f32x4 acc[4][4] = {};
    gemm128_acc(Xb, DMODEL, m0, Wqkv, DMODEL, n0, DMODEL, acc);

    const int tid = threadIdx.x, lane = tid & 63, wid = tid >> 6;
    const int l16 = lane & 15, quad = lane >> 4;
    const int wm = (wid >> 1) * 64, wn = (wid & 1) * 64;

    if (n0 < 2048) {
        #pragma unroll
        for (int mi = 0; mi < 4; mi++)
            #pragma unroll
            for (int ni = 0; ni < 4; ni++) {
                const int col = n0 + wn + ni * 16 + l16;
                const int rb = m0 + wm + mi * 16 + quad * 4;
                f32x4 v = rope4(acc[mi][ni], col, rb);
                #pragma unroll
                for (int r = 0; r < 4; r++)
                    Qo[(size_t)(rb + r) * DMODEL + col] = f2bf(v[r]);
            }
    } else if (n0 < 2560) {
        #pragma unroll
        for (int mi = 0; mi < 4; mi++)
            #pragma unroll
            for (int ni = 0; ni < 4; ni++) {
                const int col = n0 - 2048 + wn + ni * 16 + l16;
                const int rb = m0 + wm + mi * 16 + quad * 4;
                f32x4 v = rope4(acc[mi][ni], col, rb);
                #pragma unroll
                for (int r = 0; r < 4; r++)
                    Ko[(size_t)(rb + r) * 512 + col] = f2bf(v[r]);
            }
    } else {
        const int b = m0 >> 11;
        #pragma unroll
        for (int mi = 0; mi < 4; mi++)
            #pragma unroll
            for (int ni = 0; ni < 4; ni++) {
                const int ncol = n0 - 2560 + wn + ni * 16 + l16;
                const int head = ncol >> 7, dd = ncol & 127;
                const int srow = (m0 & (S_LEN - 1)) + wm + mi * 16 + quad * 4;
                uint2 pk;
                pk.x = pack2bf(acc[mi][ni][0], acc[mi][ni][1]);
                pk.y = pack2bf(acc[mi][ni][2], acc[mi][ni][3]);
                *(uint2*)(Vt + ((size_t)(b * NKVH + head) * HD + dd) * S_LEN + srow) = pk;
            }
    }
}

// Output projection. Grid (32, 16) = 512 blocks, fp32 out.
__global__ __launch_bounds__(256, 3) void gemm128_out(
    const unsigned short* __restrict__ Xb,
    const unsigned short* __restrict__ Ww,
    float* __restrict__ Out)
{
    const int m0 = blockIdx.x * 128;
    const int n0 = blockIdx.y * 128;
    f32x4 acc[4][4] = {};
    gemm128_acc(Xb, DMODEL, m0, Ww, DMODEL, n0, DMODEL, acc);

    const int tid = threadIdx.x, lane = tid & 63, wid = tid >> 6;
    const int l16 = lane & 15, quad = lane >> 4;
    const int wm = (wid >> 1) * 64, wn = (wid & 1) * 64;
    #pragma unroll
    for (int mi = 0; mi < 4; mi++)
        #pragma unroll
        for (int ni = 0; ni < 4; ni++) {
            const int col = n0 + wn + ni * 16 + l16;
            const size_t rb = (size_t)(m0 + wm + mi * 16 + quad * 4);
            #pragma unroll
            for (int r = 0; r < 4; r++)
                Out[(rb + r) * DMODEL + col] = acc[mi][ni][r];
        }
}

// ---------------------------------------------------------------------------
// MFMA flash attention v4: LDS-staged K/V shared by the whole block.
// Occupancy 3 blocks/CU.
// ---------------------------------------------------------------------------
__global__ __launch_bounds__(256, 3) void attn_mfma(
    const unsigned short* __restrict__ Q,
    const unsigned short* __restrict__ K,
    const unsigned short* __restrict__ Vt,
    unsigned short* __restrict__ O)
{
    __shared__ __align__(16) unsigned short kvbuf[2][8192];
    __shared__ unsigned short plds[4][32 * 40];
    const int tid = threadIdx.x, lane = tid & 63, wid = tid >> 6;
    const int l16 = lane & 15, quad = lane >> 4;
    const int bid = blockIdx.x;
    const int g   = bid & 7;
    const int kvh = g & 3;
    const int b   = g >> 2;
    const int qt  = 63 - (bid >> 3);
    const int q0  = qt * 32;
    const int h   = kvh * 4 + wid;

    const unsigned short* qrow0 = Q + ((size_t)(b * S_LEN + q0 + l16)) * DMODEL + h * HD;
    bf16x8 qf0[4], qf1[4];
    #pragma unroll
    for (int c = 0; c < 4; c++) {
        qf0[c] = *(const bf16x8*)(qrow0 + c * 32 + quad * 8);
        qf1[c] = *(const bf16x8*)(qrow0 + (size_t)16 * DMODEL + c * 32 + quad * 8);
    }

    const unsigned short* Kbase  = K + ((size_t)(b * S_LEN)) * (NKVH * HD) + kvh * HD;
    const unsigned short* Vplane = Vt + ((size_t)(b * NKVH + kvh) * HD) * S_LEN;
    unsigned short* pw = &plds[wid][0];

    const unsigned short* Ksrc[2];
    const unsigned short* Vsrc[2];
    #pragma unroll
    for (int c = 0; c < 2; c++) {
        const int o = wid * 2048 + c * 1024 + lane * 16;
        const int kkey = o >> 8;
        const int kdim = (o & 255) ^ ((kkey & 15) << 4);
        Ksrc[c] = Kbase + (size_t)kkey * (NKVH * HD) + (kdim >> 1);
        const int vd = o >> 6;
        const int vkb = (o & 63) ^ ((vd & 3) << 4);
        Vsrc[c] = Vplane + (size_t)vd * S_LEN + (vkb >> 1);
    }

    f32x4 oacc0[8] = {}, oacc1[8] = {};
    f32x4 lrow0 = {0.f, 0.f, 0.f, 0.f}, lrow1 = {0.f, 0.f, 0.f, 0.f};
    const float c2 = 0.12753102f;

    const int kthi = (q0 + 31) >> 5;
    int wlo = q0 - (WINDOW_ - 1); if (wlo < 0) wlo = 0;
    const int ktw = wlo >> 5;

    auto nexttile = [&](int t) -> int {
        if (t < ktw) { int u = t + 1; return (u < 2 && u < ktw) ? u : ktw; }
        return t + 1;
    };

    auto stage = [&](int buf, int ktb) {
        #pragma unroll
        for (int c = 0; c < 2; c++) {
            gld16(Ksrc[c] + (size_t)ktb * (NKVH * HD),
                  &kvbuf[buf][wid * 1024 + c * 512]);
            gld16(Vsrc[c] + ktb,
                  &kvbuf[buf][4096 + wid * 1024 + c * 512]);
        }
    };

    int kt = 0;
    stage(0, 0);
    __syncthreads();
    int cur = 0;

    while (true) {
        const int ktb = kt * 32;
        const int ktn = nexttile(kt);
        const bool last = (ktn > kthi);
        if (!last) stage(cur ^ 1, ktn * 32);

        const unsigned short* kb  = kvbuf[cur];
        const unsigned short* vbp = kvbuf[cur] + 4096;

        bf16x8 kf0[4], kf1[4];
        #pragma unroll
        for (int c = 0; c < 4; c++) {
            const int koff = (l16 * 256 + ((c * 64 + quad * 16) ^ (l16 << 4))) >> 1;
            kf0[c] = *(const bf16x8*)&kb[koff];
            kf1[c] = *(const bf16x8*)&kb[koff + 2048];
        }

        f32x4 s00 = {}, s01 = {}, s10 = {}, s11 = {};
        __builtin_amdgcn_s_setprio(1);
        #pragma unroll
        for (int c = 0; c < 4; c++) {
            s00 = __builtin_amdgcn_mfma_f32_16x16x32_bf16(qf0[c], kf0[c], s00, 0, 0, 0);
            s01 = __builtin_amdgcn_mfma_f32_16x16x32_bf16(qf0[c], kf1[c], s01, 0, 0, 0);
            s10 = __builtin_amdgcn_mfma_f32_16x16x32_bf16(qf1[c], kf0[c], s10, 0, 0, 0);
            s11 = __builtin_amdgcn_mfma_f32_16x16x32_bf16(qf1[c], kf1[c], s11, 0, 0, 0);
        }
        __builtin_amdgcn_s_setprio(0);

        #pragma unroll
        for (int s = 0; s < 2; s++) {
            const f32x4 sa0 = s ? s10 : s00;
            const f32x4 sa1 = s ? s11 : s01;
            const int qs = q0 + s * 16;
            const bool full = (ktb + 31 <= qs) &&
                              (((qs + 15) - ktb < WINDOW_) || (ktb + 31 < NGLOBAL));
            f32x4& lr = s ? lrow1 : lrow0;
            #pragma unroll
            for (int rr = 0; rr < 4; rr++) {
                float p0 = exp2f(sa0[rr] * c2);
                float p1 = exp2f(sa1[rr] * c2);
                if (!full) {
                    const int i = qs + quad * 4 + rr;
                    const int j0 = ktb + l16, j1 = j0 + 16;
                    bool a0 = (j0 <= i) && ((i - j0 < WINDOW_) || (j0 < NGLOBAL));
                    bool a1 = (j1 <= i) && ((i - j1 < WINDOW_) || (j1 < NGLOBAL));
                    p0 = a0 ? p0 : 0.f;
                    p1 = a1 ? p1 : 0.f;
                }
                lr[rr] += p0 + p1;
                pw[(s * 16 + quad * 4 + rr) * 40 + l16]      = f2bf(p0);
                pw[(s * 16 + quad * 4 + rr) * 40 + 16 + l16] = f2bf(p1);
            }
        }
        bf16x8 pa0 = *(const bf16x8*)(pw + l16 * 40 + quad * 8);
        bf16x8 pa1 = *(const bf16x8*)(pw + (16 + l16) * 40 + quad * 8);

        {
            bf16x8 va[4];
            #pragma unroll
            for (int ds = 0; ds < 4; ds++) {
                const int d = ds * 16 + l16;
                va[ds] = *(const bf16x8*)&vbp[(d * 64 + ((quad * 16) ^ ((l16 & 3) << 4))) >> 1];
            }
            __builtin_amdgcn_s_setprio(1);
            #pragma unroll
            for (int ds = 0; ds < 4; ds++) {
                oacc0[ds] = __builtin_amdgcn_mfma_f32_16x16x32_bf16(pa0, va[ds], oacc0[ds], 0, 0, 0);
                oacc1[ds] = __builtin_amdgcn_mfma_f32_16x16x32_bf16(pa1, va[ds], oacc1[ds], 0, 0, 0);
            }
            __builtin_amdgcn_s_setprio(0);
        }
        {
            bf16x8 vb[4];
            #pragma unroll
            for (int ds = 0; ds < 4; ds++) {
                const int d = (ds + 4) * 16 + l16;
                vb[ds] = *(const bf16x8*)&vbp[(d * 64 + ((quad * 16) ^ ((l16 & 3) << 4))) >> 1];
            }
            __builtin_amdgcn_s_setprio(1);
            #pragma unroll
            for (int ds = 0; ds < 4; ds++) {
                oacc0[ds + 4] = __builtin_amdgcn_mfma_f32_16x16x32_bf16(pa0, vb[ds], oacc0[ds + 4], 0, 0, 0);
                oacc1[ds + 4] = __builtin_amdgcn_mfma_f32_16x16x32_bf16(pa1, vb[ds], oacc1[ds + 4], 0, 0, 0);
            }
            __builtin_amdgcn_s_setprio(0);
        }

        if (last) break;
        __syncthreads();
        cur ^= 1;
        kt = ktn;
    }

    #pragma unroll
    for (int off = 1; off <= 8; off <<= 1) {
        #pragma unroll
        for (int rr = 0; rr < 4; rr++) {
            lrow0[rr] += __shfl_xor(lrow0[rr], off);
            lrow1[rr] += __shfl_xor(lrow1[rr], off);
        }
    }

    #pragma unroll
    for (int s = 0; s < 2; s++) {
        const f32x4& lr = s ? lrow1 : lrow0;
        #pragma unroll
        for (int rr = 0; rr < 4; rr++) {
            float inv = 1.f / lr[rr];
            unsigned short* orow = O + ((size_t)(b * S_LEN + q0 + s * 16 + quad * 4 + rr)) * DMODEL + h * HD;
            #pragma unroll
            for (int ds = 0; ds < 8; ds++) {
                float v = s ? oacc1[ds][rr] : oacc0[ds][rr];
                orow[ds * 16 + l16] = f2bf(v * inv);
            }
        }
    }
}

// ---------------------------------------------------------------------------
extern "C" void kernel_launch(void* const* d_in, const int* in_sizes, int n_in,
                              void* d_out, int out_size, void* d_ws, size_t ws_size,
                              hipStream_t stream)
{
    const float* x    = (const float*)d_in[0];
    const float* wq_w = (const float*)d_in[1];
    const float* wq_a = (const float*)d_in[2];
    const float* wq_b = (const float*)d_in[3];
    const float* wk_w = (const float*)d_in[4];
    const float* wk_a = (const float*)d_in[5];
    const float* wk_b = (const float*)d_in[6];
    const float* wv_w = (const float*)d_in[7];
    const float* wv_a = (const float*)d_in[8];
    const float* wv_b = (const float*)d_in[9];
    const float* wo_w = (const float*)d_in[10];
    const float* wo_a = (const float*)d_in[11];
    const float* wo_b = (const float*)d_in[12];

    char* ws = (char*)d_ws;
    unsigned short* wqkvb  = (unsigned short*)(ws);                 // 3072x2048
    unsigned short* apackT = (unsigned short*)(ws + 12582912);      // 3x(2048x128)
    unsigned short* bqkvb  = (unsigned short*)(ws + 14155776);      // 3072x128
    unsigned short* wobb   = (unsigned short*)(ws + 14942208);      // 2048x128 (ex-Tbuf gap)
    unsigned short* woabT  = (unsigned short*)(ws + 15466496);      // 2048x128
    unsigned short* Qbuf   = (unsigned short*)(ws + 18087936);      // 4096x2048
    unsigned short* Kbuf   = (unsigned short*)(ws + 34865152);      // 4096x512
    unsigned short* Vtbuf  = (unsigned short*)(ws + 39059456);      // 2x4x128x2048
    // post-qkv reuse of the dead wqkvb region:
    unsigned short* wowb   = (unsigned short*)(ws);                 // 2048x2048
    // x (bf16) lives in d_out's first 16 MB; dead before the final GEMM.
    unsigned short* xb = (unsigned short*)d_out;

    // 1) unified prep: x conv + A^T x4 + B convs + wo_b conv
    PrepA pa;
    pa.x = x;
    pa.aq = wq_a; pa.ak = wk_a; pa.av = wv_a; pa.ao = wo_a;
    pa.bq = wq_b; pa.bk = wk_b; pa.bv = wv_b; pa.bo = wo_b;
    pa.xb = xb; pa.apT = apackT; pa.aoT = woabT;
    pa.bqkv = bqkvb; pa.bob = wobb;
    prepk<<<dim3(4928), dim3(256), 0, stream>>>(pa);

    // 2) Weff_qkv = fp32(Wqkv) + Bqkv @ A  -> bf16
    weffk<<<dim3(24, 16), dim3(256), 0, stream>>>(
        wqkvb, DMODEL, wq_w, wk_w, wv_w, bqkvb, apackT, 1);

    // 3) Q/K/V + fused RoPE (V transposed into Vt)
    gemm128_qkv<<<dim3(32, 24), dim3(256), 0, stream>>>(
        xb, wqkvb, Qbuf, Kbuf, Vtbuf);

    // 4) Weff_o = fp32(Wo) + Bo @ Ao -> bf16 (wqkvb region dead after qkv)
    weffk<<<dim3(16, 16), dim3(256), 0, stream>>>(
        wowb, DMODEL, wo_w, wo_w, wo_w, wobb, woabT, 0);

    // 5) attention (O written over Q in place)
    attn_mfma<<<dim3(512), dim3(256), 0, stream>>>(Qbuf, Kbuf, Vtbuf, Qbuf);

    // 6) final: out = attn_out @ Weff_o^T  (fp32)
    gemm128_out<<<dim3(32, 16), dim3(256), 0, stream>>>(
        Qbuf, wowb, (float*)d_out);
}